// Round 5
// baseline (1567.133 us; speedup 1.0000x reference)
//
#include <hip/hip_runtime.h>
#include <math.h>
#include <float.h>

#define E0 131072
#define NN 32768
#define NB 1024
#define NSIDE 994
#define ETOT (E0 + NN)

typedef short bf16x8 __attribute__((ext_vector_type(8)));
typedef unsigned short ushort8 __attribute__((ext_vector_type(8)));
typedef float f32x4 __attribute__((ext_vector_type(4)));

__device__ inline float b2f(unsigned short u) { return __uint_as_float(((unsigned)u) << 16); }
__device__ inline unsigned short f2b(float f) {
  unsigned u = __float_as_uint(f);
  return (unsigned short)((u + 0x7fffu + ((u >> 16) & 1u)) >> 16);
}

__device__ inline void gload_lds16(const void* g, void* l) {
  __builtin_amdgcn_global_load_lds(
      (const __attribute__((address_space(1))) unsigned int*)g,
      (__attribute__((address_space(3))) unsigned int*)l, 16, 0, 0);
}

__device__ inline void atomicMaxF(float* addr, float val) {
  if (val >= 0.f) atomicMax((int*)addr, __float_as_int(val));
  else atomicMin((unsigned int*)addr, __float_as_uint(val));
}

__global__ void fill_f32(float* p, float v, int n) {
  int i = blockIdx.x * blockDim.x + threadIdx.x;
  if (i < n) p[i] = v;
}
__global__ void fill_i32(int* p, int v, int n) {
  int i = blockIdx.x * blockDim.x + threadIdx.x;
  if (i < n) p[i] = v;
}
__global__ void copy_i32(const int* s, int* d, int n) {
  int i = blockIdx.x * blockDim.x + threadIdx.x;
  if (i < n) d[i] = s[i];
}

// fp32 [RrealxC] -> bf16 [rowsOut x Cp], zero pad rows >= Rreal and cols >= C
__global__ void conv_pad(const float* __restrict__ in, unsigned short* __restrict__ out,
                         int rowsOut, int Rreal, int C, int Cp) {
  size_t idx = (size_t)blockIdx.x * blockDim.x + threadIdx.x;
  size_t tot = (size_t)rowsOut * Cp;
  if (idx >= tot) return;
  int r = (int)(idx / Cp), c = (int)(idx % Cp);
  out[idx] = (r < Rreal && c < C) ? f2b(in[(size_t)r * C + c]) : (unsigned short)0;
}

// W [K][N] f32 -> WT [Npad][Kp] bf16; rows n in [N,Npad) and cols k in [K,Kp) zeroed
__global__ __launch_bounds__(256) void transpose_w(const float* __restrict__ W,
                                                   unsigned short* __restrict__ WT,
                                                   int K, int N, int Kp, int Npad) {
  __shared__ float t[32][33];
  int k0 = blockIdx.y * 32, n0 = blockIdx.x * 32;
  int tx = threadIdx.x & 31, ty = threadIdx.x >> 5;
  for (int r = ty; r < 32; r += 8) {
    int k = k0 + r, n = n0 + tx;
    t[r][tx] = (k < K && n < N) ? W[(size_t)k * N + n] : 0.f;
  }
  __syncthreads();
  for (int r = ty; r < 32; r += 8) {
    int n = n0 + r, k = k0 + tx;
    if (n < Npad && k < Kp) WT[(size_t)n * Kp + k] = (n < N) ? f2b(t[tx][r]) : (unsigned short)0;
  }
}

// ---------------- CSR build over dst ----------------
__global__ void count_deg(const int* __restrict__ ei, int* deg) {
  int e = blockIdx.x * blockDim.x + threadIdx.x;
  if (e >= ETOT) return;
  int dst = (e < E0) ? ei[E0 + e] : (e - E0);
  atomicAdd(&deg[dst], 1);
}

__global__ void scan_deg(const int* __restrict__ deg, int* rowptr) {
  __shared__ int part[1024];
  int tid = threadIdx.x;
  const int chunk = NN / 1024;  // 32
  int base = tid * chunk;
  int local[chunk];
  int sum = 0;
#pragma unroll
  for (int i = 0; i < chunk; ++i) { local[i] = sum; sum += deg[base + i]; }
  part[tid] = sum;
  __syncthreads();
  for (int off = 1; off < 1024; off <<= 1) {
    int t = (tid >= off) ? part[tid - off] : 0;
    __syncthreads();
    part[tid] += t;
    __syncthreads();
  }
  int offset = part[tid] - sum;
#pragma unroll
  for (int i = 0; i < chunk; ++i) rowptr[base + i] = offset + local[i];
  if (tid == 1023) rowptr[NN] = offset + sum;
}

__global__ void fill_csr(const int* __restrict__ ei, int* cursor, int* csr) {
  int e = blockIdx.x * blockDim.x + threadIdx.x;
  if (e >= ETOT) return;
  int dst = (e < E0) ? ei[E0 + e] : (e - E0);
  int pos = atomicAdd(&cursor[dst], 1);
  csr[pos] = e;
}

// ---------------- bf16 MFMA GEMM ----------------
// 128x128 tile, BK=32, 4 waves; 1D grid (nwg%8==0) with XCD-chunked swizzle.
// LDS chunk layout (conflict-free): 1KB chunk = [4 kslots][16 rows][16B];
// staged via per-lane global src (row=lane&15, kslot=lane>>4), read at lane*16B.
// ACT: 0 none, 1 relu, 2 tanh, 3 abs(tanh). OBF: 1 bf16 out, 0 f32 out.
template <int ACT, int OBF>
__global__ __launch_bounds__(256) void gemm_mfma(
    const unsigned short* __restrict__ A, const unsigned short* __restrict__ BT,
    const float* __restrict__ bias, void* __restrict__ Cp,
    int Nreal, int K, int lda, int ldb, int ldc, int gx, int zpad) {
  __shared__ unsigned short As[128 * 32];
  __shared__ unsigned short Bs[128 * 32];
  const int nwg = gridDim.x;
  const int chunk = nwg >> 3;
  const int bid = blockIdx.x;
  const int swz = (bid & 7) * chunk + (bid >> 3);
  const int bm = (swz / gx) * 128, bn = (swz % gx) * 128;
  const int tid = threadIdx.x;
  const int wv = tid >> 6, lane = tid & 63;
  const int sr = lane & 15, sk = (lane >> 4) * 8;  // swizzled staging src
  const int wr = wv >> 1, wc = wv & 1;
  f32x4 acc[4][4];
#pragma unroll
  for (int i = 0; i < 4; ++i)
#pragma unroll
    for (int j = 0; j < 4; ++j) acc[i][j] = (f32x4){0.f, 0.f, 0.f, 0.f};

  const unsigned short* Abase = A + (size_t)bm * lda;
  const unsigned short* Bbase = BT + (size_t)bn * ldb;
  for (int k0 = 0; k0 < K; k0 += 32) {
    gload_lds16(Abase + (size_t)(wv * 16 + sr) * lda + k0 + sk, &As[wv * 512]);
    gload_lds16(Abase + (size_t)(64 + wv * 16 + sr) * lda + k0 + sk, &As[2048 + wv * 512]);
    gload_lds16(Bbase + (size_t)(wv * 16 + sr) * ldb + k0 + sk, &Bs[wv * 512]);
    gload_lds16(Bbase + (size_t)(64 + wv * 16 + sr) * ldb + k0 + sk, &Bs[2048 + wv * 512]);
    __syncthreads();
    bf16x8 af[4], bfr[4];
#pragma unroll
    for (int i = 0; i < 4; ++i)
      af[i] = *(const bf16x8*)&As[(wr * 4 + i) * 512 + lane * 8];
#pragma unroll
    for (int j = 0; j < 4; ++j)
      bfr[j] = *(const bf16x8*)&Bs[(wc * 4 + j) * 512 + lane * 8];
#pragma unroll
    for (int i = 0; i < 4; ++i)
#pragma unroll
      for (int j = 0; j < 4; ++j)
        acc[i][j] = __builtin_amdgcn_mfma_f32_16x16x32_bf16(af[i], bfr[j], acc[i][j], 0, 0, 0);
    __syncthreads();
  }
  const int r16 = lane & 15, kq = lane >> 4;
#pragma unroll
  for (int i = 0; i < 4; ++i) {
    int row = bm + wr * 64 + i * 16 + kq * 4;
#pragma unroll
    for (int j = 0; j < 4; ++j) {
      int col = bn + wc * 64 + j * 16 + r16;
      bool real = col < Nreal;
      if (!real && !zpad) continue;
      float bv = (bias && real) ? bias[col] : 0.f;
#pragma unroll
      for (int r = 0; r < 4; ++r) {
        float v = acc[i][j][r] + bv;
        if (ACT == 1) v = v > 0.f ? v : 0.f;
        else if (ACT == 2) v = tanhf(v);
        else if (ACT == 3) v = fabsf(tanhf(v));
        if (!real) v = 0.f;
        if (OBF) ((unsigned short*)Cp)[(size_t)(row + r) * ldc + col] = f2b(v);
        else ((float*)Cp)[(size_t)(row + r) * ldc + col] = v;
      }
    }
  }
}

// ---------------- split-K MFMA GEMM for z1 ----------------
// M=1024, Npad=1664 (Nreal 1600), K=19136 (598 k-steps). 16 K-slices (38/37 steps).
// grid = 1664; bijective XCD-chunk: each XCD owns 2 whole K-slices (L2 locality).
// Writes bf16 partials to PART[s][1024][1664].
__global__ __launch_bounds__(256) void gemm_mfma_sk(
    const unsigned short* __restrict__ A, const unsigned short* __restrict__ BT,
    unsigned short* __restrict__ PART, int lda, int ldb, int ldc) {
  __shared__ unsigned short As[128 * 32];
  __shared__ unsigned short Bs[128 * 32];
  const int bid = blockIdx.x;
  const int swz = (bid & 7) * 208 + (bid >> 3);  // nwg=1664, chunk=208
  const int s = swz / 104;                        // K-slice 0..15
  const int pos = swz - s * 104;                  // tile 0..103
  const int bm = (pos / 13) * 128, bn = (pos % 13) * 128;
  const int base = s * 37 + (s < 6 ? s : 6);
  const int nsteps = 37 + (s < 6 ? 1 : 0);
  const int tid = threadIdx.x;
  const int wv = tid >> 6, lane = tid & 63;
  const int sr = lane & 15, sk = (lane >> 4) * 8;
  const int wr = wv >> 1, wc = wv & 1;
  f32x4 acc[4][4];
#pragma unroll
  for (int i = 0; i < 4; ++i)
#pragma unroll
    for (int j = 0; j < 4; ++j) acc[i][j] = (f32x4){0.f, 0.f, 0.f, 0.f};

  const unsigned short* Abase = A + (size_t)bm * lda;
  const unsigned short* Bbase = BT + (size_t)bn * ldb;
  for (int ks = 0; ks < nsteps; ++ks) {
    int k0 = (base + ks) * 32;
    gload_lds16(Abase + (size_t)(wv * 16 + sr) * lda + k0 + sk, &As[wv * 512]);
    gload_lds16(Abase + (size_t)(64 + wv * 16 + sr) * lda + k0 + sk, &As[2048 + wv * 512]);
    gload_lds16(Bbase + (size_t)(wv * 16 + sr) * ldb + k0 + sk, &Bs[wv * 512]);
    gload_lds16(Bbase + (size_t)(64 + wv * 16 + sr) * ldb + k0 + sk, &Bs[2048 + wv * 512]);
    __syncthreads();
    bf16x8 af[4], bfr[4];
#pragma unroll
    for (int i = 0; i < 4; ++i)
      af[i] = *(const bf16x8*)&As[(wr * 4 + i) * 512 + lane * 8];
#pragma unroll
    for (int j = 0; j < 4; ++j)
      bfr[j] = *(const bf16x8*)&Bs[(wc * 4 + j) * 512 + lane * 8];
#pragma unroll
    for (int i = 0; i < 4; ++i)
#pragma unroll
      for (int j = 0; j < 4; ++j)
        acc[i][j] = __builtin_amdgcn_mfma_f32_16x16x32_bf16(af[i], bfr[j], acc[i][j], 0, 0, 0);
    __syncthreads();
  }
  unsigned short* out = PART + (size_t)s * 1024 * ldc;
  const int r16 = lane & 15, kq = lane >> 4;
#pragma unroll
  for (int i = 0; i < 4; ++i) {
    int row = bm + wr * 64 + i * 16 + kq * 4;
#pragma unroll
    for (int j = 0; j < 4; ++j) {
      int col = bn + wc * 64 + j * 16 + r16;
      if (col >= 1600) continue;
#pragma unroll
      for (int r = 0; r < 4; ++r)
        out[(size_t)(row + r) * ldc + col] = f2b(acc[i][j][r]);
    }
  }
}

// reduce 16 bf16 K-slice partials + bias + relu -> ZB bf16 [1024][1664], pad cols zeroed
__global__ void zred(const unsigned short* __restrict__ PART, const float* __restrict__ bias,
                     unsigned short* __restrict__ ZB) {
  int idx = blockIdx.x * blockDim.x + threadIdx.x;
  if (idx >= 1024 * 1664) return;
  int c = idx % 1664;
  if (c >= 1600) { ZB[idx] = 0; return; }
  float s = 0.f;
#pragma unroll
  for (int k = 0; k < 16; ++k) s += b2f(PART[(size_t)k * 1024 * 1664 + idx]);
  s += bias[c];
  ZB[idx] = f2b(s > 0.f ? s : 0.f);
}

// ---------------- GAT pieces ----------------
__global__ void gat_scores_bf(const unsigned short* __restrict__ hlin,
                              const float* __restrict__ a_s, const float* __restrict__ a_d,
                              float* __restrict__ als, float* __restrict__ ald,
                              int H, int C, int tot) {
  int idx = blockIdx.x * blockDim.x + threadIdx.x;
  if (idx >= tot) return;
  int n = idx / H, h = idx - n * H;
  const unsigned short* base = hlin + (size_t)n * H * C + (size_t)h * C;
  const float* as = a_s + h * C;
  const float* ad = a_d + h * C;
  float ss = 0.f, sd = 0.f;
  for (int c = 0; c < C; c += 8) {
    ushort8 v = *(const ushort8*)(base + c);
#pragma unroll
    for (int t = 0; t < 8; ++t) {
      float f = b2f(v[t]);
      ss = fmaf(f, as[c + t], ss);
      sd = fmaf(f, ad[c + t], sd);
    }
  }
  als[idx] = ss;
  ald[idx] = sd;
}

// fused attention: p = exp(leaky_relu(als[src]+ald[dst])), sb[dst] += p
template <int H>
__global__ void edge_attn(const int* __restrict__ ei, const float* __restrict__ als,
                          const float* __restrict__ ald, float* __restrict__ eb,
                          float* __restrict__ sb) {
  int e = blockIdx.x * blockDim.x + threadIdx.x;
  if (e >= ETOT) return;
  int src, dst;
  if (e < E0) { src = ei[e]; dst = ei[E0 + e]; } else { src = dst = e - E0; }
  if (H == 8) {
    float4 s0 = *(const float4*)(als + src * 8);
    float4 s1 = *(const float4*)(als + src * 8 + 4);
    float4 d0 = *(const float4*)(ald + dst * 8);
    float4 d1 = *(const float4*)(ald + dst * 8 + 4);
    float ev[8] = {s0.x + d0.x, s0.y + d0.y, s0.z + d0.z, s0.w + d0.w,
                   s1.x + d1.x, s1.y + d1.y, s1.z + d1.z, s1.w + d1.w};
#pragma unroll
    for (int h = 0; h < 8; ++h) {
      float v = ev[h];
      v = (v >= 0.f) ? v : 0.2f * v;
      float p = __expf(v);
      eb[(size_t)e * 8 + h] = p;
      atomicAdd(&sb[dst * 8 + h], p);
    }
  } else {
    float v = als[src] + ald[dst];
    v = (v >= 0.f) ? v : 0.2f * v;
    float p = __expf(v);
    eb[e] = p;
    atomicAdd(&sb[dst], p);
  }
}

// vectorized aggregate: thread = (node, 8-channel chunk); one edge loop, ushort8 gather
template <int F, int C>
__global__ __launch_bounds__(256) void gat_agg_v2(
    const int* __restrict__ rowptr, const int* __restrict__ csr,
    const int* __restrict__ ei, const float* __restrict__ eb,
    const float* __restrict__ sb, const unsigned short* __restrict__ hlin,
    const float* __restrict__ bias, unsigned short* __restrict__ out) {
  constexpr int H = F / C;
  constexpr int CPN = F / 8;
  int gidx = blockIdx.x * 256 + threadIdx.x;
  if (gidx >= NN * CPN) return;
  int node = gidx / CPN;
  int c0 = (gidx - node * CPN) * 8;
  int h = c0 / C;
  float inv_s = 1.f / sb[node * H + h];
  float acc[8] = {0.f, 0.f, 0.f, 0.f, 0.f, 0.f, 0.f, 0.f};
  int start = rowptr[node], end = rowptr[node + 1];
  for (int k = start; k < end; ++k) {
    int eid = csr[k];
    int src = (eid < E0) ? ei[eid] : (eid - E0);
    float p = eb[(size_t)eid * H + h];
    ushort8 hv = *(const ushort8*)(hlin + (size_t)src * F + c0);
#pragma unroll
    for (int t = 0; t < 8; ++t) acc[t] = fmaf(p, b2f(hv[t]), acc[t]);
  }
  ushort8 o;
#pragma unroll
  for (int t = 0; t < 8; ++t) {
    float val = acc[t] * inv_s + bias[c0 + t];
    o[t] = f2b(val > 0.f ? val : 0.f);
  }
  *(ushort8*)(out + (size_t)node * F + c0) = o;
}

__global__ void pool_scatter_bf(const unsigned short* __restrict__ h,
                                const int* __restrict__ batch, float* xg, int F, int tot) {
  int idx = blockIdx.x * blockDim.x + threadIdx.x;
  if (idx >= tot) return;
  int n = idx / F, f = idx - n * F;
  atomicMaxF(&xg[batch[n] * F + f], b2f(h[idx]));
}

__global__ void rownorm(const float* __restrict__ in, float* __restrict__ outp) {
  int r = blockIdx.x, lane = threadIdx.x;
  float v = in[r * 64 + lane];
  float ss = v * v;
#pragma unroll
  for (int off = 1; off < 64; off <<= 1) ss += __shfl_xor(ss, off);
  float nrm = fmaxf(sqrtf(ss), 1e-12f);
  outp[r * 64 + lane] = v / nrm;
}

__global__ __launch_bounds__(256) void freq_k(const float* __restrict__ dn,
                                              const float* __restrict__ sn,
                                              float* __restrict__ C, int M, int N) {
  __shared__ float As[16][64];
  __shared__ float Bs[16][65];
  int tid = threadIdx.x;
  int tx = tid & 15, ty = tid >> 4;
  int bi = blockIdx.y * 16, bj = blockIdx.x * 16;
#pragma unroll
  for (int t = 0; t < 4; ++t) {
    int idx = tid * 4 + t;
    int r = idx >> 6, c = idx & 63;
    As[r][c] = (bi + r < M) ? dn[(bi + r) * 64 + c] : 0.f;
    Bs[r][c] = (bj + r < N) ? sn[(bj + r) * 64 + c] : 0.f;
  }
  __syncthreads();
  float acc = 0.f;
#pragma unroll
  for (int k = 0; k < 64; ++k) acc = fmaf(As[ty][k], Bs[tx][k], acc);
  if (bi + ty < M && bj + tx < N) C[(size_t)(bi + ty) * N + (bj + tx)] = 5.f * acc;
}

// ---------------- launch ----------------
extern "C" void kernel_launch(void* const* d_in, const int* in_sizes, int n_in,
                              void* d_out, int out_size, void* d_ws, size_t ws_size,
                              hipStream_t stream) {
  const float* x = (const float*)d_in[0];
  const int* ei = (const int*)d_in[1];
  const int* batch = (const int*)d_in[2];
  const float* w = (const float*)d_in[3];
  const float* z = (const float*)d_in[4];
  const float* v = (const float*)d_in[5];
  const float* side = (const float*)d_in[6];
  const float* gW[4] = {(const float*)d_in[7], (const float*)d_in[11],
                        (const float*)d_in[15], (const float*)d_in[19]};
  const float* gas[4] = {(const float*)d_in[8], (const float*)d_in[12],
                         (const float*)d_in[16], (const float*)d_in[20]};
  const float* gad[4] = {(const float*)d_in[9], (const float*)d_in[13],
                         (const float*)d_in[17], (const float*)d_in[21]};
  const float* gb[4] = {(const float*)d_in[10], (const float*)d_in[14],
                        (const float*)d_in[18], (const float*)d_in[22]};
  const float* x5_W = (const float*)d_in[23]; const float* x5_b = (const float*)d_in[24];
  const float* x6_W = (const float*)d_in[25]; const float* x6_b = (const float*)d_in[26];
  const float* w1_W = (const float*)d_in[27]; const float* w1_b = (const float*)d_in[28];
  const float* w2_W = (const float*)d_in[29]; const float* w2_b = (const float*)d_in[30];
  const float* z1_W = (const float*)d_in[31]; const float* z1_b = (const float*)d_in[32];
  const float* z2_W = (const float*)d_in[33]; const float* z2_b = (const float*)d_in[34];
  const float* v1_W = (const float*)d_in[35]; const float* v1_b = (const float*)d_in[36];
  const float* v2_W = (const float*)d_in[37]; const float* v2_b = (const float*)d_in[38];
  const float* agg_W = (const float*)d_in[39]; const float* agg_b = (const float*)d_in[40];
  const float* col_W = (const float*)d_in[41]; const float* col_b = (const float*)d_in[42];
  const float* s1_W = (const float*)d_in[43]; const float* s1_b = (const float*)d_in[44];
  const float* s2_W = (const float*)d_in[45]; const float* s2_b = (const float*)d_in[46];

  char* wsb = (char*)d_ws;
  size_t off = 0;
  auto alloc = [&](size_t bytes) {
    void* p = wsb + off;
    off = (off + bytes + 255) & ~(size_t)255;
    return p;
  };
  unsigned short* HLIN = (unsigned short*)alloc((size_t)NN * 1024 * 2);  // aliased as PART later
  unsigned short* XB = (unsigned short*)alloc((size_t)NN * 1024 * 2);
  unsigned short* WTZ = (unsigned short*)alloc((size_t)1664 * 19136 * 2);
  unsigned short* ZA = (unsigned short*)alloc((size_t)1024 * 19136 * 2);
  unsigned short* WT1 = (unsigned short*)alloc((size_t)768 * 128 * 2);
  unsigned short* WT2 = (unsigned short*)alloc((size_t)1024 * 768 * 2);
  unsigned short* WT3 = (unsigned short*)alloc((size_t)1024 * 1024 * 2);
  unsigned short* WT4 = (unsigned short*)alloc((size_t)128 * 1024 * 2);
  unsigned short* WTW1 = (unsigned short*)alloc((size_t)768 * 768 * 2);
  unsigned short* WTW2 = (unsigned short*)alloc((size_t)128 * 768 * 2);
  unsigned short* WTZ2 = (unsigned short*)alloc((size_t)128 * 1664 * 2);
  unsigned short* WTV1 = (unsigned short*)alloc((size_t)256 * 1024 * 2);
  unsigned short* WTV2 = (unsigned short*)alloc((size_t)128 * 256 * 2);
  unsigned short* WTX5 = (unsigned short*)alloc((size_t)128 * 128 * 2);
  unsigned short* WTX6 = (unsigned short*)alloc((size_t)128 * 64 * 2);
  unsigned short* WTAGG = (unsigned short*)alloc((size_t)128 * 192 * 2);
  unsigned short* WTCOL = (unsigned short*)alloc((size_t)128 * 128 * 2);
  unsigned short* WTS1 = (unsigned short*)alloc((size_t)128 * 1056 * 2);
  unsigned short* WTS2 = (unsigned short*)alloc((size_t)128 * 64 * 2);
  unsigned short* WB = (unsigned short*)alloc((size_t)1024 * 768 * 2);
  unsigned short* VB = (unsigned short*)alloc((size_t)1024 * 1024 * 2);
  unsigned short* SIDEB = (unsigned short*)alloc((size_t)1024 * 1056 * 2);
  unsigned short* XGB = (unsigned short*)alloc((size_t)1024 * 128 * 2);
  unsigned short* ZB = (unsigned short*)alloc((size_t)1024 * 1664 * 2);
  unsigned short* X5O = (unsigned short*)alloc((size_t)1024 * 128 * 2);
  unsigned short* WMID = (unsigned short*)alloc((size_t)1024 * 768 * 2);
  unsigned short* VMID = (unsigned short*)alloc((size_t)1024 * 256 * 2);
  unsigned short* SEMID = (unsigned short*)alloc((size_t)1024 * 128 * 2);
  unsigned short* CAT192 = (unsigned short*)alloc((size_t)1024 * 192 * 2);
  unsigned short* CAT128 = (unsigned short*)alloc((size_t)1024 * 128 * 2);
  float* EB = (float*)alloc((size_t)ETOT * 8 * 4);
  float* ALS = (float*)alloc((size_t)NN * 8 * 4);
  float* ALD = (float*)alloc((size_t)NN * 8 * 4);
  float* SB = (float*)alloc((size_t)NN * 8 * 4);
  float* XG = (float*)alloc((size_t)NB * 128 * 4);
  float* DRUG = (float*)alloc((size_t)NB * 64 * 4);
  float* SE = (float*)alloc((size_t)1024 * 64 * 4);
  int* DEG = (int*)alloc((size_t)NN * 4);
  int* ROWPTR = (int*)alloc((size_t)(NN + 1) * 4);
  int* CURSOR = (int*)alloc((size_t)NN * 4);
  int* CSR = (int*)alloc((size_t)ETOT * 4);
  unsigned short* PART = (unsigned short*)HLIN;  // 16*1024*1664*2 = 54.5MB <= 64MB

  // CSR build
  hipLaunchKernelGGL(fill_i32, dim3((NN + 255) / 256), dim3(256), 0, stream, DEG, 0, NN);
  hipLaunchKernelGGL(count_deg, dim3((ETOT + 255) / 256), dim3(256), 0, stream, ei, DEG);
  hipLaunchKernelGGL(scan_deg, dim3(1), dim3(1024), 0, stream, DEG, ROWPTR);
  hipLaunchKernelGGL(copy_i32, dim3((NN + 255) / 256), dim3(256), 0, stream, ROWPTR, CURSOR, NN);
  hipLaunchKernelGGL(fill_csr, dim3((ETOT + 255) / 256), dim3(256), 0, stream, ei, CURSOR, CSR);

  // weight transposes (WT[Npad][Kp], zero-padded)
  auto launch_tw = [&](const float* W, unsigned short* WT, int K, int N, int Kp, int Npad) {
    dim3 g((Npad + 31) / 32, (Kp + 31) / 32);
    hipLaunchKernelGGL(transpose_w, g, dim3(256), 0, stream, W, WT, K, N, Kp, Npad);
  };
  launch_tw(gW[0], WT1, 109, 768, 128, 768);
  launch_tw(gW[1], WT2, 768, 1024, 768, 1024);
  launch_tw(gW[2], WT3, 1024, 1024, 1024, 1024);
  launch_tw(gW[3], WT4, 1024, 128, 1024, 128);
  launch_tw(z1_W, WTZ, 19127, 1600, 19136, 1664);
  launch_tw(w1_W, WTW1, 750, 750, 768, 768);
  launch_tw(w2_W, WTW2, 750, 64, 768, 128);
  launch_tw(z2_W, WTZ2, 1600, 64, 1664, 128);
  launch_tw(v1_W, WTV1, 1024, 256, 1024, 256);
  launch_tw(v2_W, WTV2, 256, 64, 256, 128);
  launch_tw(x5_W, WTX5, 128, 64, 128, 128);
  launch_tw(x6_W, WTX6, 64, 64, 64, 128);
  launch_tw(agg_W, WTAGG, 192, 64, 192, 128);
  launch_tw(col_W, WTCOL, 128, 64, 128, 128);
  launch_tw(s1_W, WTS1, 1050, 64, 1056, 128);
  launch_tw(s2_W, WTS2, 64, 64, 64, 128);

  // input conversions
  auto launch_conv = [&](const float* in, unsigned short* out, int rowsOut, int Rreal, int C, int Cp) {
    size_t tot = (size_t)rowsOut * Cp;
    hipLaunchKernelGGL(conv_pad, dim3((unsigned)((tot + 255) / 256)), dim3(256), 0, stream,
                       in, out, rowsOut, Rreal, C, Cp);
  };
  launch_conv(x, XB, NN, NN, 109, 128);
  launch_conv(z, ZA, NB, NB, 19127, 19136);
  launch_conv(w, WB, 1024, 1024, 750, 768);
  launch_conv(v, VB, 1024, 1024, 1024, 1024);
  launch_conv(side, SIDEB, 1024, 994, 1050, 1056);

  auto mm = [&](int act, int obf, const unsigned short* A, const unsigned short* BT,
                const float* bias, void* C, int M, int Npad, int Nreal, int K,
                int lda, int ldb, int ldc, int zpad) {
    int gx = Npad / 128;
    int nwg = gx * (M / 128);
    switch (act * 2 + obf) {
      case 0: hipLaunchKernelGGL((gemm_mfma<0,0>), dim3(nwg), dim3(256), 0, stream, A, BT, bias, C, Nreal, K, lda, ldb, ldc, gx, zpad); break;
      case 1: hipLaunchKernelGGL((gemm_mfma<0,1>), dim3(nwg), dim3(256), 0, stream, A, BT, bias, C, Nreal, K, lda, ldb, ldc, gx, zpad); break;
      case 2: hipLaunchKernelGGL((gemm_mfma<1,0>), dim3(nwg), dim3(256), 0, stream, A, BT, bias, C, Nreal, K, lda, ldb, ldc, gx, zpad); break;
      case 3: hipLaunchKernelGGL((gemm_mfma<1,1>), dim3(nwg), dim3(256), 0, stream, A, BT, bias, C, Nreal, K, lda, ldb, ldc, gx, zpad); break;
      case 4: hipLaunchKernelGGL((gemm_mfma<2,0>), dim3(nwg), dim3(256), 0, stream, A, BT, bias, C, Nreal, K, lda, ldb, ldc, gx, zpad); break;
      case 6: hipLaunchKernelGGL((gemm_mfma<3,0>), dim3(nwg), dim3(256), 0, stream, A, BT, bias, C, Nreal, K, lda, ldb, ldc, gx, zpad); break;
      default: break;
    }
  };

  // GAT layers
  const int Hs[4] = {8, 8, 8, 1};
  const int Cs[4] = {96, 128, 128, 128};
  const int Kp[4] = {128, 768, 1024, 1024};
  const unsigned short* WTs[4] = {WT1, WT2, WT3, WT4};
  for (int l = 0; l < 4; ++l) {
    int H = Hs[l], C = Cs[l], F = H * C;
    mm(0, 1, XB, WTs[l], nullptr, HLIN, NN, F, F, Kp[l], Kp[l], Kp[l], F, 0);
    int totNH = NN * H;
    hipLaunchKernelGGL(gat_scores_bf, dim3((totNH + 255) / 256), dim3(256), 0, stream,
                       HLIN, gas[l], gad[l], ALS, ALD, H, C, totNH);
    hipLaunchKernelGGL(fill_f32, dim3((totNH + 255) / 256), dim3(256), 0, stream, SB, 0.f, totNH);
    if (H == 8)
      hipLaunchKernelGGL((edge_attn<8>), dim3((ETOT + 255) / 256), dim3(256), 0, stream, ei, ALS, ALD, EB, SB);
    else
      hipLaunchKernelGGL((edge_attn<1>), dim3((ETOT + 255) / 256), dim3(256), 0, stream, ei, ALS, ALD, EB, SB);
    if (l == 0)
      hipLaunchKernelGGL((gat_agg_v2<768, 96>), dim3(NN * 96 / 256), dim3(256), 0, stream,
                         ROWPTR, CSR, ei, EB, SB, HLIN, gb[l], XB);
    else if (l == 3)
      hipLaunchKernelGGL((gat_agg_v2<128, 128>), dim3(NN * 16 / 256), dim3(256), 0, stream,
                         ROWPTR, CSR, ei, EB, SB, HLIN, gb[l], XB);
    else
      hipLaunchKernelGGL((gat_agg_v2<1024, 128>), dim3(NN * 128 / 256), dim3(256), 0, stream,
                         ROWPTR, CSR, ei, EB, SB, HLIN, gb[l], XB);
  }

  // global max pool -> XG f32 -> XGB bf16
  hipLaunchKernelGGL(fill_f32, dim3((NB * 128 + 255) / 256), dim3(256), 0, stream, XG, -FLT_MAX, NB * 128);
  hipLaunchKernelGGL(pool_scatter_bf, dim3((NN * 128 + 255) / 256), dim3(256), 0, stream, XB, batch, XG, 128, NN * 128);
  launch_conv(XG, XGB, 1024, 1024, 128, 128);

  // z1 split-K (16 slices, bf16 partials) + reduce -> ZB bf16
  hipLaunchKernelGGL(gemm_mfma_sk, dim3(1664), dim3(256), 0, stream, ZA, WTZ, PART, 19136, 19136, 1664);
  hipLaunchKernelGGL(zred, dim3((1024 * 1664 + 255) / 256), dim3(256), 0, stream, PART, z1_b, ZB);

  // tail chains (all MFMA bf16)
  mm(1, 1, XGB, WTX5, x5_b, X5O, 1024, 128, 64, 128, 128, 128, 128, 1);       // x5
  mm(1, 1, X5O, WTX6, x6_b, CAT192 + 0, 1024, 128, 64, 64, 128, 64, 192, 0);  // x6
  mm(1, 1, WB, WTW1, w1_b, WMID, 1024, 768, 750, 768, 768, 768, 768, 1);      // w1
  mm(1, 1, WMID, WTW2, w2_b, CAT192 + 64, 1024, 128, 64, 768, 768, 768, 192, 0);  // w2
  mm(1, 1, ZB, WTZ2, z2_b, CAT192 + 128, 1024, 128, 64, 1664, 1664, 1664, 192, 0); // z2
  mm(1, 1, VB, WTV1, v1_b, VMID, 1024, 256, 256, 1024, 1024, 1024, 256, 0);   // v1
  mm(1, 1, VMID, WTV2, v2_b, CAT128 + 64, 1024, 128, 64, 256, 256, 256, 128, 0);   // v2
  mm(0, 1, CAT192, WTAGG, agg_b, CAT128 + 0, 1024, 128, 64, 192, 192, 192, 128, 0); // agg
  mm(3, 0, CAT128, WTCOL, col_b, DRUG, 1024, 128, 64, 128, 128, 128, 64, 0);  // col: |tanh|
  mm(1, 1, SIDEB, WTS1, s1_b, SEMID, 1024, 128, 64, 1056, 1056, 1056, 128, 1); // s1
  mm(2, 0, SEMID, WTS2, s2_b, SE, 1024, 128, 64, 64, 128, 64, 64, 0);         // s2: tanh

  // normalize + similarity
  float* outp = (float*)d_out;
  float* DN = outp + (size_t)NB * NSIDE;
  float* SN = DN + (size_t)NB * 64;
  hipLaunchKernelGGL(rownorm, dim3(NB), dim3(64), 0, stream, DRUG, DN);
  hipLaunchKernelGGL(rownorm, dim3(NSIDE), dim3(64), 0, stream, SE, SN);
  hipLaunchKernelGGL(freq_k, dim3((NSIDE + 15) / 16, (NB + 15) / 16), dim3(256), 0, stream,
                     DN, SN, outp, NB, NSIDE);
}

// Round 6
// 1392.290 us; speedup vs baseline: 1.1256x; 1.1256x over previous
//
#include <hip/hip_runtime.h>
#include <math.h>
#include <float.h>

#define E0 131072
#define NN 32768
#define NB 1024
#define NSIDE 994
#define ETOT (E0 + NN)

typedef short bf16x8 __attribute__((ext_vector_type(8)));
typedef unsigned short ushort8 __attribute__((ext_vector_type(8)));
typedef float f32x4 __attribute__((ext_vector_type(4)));

__device__ inline float b2f(unsigned short u) { return __uint_as_float(((unsigned)u) << 16); }
__device__ inline unsigned short f2b(float f) {
  unsigned u = __float_as_uint(f);
  return (unsigned short)((u + 0x7fffu + ((u >> 16) & 1u)) >> 16);
}

__device__ inline void gload_lds16(const void* g, void* l) {
  __builtin_amdgcn_global_load_lds(
      (const __attribute__((address_space(1))) unsigned int*)g,
      (__attribute__((address_space(3))) unsigned int*)l, 16, 0, 0);
}

__device__ inline void atomicMaxF(float* addr, float val) {
  if (val >= 0.f) atomicMax((int*)addr, __float_as_int(val));
  else atomicMin((unsigned int*)addr, __float_as_uint(val));
}

__global__ void fill_f32(float* p, float v, int n) {
  int i = blockIdx.x * blockDim.x + threadIdx.x;
  if (i < n) p[i] = v;
}
__global__ void fill_i32(int* p, int v, int n) {
  int i = blockIdx.x * blockDim.x + threadIdx.x;
  if (i < n) p[i] = v;
}
__global__ void copy_i32(const int* s, int* d, int n) {
  int i = blockIdx.x * blockDim.x + threadIdx.x;
  if (i < n) d[i] = s[i];
}

// fp32 [RrealxC] -> bf16 [rowsOut x Cp], zero pad rows >= Rreal and cols >= C
__global__ void conv_pad(const float* __restrict__ in, unsigned short* __restrict__ out,
                         int rowsOut, int Rreal, int C, int Cp) {
  size_t idx = (size_t)blockIdx.x * blockDim.x + threadIdx.x;
  size_t tot = (size_t)rowsOut * Cp;
  if (idx >= tot) return;
  int r = (int)(idx / Cp), c = (int)(idx % Cp);
  out[idx] = (r < Rreal && c < C) ? f2b(in[(size_t)r * C + c]) : (unsigned short)0;
}

// W [K][N] f32 -> WT [Npad][Kp] bf16; rows n in [N,Npad) and cols k in [K,Kp) zeroed
__global__ __launch_bounds__(256) void transpose_w(const float* __restrict__ W,
                                                   unsigned short* __restrict__ WT,
                                                   int K, int N, int Kp, int Npad) {
  __shared__ float t[32][33];
  int k0 = blockIdx.y * 32, n0 = blockIdx.x * 32;
  int tx = threadIdx.x & 31, ty = threadIdx.x >> 5;
  for (int r = ty; r < 32; r += 8) {
    int k = k0 + r, n = n0 + tx;
    t[r][tx] = (k < K && n < N) ? W[(size_t)k * N + n] : 0.f;
  }
  __syncthreads();
  for (int r = ty; r < 32; r += 8) {
    int n = n0 + r, k = k0 + tx;
    if (n < Npad && k < Kp) WT[(size_t)n * Kp + k] = (n < N) ? f2b(t[tx][r]) : (unsigned short)0;
  }
}

// ---------------- CSR build over dst ----------------
__global__ void count_deg(const int* __restrict__ ei, int* deg) {
  int e = blockIdx.x * blockDim.x + threadIdx.x;
  if (e >= ETOT) return;
  int dst = (e < E0) ? ei[E0 + e] : (e - E0);
  atomicAdd(&deg[dst], 1);
}

__global__ void scan_deg(const int* __restrict__ deg, int* rowptr) {
  __shared__ int part[1024];
  int tid = threadIdx.x;
  const int chunk = NN / 1024;  // 32
  int base = tid * chunk;
  int local[chunk];
  int sum = 0;
#pragma unroll
  for (int i = 0; i < chunk; ++i) { local[i] = sum; sum += deg[base + i]; }
  part[tid] = sum;
  __syncthreads();
  for (int off = 1; off < 1024; off <<= 1) {
    int t = (tid >= off) ? part[tid - off] : 0;
    __syncthreads();
    part[tid] += t;
    __syncthreads();
  }
  int offset = part[tid] - sum;
#pragma unroll
  for (int i = 0; i < chunk; ++i) rowptr[base + i] = offset + local[i];
  if (tid == 1023) rowptr[NN] = offset + sum;
}

__global__ void fill_csr(const int* __restrict__ ei, int* cursor, int* csr) {
  int e = blockIdx.x * blockDim.x + threadIdx.x;
  if (e >= ETOT) return;
  int dst = (e < E0) ? ei[E0 + e] : (e - E0);
  int pos = atomicAdd(&cursor[dst], 1);
  csr[pos] = e;
}

// ---------------- bf16 MFMA GEMM ----------------
// 128x128 tile, BK=32, 4 waves; 1D grid (nwg%8==0) with XCD-chunked swizzle.
// LDS: row-major [128][32], linear gload_lds dest. XOR k-slot swizzle:
//   stage: lane l fetches row (l>>2), phys k-chunk (l&3)^((l>>3)&3)  [coalesced: each
//          4-lane cluster covers one row's contiguous 64B, permuted within]
//   read:  lane reads slot kq^((r16>>1)&3) -> phys chunk kq (uniform per 16-lane group)
//   -> ds_read_b128 bijectively covers contiguous 1KB, 2 lanes/bank-quad = conflict-free.
// ACT: 0 none, 1 relu, 2 tanh, 3 abs(tanh). OBF: 1 bf16 out, 0 f32 out.
template <int ACT, int OBF>
__global__ __launch_bounds__(256) void gemm_mfma(
    const unsigned short* __restrict__ A, const unsigned short* __restrict__ BT,
    const float* __restrict__ bias, void* __restrict__ Cp,
    int Nreal, int K, int lda, int ldb, int ldc, int gx, int zpad) {
  __shared__ unsigned short As[128 * 32];
  __shared__ unsigned short Bs[128 * 32];
  const int nwg = gridDim.x;
  const int chunk = nwg >> 3;
  const int bid = blockIdx.x;
  const int swz = (bid & 7) * chunk + (bid >> 3);
  const int bm = (swz / gx) * 128, bn = (swz % gx) * 128;
  const int tid = threadIdx.x;
  const int wv = tid >> 6, lane = tid & 63;
  const int sr = lane >> 2;                                  // staging row-in-16
  const int sk = ((lane & 3) ^ ((lane >> 3) & 3)) * 8;       // XOR'd phys k-chunk
  const int r16 = lane & 15, kq = lane >> 4;
  const int slot8 = (kq ^ ((r16 >> 1) & 3)) * 8;             // read slot (ushorts)
  const int wr = wv >> 1, wc = wv & 1;
  f32x4 acc[4][4];
#pragma unroll
  for (int i = 0; i < 4; ++i)
#pragma unroll
    for (int j = 0; j < 4; ++j) acc[i][j] = (f32x4){0.f, 0.f, 0.f, 0.f};

  const unsigned short* Abase = A + (size_t)bm * lda;
  const unsigned short* Bbase = BT + (size_t)bn * ldb;
  for (int k0 = 0; k0 < K; k0 += 32) {
    gload_lds16(Abase + (size_t)(wv * 16 + sr) * lda + k0 + sk, &As[wv * 512]);
    gload_lds16(Abase + (size_t)(64 + wv * 16 + sr) * lda + k0 + sk, &As[2048 + wv * 512]);
    gload_lds16(Bbase + (size_t)(wv * 16 + sr) * ldb + k0 + sk, &Bs[wv * 512]);
    gload_lds16(Bbase + (size_t)(64 + wv * 16 + sr) * ldb + k0 + sk, &Bs[2048 + wv * 512]);
    __syncthreads();
    bf16x8 af[4], bfr[4];
#pragma unroll
    for (int i = 0; i < 4; ++i)
      af[i] = *(const bf16x8*)&As[(wr * 64 + i * 16 + r16) * 32 + slot8];
#pragma unroll
    for (int j = 0; j < 4; ++j)
      bfr[j] = *(const bf16x8*)&Bs[(wc * 64 + j * 16 + r16) * 32 + slot8];
#pragma unroll
    for (int i = 0; i < 4; ++i)
#pragma unroll
      for (int j = 0; j < 4; ++j)
        acc[i][j] = __builtin_amdgcn_mfma_f32_16x16x32_bf16(af[i], bfr[j], acc[i][j], 0, 0, 0);
    __syncthreads();
  }
#pragma unroll
  for (int i = 0; i < 4; ++i) {
    int row = bm + wr * 64 + i * 16 + kq * 4;
#pragma unroll
    for (int j = 0; j < 4; ++j) {
      int col = bn + wc * 64 + j * 16 + r16;
      bool real = col < Nreal;
      if (!real && !zpad) continue;
      float bv = (bias && real) ? bias[col] : 0.f;
#pragma unroll
      for (int r = 0; r < 4; ++r) {
        float v = acc[i][j][r] + bv;
        if (ACT == 1) v = v > 0.f ? v : 0.f;
        else if (ACT == 2) v = tanhf(v);
        else if (ACT == 3) v = fabsf(tanhf(v));
        if (!real) v = 0.f;
        if (OBF) ((unsigned short*)Cp)[(size_t)(row + r) * ldc + col] = f2b(v);
        else ((float*)Cp)[(size_t)(row + r) * ldc + col] = v;
      }
    }
  }
}

// ---------------- split-K MFMA GEMM for z1 ----------------
// M=1024, Npad=1664 (Nreal 1600), K=19136 (598 k-steps). 8 K-slices (75/74 steps).
// grid = 832; s = bid&7 -> XCD round-robin puts one K-slice per XCD.
// f32 partials to PART[s][1024][1664]. Same XOR staging as gemm_mfma.
__global__ __launch_bounds__(256) void gemm_mfma_sk(
    const unsigned short* __restrict__ A, const unsigned short* __restrict__ BT,
    float* __restrict__ PART, int lda, int ldb, int ldc) {
  __shared__ unsigned short As[128 * 32];
  __shared__ unsigned short Bs[128 * 32];
  const int bid = blockIdx.x;
  const int s = bid & 7;
  const int pos = bid >> 3;            // 0..103
  const int bm = (pos / 13) * 128, bn = (pos % 13) * 128;
  const int base = s * 74 + (s < 6 ? s : 6);
  const int nsteps = 74 + (s < 6 ? 1 : 0);
  const int tid = threadIdx.x;
  const int wv = tid >> 6, lane = tid & 63;
  const int sr = lane >> 2;
  const int sk = ((lane & 3) ^ ((lane >> 3) & 3)) * 8;
  const int r16 = lane & 15, kq = lane >> 4;
  const int slot8 = (kq ^ ((r16 >> 1) & 3)) * 8;
  const int wr = wv >> 1, wc = wv & 1;
  f32x4 acc[4][4];
#pragma unroll
  for (int i = 0; i < 4; ++i)
#pragma unroll
    for (int j = 0; j < 4; ++j) acc[i][j] = (f32x4){0.f, 0.f, 0.f, 0.f};

  const unsigned short* Abase = A + (size_t)bm * lda;
  const unsigned short* Bbase = BT + (size_t)bn * ldb;
  for (int ks = 0; ks < nsteps; ++ks) {
    int k0 = (base + ks) * 32;
    gload_lds16(Abase + (size_t)(wv * 16 + sr) * lda + k0 + sk, &As[wv * 512]);
    gload_lds16(Abase + (size_t)(64 + wv * 16 + sr) * lda + k0 + sk, &As[2048 + wv * 512]);
    gload_lds16(Bbase + (size_t)(wv * 16 + sr) * ldb + k0 + sk, &Bs[wv * 512]);
    gload_lds16(Bbase + (size_t)(64 + wv * 16 + sr) * ldb + k0 + sk, &Bs[2048 + wv * 512]);
    __syncthreads();
    bf16x8 af[4], bfr[4];
#pragma unroll
    for (int i = 0; i < 4; ++i)
      af[i] = *(const bf16x8*)&As[(wr * 64 + i * 16 + r16) * 32 + slot8];
#pragma unroll
    for (int j = 0; j < 4; ++j)
      bfr[j] = *(const bf16x8*)&Bs[(wc * 64 + j * 16 + r16) * 32 + slot8];
#pragma unroll
    for (int i = 0; i < 4; ++i)
#pragma unroll
      for (int j = 0; j < 4; ++j)
        acc[i][j] = __builtin_amdgcn_mfma_f32_16x16x32_bf16(af[i], bfr[j], acc[i][j], 0, 0, 0);
    __syncthreads();
  }
  float* out = PART + (size_t)s * 1024 * ldc;
#pragma unroll
  for (int i = 0; i < 4; ++i) {
    int row = bm + wr * 64 + i * 16 + kq * 4;
#pragma unroll
    for (int j = 0; j < 4; ++j) {
      int col = bn + wc * 64 + j * 16 + r16;
      if (col >= 1600) continue;
#pragma unroll
      for (int r = 0; r < 4; ++r)
        out[(size_t)(row + r) * ldc + col] = acc[i][j][r];
    }
  }
}

// reduce 8 f32 K-slice partials + bias + relu -> ZB bf16 [1024][1664], pad cols zeroed
__global__ void zred(const float* __restrict__ PART, const float* __restrict__ bias,
                     unsigned short* __restrict__ ZB) {
  int idx = blockIdx.x * blockDim.x + threadIdx.x;
  if (idx >= 1024 * 1664) return;
  int c = idx % 1664;
  if (c >= 1600) { ZB[idx] = 0; return; }
  float s = 0.f;
#pragma unroll
  for (int k = 0; k < 8; ++k) s += PART[(size_t)k * 1024 * 1664 + idx];
  s += bias[c];
  ZB[idx] = f2b(s > 0.f ? s : 0.f);
}

// ---------------- GAT pieces ----------------
__global__ void gat_scores_bf(const unsigned short* __restrict__ hlin,
                              const float* __restrict__ a_s, const float* __restrict__ a_d,
                              float* __restrict__ als, float* __restrict__ ald,
                              int H, int C, int tot) {
  int idx = blockIdx.x * blockDim.x + threadIdx.x;
  if (idx >= tot) return;
  int n = idx / H, h = idx - n * H;
  const unsigned short* base = hlin + (size_t)n * H * C + (size_t)h * C;
  const float* as = a_s + h * C;
  const float* ad = a_d + h * C;
  float ss = 0.f, sd = 0.f;
  for (int c = 0; c < C; c += 8) {
    ushort8 v = *(const ushort8*)(base + c);
#pragma unroll
    for (int t = 0; t < 8; ++t) {
      float f = b2f(v[t]);
      ss = fmaf(f, as[c + t], ss);
      sd = fmaf(f, ad[c + t], sd);
    }
  }
  als[idx] = ss;
  ald[idx] = sd;
}

// fused attention: p = exp(leaky_relu(als[src]+ald[dst])), sb[dst] += p
template <int H>
__global__ void edge_attn(const int* __restrict__ ei, const float* __restrict__ als,
                          const float* __restrict__ ald, float* __restrict__ eb,
                          float* __restrict__ sb) {
  int e = blockIdx.x * blockDim.x + threadIdx.x;
  if (e >= ETOT) return;
  int src, dst;
  if (e < E0) { src = ei[e]; dst = ei[E0 + e]; } else { src = dst = e - E0; }
  if (H == 8) {
    float4 s0 = *(const float4*)(als + src * 8);
    float4 s1 = *(const float4*)(als + src * 8 + 4);
    float4 d0 = *(const float4*)(ald + dst * 8);
    float4 d1 = *(const float4*)(ald + dst * 8 + 4);
    float ev[8] = {s0.x + d0.x, s0.y + d0.y, s0.z + d0.z, s0.w + d0.w,
                   s1.x + d1.x, s1.y + d1.y, s1.z + d1.z, s1.w + d1.w};
#pragma unroll
    for (int h = 0; h < 8; ++h) {
      float v = ev[h];
      v = (v >= 0.f) ? v : 0.2f * v;
      float p = __expf(v);
      eb[(size_t)e * 8 + h] = p;
      atomicAdd(&sb[dst * 8 + h], p);
    }
  } else {
    float v = als[src] + ald[dst];
    v = (v >= 0.f) ? v : 0.2f * v;
    float p = __expf(v);
    eb[e] = p;
    atomicAdd(&sb[dst], p);
  }
}

// vectorized aggregate: thread = (node, 8-channel chunk); one edge loop, ushort8 gather
template <int F, int C>
__global__ __launch_bounds__(256) void gat_agg_v2(
    const int* __restrict__ rowptr, const int* __restrict__ csr,
    const int* __restrict__ ei, const float* __restrict__ eb,
    const float* __restrict__ sb, const unsigned short* __restrict__ hlin,
    const float* __restrict__ bias, unsigned short* __restrict__ out) {
  constexpr int H = F / C;
  constexpr int CPN = F / 8;
  int gidx = blockIdx.x * 256 + threadIdx.x;
  if (gidx >= NN * CPN) return;
  int node = gidx / CPN;
  int c0 = (gidx - node * CPN) * 8;
  int h = c0 / C;
  float inv_s = 1.f / sb[node * H + h];
  float acc[8] = {0.f, 0.f, 0.f, 0.f, 0.f, 0.f, 0.f, 0.f};
  int start = rowptr[node], end = rowptr[node + 1];
  for (int k = start; k < end; ++k) {
    int eid = csr[k];
    int src = (eid < E0) ? ei[eid] : (eid - E0);
    float p = eb[(size_t)eid * H + h];
    ushort8 hv = *(const ushort8*)(hlin + (size_t)src * F + c0);
#pragma unroll
    for (int t = 0; t < 8; ++t) acc[t] = fmaf(p, b2f(hv[t]), acc[t]);
  }
  ushort8 o;
#pragma unroll
  for (int t = 0; t < 8; ++t) {
    float val = acc[t] * inv_s + bias[c0 + t];
    o[t] = f2b(val > 0.f ? val : 0.f);
  }
  *(ushort8*)(out + (size_t)node * F + c0) = o;
}

__global__ void pool_scatter_bf(const unsigned short* __restrict__ h,
                                const int* __restrict__ batch, float* xg, int F, int tot) {
  int idx = blockIdx.x * blockDim.x + threadIdx.x;
  if (idx >= tot) return;
  int n = idx / F, f = idx - n * F;
  atomicMaxF(&xg[batch[n] * F + f], b2f(h[idx]));
}

__global__ void rownorm(const float* __restrict__ in, float* __restrict__ outp) {
  int r = blockIdx.x, lane = threadIdx.x;
  float v = in[r * 64 + lane];
  float ss = v * v;
#pragma unroll
  for (int off = 1; off < 64; off <<= 1) ss += __shfl_xor(ss, off);
  float nrm = fmaxf(sqrtf(ss), 1e-12f);
  outp[r * 64 + lane] = v / nrm;
}

__global__ __launch_bounds__(256) void freq_k(const float* __restrict__ dn,
                                              const float* __restrict__ sn,
                                              float* __restrict__ C, int M, int N) {
  __shared__ float As[16][64];
  __shared__ float Bs[16][65];
  int tid = threadIdx.x;
  int tx = tid & 15, ty = tid >> 4;
  int bi = blockIdx.y * 16, bj = blockIdx.x * 16;
#pragma unroll
  for (int t = 0; t < 4; ++t) {
    int idx = tid * 4 + t;
    int r = idx >> 6, c = idx & 63;
    As[r][c] = (bi + r < M) ? dn[(bi + r) * 64 + c] : 0.f;
    Bs[r][c] = (bj + r < N) ? sn[(bj + r) * 64 + c] : 0.f;
  }
  __syncthreads();
  float acc = 0.f;
#pragma unroll
  for (int k = 0; k < 64; ++k) acc = fmaf(As[ty][k], Bs[tx][k], acc);
  if (bi + ty < M && bj + tx < N) C[(size_t)(bi + ty) * N + (bj + tx)] = 5.f * acc;
}

// ---------------- launch ----------------
extern "C" void kernel_launch(void* const* d_in, const int* in_sizes, int n_in,
                              void* d_out, int out_size, void* d_ws, size_t ws_size,
                              hipStream_t stream) {
  const float* x = (const float*)d_in[0];
  const int* ei = (const int*)d_in[1];
  const int* batch = (const int*)d_in[2];
  const float* w = (const float*)d_in[3];
  const float* z = (const float*)d_in[4];
  const float* v = (const float*)d_in[5];
  const float* side = (const float*)d_in[6];
  const float* gW[4] = {(const float*)d_in[7], (const float*)d_in[11],
                        (const float*)d_in[15], (const float*)d_in[19]};
  const float* gas[4] = {(const float*)d_in[8], (const float*)d_in[12],
                         (const float*)d_in[16], (const float*)d_in[20]};
  const float* gad[4] = {(const float*)d_in[9], (const float*)d_in[13],
                         (const float*)d_in[17], (const float*)d_in[21]};
  const float* gb[4] = {(const float*)d_in[10], (const float*)d_in[14],
                        (const float*)d_in[18], (const float*)d_in[22]};
  const float* x5_W = (const float*)d_in[23]; const float* x5_b = (const float*)d_in[24];
  const float* x6_W = (const float*)d_in[25]; const float* x6_b = (const float*)d_in[26];
  const float* w1_W = (const float*)d_in[27]; const float* w1_b = (const float*)d_in[28];
  const float* w2_W = (const float*)d_in[29]; const float* w2_b = (const float*)d_in[30];
  const float* z1_W = (const float*)d_in[31]; const float* z1_b = (const float*)d_in[32];
  const float* z2_W = (const float*)d_in[33]; const float* z2_b = (const float*)d_in[34];
  const float* v1_W = (const float*)d_in[35]; const float* v1_b = (const float*)d_in[36];
  const float* v2_W = (const float*)d_in[37]; const float* v2_b = (const float*)d_in[38];
  const float* agg_W = (const float*)d_in[39]; const float* agg_b = (const float*)d_in[40];
  const float* col_W = (const float*)d_in[41]; const float* col_b = (const float*)d_in[42];
  const float* s1_W = (const float*)d_in[43]; const float* s1_b = (const float*)d_in[44];
  const float* s2_W = (const float*)d_in[45]; const float* s2_b = (const float*)d_in[46];

  char* wsb = (char*)d_ws;
  size_t off = 0;
  auto alloc = [&](size_t bytes) {
    void* p = wsb + off;
    off = (off + bytes + 255) & ~(size_t)255;
    return p;
  };
  unsigned short* HLIN = (unsigned short*)alloc((size_t)NN * 1024 * 2);  // aliased as PART later
  unsigned short* XB = (unsigned short*)alloc((size_t)NN * 1024 * 2);
  unsigned short* WTZ = (unsigned short*)alloc((size_t)1664 * 19136 * 2);
  unsigned short* ZA = (unsigned short*)alloc((size_t)1024 * 19136 * 2);
  unsigned short* WT1 = (unsigned short*)alloc((size_t)768 * 128 * 2);
  unsigned short* WT2 = (unsigned short*)alloc((size_t)1024 * 768 * 2);
  unsigned short* WT3 = (unsigned short*)alloc((size_t)1024 * 1024 * 2);
  unsigned short* WT4 = (unsigned short*)alloc((size_t)128 * 1024 * 2);
  unsigned short* WTW1 = (unsigned short*)alloc((size_t)768 * 768 * 2);
  unsigned short* WTW2 = (unsigned short*)alloc((size_t)128 * 768 * 2);
  unsigned short* WTZ2 = (unsigned short*)alloc((size_t)128 * 1664 * 2);
  unsigned short* WTV1 = (unsigned short*)alloc((size_t)256 * 1024 * 2);
  unsigned short* WTV2 = (unsigned short*)alloc((size_t)128 * 256 * 2);
  unsigned short* WTX5 = (unsigned short*)alloc((size_t)128 * 128 * 2);
  unsigned short* WTX6 = (unsigned short*)alloc((size_t)128 * 64 * 2);
  unsigned short* WTAGG = (unsigned short*)alloc((size_t)128 * 192 * 2);
  unsigned short* WTCOL = (unsigned short*)alloc((size_t)128 * 128 * 2);
  unsigned short* WTS1 = (unsigned short*)alloc((size_t)128 * 1056 * 2);
  unsigned short* WTS2 = (unsigned short*)alloc((size_t)128 * 64 * 2);
  unsigned short* WB = (unsigned short*)alloc((size_t)1024 * 768 * 2);
  unsigned short* VB = (unsigned short*)alloc((size_t)1024 * 1024 * 2);
  unsigned short* SIDEB = (unsigned short*)alloc((size_t)1024 * 1056 * 2);
  unsigned short* XGB = (unsigned short*)alloc((size_t)1024 * 128 * 2);
  unsigned short* ZB = (unsigned short*)alloc((size_t)1024 * 1664 * 2);
  unsigned short* X5O = (unsigned short*)alloc((size_t)1024 * 128 * 2);
  unsigned short* WMID = (unsigned short*)alloc((size_t)1024 * 768 * 2);
  unsigned short* VMID = (unsigned short*)alloc((size_t)1024 * 256 * 2);
  unsigned short* SEMID = (unsigned short*)alloc((size_t)1024 * 128 * 2);
  unsigned short* CAT192 = (unsigned short*)alloc((size_t)1024 * 192 * 2);
  unsigned short* CAT128 = (unsigned short*)alloc((size_t)1024 * 128 * 2);
  float* EB = (float*)alloc((size_t)ETOT * 8 * 4);
  float* ALS = (float*)alloc((size_t)NN * 8 * 4);
  float* ALD = (float*)alloc((size_t)NN * 8 * 4);
  float* SB = (float*)alloc((size_t)NN * 8 * 4);
  float* XG = (float*)alloc((size_t)NB * 128 * 4);
  float* DRUG = (float*)alloc((size_t)NB * 64 * 4);
  float* SE = (float*)alloc((size_t)1024 * 64 * 4);
  int* DEG = (int*)alloc((size_t)NN * 4);
  int* ROWPTR = (int*)alloc((size_t)(NN + 1) * 4);
  int* CURSOR = (int*)alloc((size_t)NN * 4);
  int* CSR = (int*)alloc((size_t)ETOT * 4);
  float* PART = (float*)HLIN;  // 8*1024*1664*4 = 54.5MB <= 67MB

  // CSR build
  hipLaunchKernelGGL(fill_i32, dim3((NN + 255) / 256), dim3(256), 0, stream, DEG, 0, NN);
  hipLaunchKernelGGL(count_deg, dim3((ETOT + 255) / 256), dim3(256), 0, stream, ei, DEG);
  hipLaunchKernelGGL(scan_deg, dim3(1), dim3(1024), 0, stream, DEG, ROWPTR);
  hipLaunchKernelGGL(copy_i32, dim3((NN + 255) / 256), dim3(256), 0, stream, ROWPTR, CURSOR, NN);
  hipLaunchKernelGGL(fill_csr, dim3((ETOT + 255) / 256), dim3(256), 0, stream, ei, CURSOR, CSR);

  // weight transposes (WT[Npad][Kp], zero-padded)
  auto launch_tw = [&](const float* W, unsigned short* WT, int K, int N, int Kp, int Npad) {
    dim3 g((Npad + 31) / 32, (Kp + 31) / 32);
    hipLaunchKernelGGL(transpose_w, g, dim3(256), 0, stream, W, WT, K, N, Kp, Npad);
  };
  launch_tw(gW[0], WT1, 109, 768, 128, 768);
  launch_tw(gW[1], WT2, 768, 1024, 768, 1024);
  launch_tw(gW[2], WT3, 1024, 1024, 1024, 1024);
  launch_tw(gW[3], WT4, 1024, 128, 1024, 128);
  launch_tw(z1_W, WTZ, 19127, 1600, 19136, 1664);
  launch_tw(w1_W, WTW1, 750, 750, 768, 768);
  launch_tw(w2_W, WTW2, 750, 64, 768, 128);
  launch_tw(z2_W, WTZ2, 1600, 64, 1664, 128);
  launch_tw(v1_W, WTV1, 1024, 256, 1024, 256);
  launch_tw(v2_W, WTV2, 256, 64, 256, 128);
  launch_tw(x5_W, WTX5, 128, 64, 128, 128);
  launch_tw(x6_W, WTX6, 64, 64, 64, 128);
  launch_tw(agg_W, WTAGG, 192, 64, 192, 128);
  launch_tw(col_W, WTCOL, 128, 64, 128, 128);
  launch_tw(s1_W, WTS1, 1050, 64, 1056, 128);
  launch_tw(s2_W, WTS2, 64, 64, 64, 128);

  // input conversions
  auto launch_conv = [&](const float* in, unsigned short* out, int rowsOut, int Rreal, int C, int Cp) {
    size_t tot = (size_t)rowsOut * Cp;
    hipLaunchKernelGGL(conv_pad, dim3((unsigned)((tot + 255) / 256)), dim3(256), 0, stream,
                       in, out, rowsOut, Rreal, C, Cp);
  };
  launch_conv(x, XB, NN, NN, 109, 128);
  launch_conv(z, ZA, NB, NB, 19127, 19136);
  launch_conv(w, WB, 1024, 1024, 750, 768);
  launch_conv(v, VB, 1024, 1024, 1024, 1024);
  launch_conv(side, SIDEB, 1024, 994, 1050, 1056);

  auto mm = [&](int act, int obf, const unsigned short* A, const unsigned short* BT,
                const float* bias, void* C, int M, int Npad, int Nreal, int K,
                int lda, int ldb, int ldc, int zpad) {
    int gx = Npad / 128;
    int nwg = gx * (M / 128);
    switch (act * 2 + obf) {
      case 0: hipLaunchKernelGGL((gemm_mfma<0,0>), dim3(nwg), dim3(256), 0, stream, A, BT, bias, C, Nreal, K, lda, ldb, ldc, gx, zpad); break;
      case 1: hipLaunchKernelGGL((gemm_mfma<0,1>), dim3(nwg), dim3(256), 0, stream, A, BT, bias, C, Nreal, K, lda, ldb, ldc, gx, zpad); break;
      case 2: hipLaunchKernelGGL((gemm_mfma<1,0>), dim3(nwg), dim3(256), 0, stream, A, BT, bias, C, Nreal, K, lda, ldb, ldc, gx, zpad); break;
      case 3: hipLaunchKernelGGL((gemm_mfma<1,1>), dim3(nwg), dim3(256), 0, stream, A, BT, bias, C, Nreal, K, lda, ldb, ldc, gx, zpad); break;
      case 4: hipLaunchKernelGGL((gemm_mfma<2,0>), dim3(nwg), dim3(256), 0, stream, A, BT, bias, C, Nreal, K, lda, ldb, ldc, gx, zpad); break;
      case 6: hipLaunchKernelGGL((gemm_mfma<3,0>), dim3(nwg), dim3(256), 0, stream, A, BT, bias, C, Nreal, K, lda, ldb, ldc, gx, zpad); break;
      default: break;
    }
  };

  // GAT layers
  const int Hs[4] = {8, 8, 8, 1};
  const int Cs[4] = {96, 128, 128, 128};
  const int Kp[4] = {128, 768, 1024, 1024};
  const unsigned short* WTs[4] = {WT1, WT2, WT3, WT4};
  for (int l = 0; l < 4; ++l) {
    int H = Hs[l], C = Cs[l], F = H * C;
    mm(0, 1, XB, WTs[l], nullptr, HLIN, NN, F, F, Kp[l], Kp[l], Kp[l], F, 0);
    int totNH = NN * H;
    hipLaunchKernelGGL(gat_scores_bf, dim3((totNH + 255) / 256), dim3(256), 0, stream,
                       HLIN, gas[l], gad[l], ALS, ALD, H, C, totNH);
    hipLaunchKernelGGL(fill_f32, dim3((totNH + 255) / 256), dim3(256), 0, stream, SB, 0.f, totNH);
    if (H == 8)
      hipLaunchKernelGGL((edge_attn<8>), dim3((ETOT + 255) / 256), dim3(256), 0, stream, ei, ALS, ALD, EB, SB);
    else
      hipLaunchKernelGGL((edge_attn<1>), dim3((ETOT + 255) / 256), dim3(256), 0, stream, ei, ALS, ALD, EB, SB);
    if (l == 0)
      hipLaunchKernelGGL((gat_agg_v2<768, 96>), dim3(NN * 96 / 256), dim3(256), 0, stream,
                         ROWPTR, CSR, ei, EB, SB, HLIN, gb[l], XB);
    else if (l == 3)
      hipLaunchKernelGGL((gat_agg_v2<128, 128>), dim3(NN * 16 / 256), dim3(256), 0, stream,
                         ROWPTR, CSR, ei, EB, SB, HLIN, gb[l], XB);
    else
      hipLaunchKernelGGL((gat_agg_v2<1024, 128>), dim3(NN * 128 / 256), dim3(256), 0, stream,
                         ROWPTR, CSR, ei, EB, SB, HLIN, gb[l], XB);
  }

  // global max pool -> XG f32 -> XGB bf16
  hipLaunchKernelGGL(fill_f32, dim3((NB * 128 + 255) / 256), dim3(256), 0, stream, XG, -FLT_MAX, NB * 128);
  hipLaunchKernelGGL(pool_scatter_bf, dim3((NN * 128 + 255) / 256), dim3(256), 0, stream, XB, batch, XG, 128, NN * 128);
  launch_conv(XG, XGB, 1024, 1024, 128, 128);

  // z1 split-K (8 slices, f32 partials) + reduce -> ZB bf16
  hipLaunchKernelGGL(gemm_mfma_sk, dim3(832), dim3(256), 0, stream, ZA, WTZ, PART, 19136, 19136, 1664);
  hipLaunchKernelGGL(zred, dim3((1024 * 1664 + 255) / 256), dim3(256), 0, stream, PART, z1_b, ZB);

  // tail chains (all MFMA bf16)
  mm(1, 1, XGB, WTX5, x5_b, X5O, 1024, 128, 64, 128, 128, 128, 128, 1);       // x5
  mm(1, 1, X5O, WTX6, x6_b, CAT192 + 0, 1024, 128, 64, 64, 128, 64, 192, 0);  // x6
  mm(1, 1, WB, WTW1, w1_b, WMID, 1024, 768, 750, 768, 768, 768, 768, 1);      // w1
  mm(1, 1, WMID, WTW2, w2_b, CAT192 + 64, 1024, 128, 64, 768, 768, 768, 192, 0);  // w2
  mm(1, 1, ZB, WTZ2, z2_b, CAT192 + 128, 1024, 128, 64, 1664, 1664, 1664, 192, 0); // z2
  mm(1, 1, VB, WTV1, v1_b, VMID, 1024, 256, 256, 1024, 1024, 1024, 256, 0);   // v1
  mm(1, 1, VMID, WTV2, v2_b, CAT128 + 64, 1024, 128, 64, 256, 256, 256, 128, 0);   // v2
  mm(0, 1, CAT192, WTAGG, agg_b, CAT128 + 0, 1024, 128, 64, 192, 192, 192, 128, 0); // agg
  mm(3, 0, CAT128, WTCOL, col_b, DRUG, 1024, 128, 64, 128, 128, 128, 64, 0);  // col: |tanh|
  mm(1, 1, SIDEB, WTS1, s1_b, SEMID, 1024, 128, 64, 1056, 1056, 1056, 128, 1); // s1
  mm(2, 0, SEMID, WTS2, s2_b, SE, 1024, 128, 64, 64, 128, 64, 64, 0);         // s2: tanh

  // normalize + similarity
  float* outp = (float*)d_out;
  float* DN = outp + (size_t)NB * NSIDE;
  float* SN = DN + (size_t)NB * 64;
  hipLaunchKernelGGL(rownorm, dim3(NB), dim3(64), 0, stream, DRUG, DN);
  hipLaunchKernelGGL(rownorm, dim3(NSIDE), dim3(64), 0, stream, SE, SN);
  hipLaunchKernelGGL(freq_k, dim3((NSIDE + 15) / 16, (NB + 15) / 16), dim3(256), 0, stream,
                     DN, SN, outp, NB, NSIDE);
}

// Round 7
// 1165.375 us; speedup vs baseline: 1.3447x; 1.1947x over previous
//
#include <hip/hip_runtime.h>
#include <math.h>
#include <float.h>

#define E0 131072
#define NN 32768
#define NB 1024
#define NSIDE 994
#define ETOT (E0 + NN)

typedef short bf16x8 __attribute__((ext_vector_type(8)));
typedef unsigned short ushort8 __attribute__((ext_vector_type(8)));
typedef float f32x4 __attribute__((ext_vector_type(4)));

__device__ inline float b2f(unsigned short u) { return __uint_as_float(((unsigned)u) << 16); }
__device__ inline unsigned short f2b(float f) {
  unsigned u = __float_as_uint(f);
  return (unsigned short)((u + 0x7fffu + ((u >> 16) & 1u)) >> 16);
}

__device__ inline void gload_lds16(const void* g, void* l) {
  __builtin_amdgcn_global_load_lds(
      (const __attribute__((address_space(1))) unsigned int*)g,
      (__attribute__((address_space(3))) unsigned int*)l, 16, 0, 0);
}

__global__ void fill_i32(int* p, int v, int n) {
  int i = blockIdx.x * blockDim.x + threadIdx.x;
  if (i < n) p[i] = v;
}
__global__ void copy_i32(const int* s, int* d, int n) {
  int i = blockIdx.x * blockDim.x + threadIdx.x;
  if (i < n) d[i] = s[i];
}

// fp32 [RrealxC] -> bf16 [rowsOut x Cp], zero pad rows >= Rreal and cols >= C
__global__ void conv_pad(const float* __restrict__ in, unsigned short* __restrict__ out,
                         int rowsOut, int Rreal, int C, int Cp) {
  size_t idx = (size_t)blockIdx.x * blockDim.x + threadIdx.x;
  size_t tot = (size_t)rowsOut * Cp;
  if (idx >= tot) return;
  int r = (int)(idx / Cp), c = (int)(idx % Cp);
  out[idx] = (r < Rreal && c < C) ? f2b(in[(size_t)r * C + c]) : (unsigned short)0;
}

// W [K][N] f32 -> WT [Npad][Kp] bf16; rows n in [N,Npad) and cols k in [K,Kp) zeroed
__global__ __launch_bounds__(256) void transpose_w(const float* __restrict__ W,
                                                   unsigned short* __restrict__ WT,
                                                   int K, int N, int Kp, int Npad) {
  __shared__ float t[32][33];
  int k0 = blockIdx.y * 32, n0 = blockIdx.x * 32;
  int tx = threadIdx.x & 31, ty = threadIdx.x >> 5;
  for (int r = ty; r < 32; r += 8) {
    int k = k0 + r, n = n0 + tx;
    t[r][tx] = (k < K && n < N) ? W[(size_t)k * N + n] : 0.f;
  }
  __syncthreads();
  for (int r = ty; r < 32; r += 8) {
    int n = n0 + r, k = k0 + tx;
    if (n < Npad && k < Kp) WT[(size_t)n * Kp + k] = (n < N) ? f2b(t[tx][r]) : (unsigned short)0;
  }
}

// ---------------- CSR build over dst ----------------
__global__ void count_deg(const int* __restrict__ ei, int* deg) {
  int e = blockIdx.x * blockDim.x + threadIdx.x;
  if (e >= ETOT) return;
  int dst = (e < E0) ? ei[E0 + e] : (e - E0);
  atomicAdd(&deg[dst], 1);
}

__global__ void scan_deg(const int* __restrict__ deg, int* rowptr) {
  __shared__ int part[1024];
  int tid = threadIdx.x;
  const int chunk = NN / 1024;  // 32
  int base = tid * chunk;
  int local[chunk];
  int sum = 0;
#pragma unroll
  for (int i = 0; i < chunk; ++i) { local[i] = sum; sum += deg[base + i]; }
  part[tid] = sum;
  __syncthreads();
  for (int off = 1; off < 1024; off <<= 1) {
    int t = (tid >= off) ? part[tid - off] : 0;
    __syncthreads();
    part[tid] += t;
    __syncthreads();
  }
  int offset = part[tid] - sum;
#pragma unroll
  for (int i = 0; i < chunk; ++i) rowptr[base + i] = offset + local[i];
  if (tid == 1023) rowptr[NN] = offset + sum;
}

// stores src per CSR slot (SRCL) and the CSR slot per edge (POS); no eid list needed
__global__ void fill_csr(const int* __restrict__ ei, int* cursor,
                         int* __restrict__ srcl, int* __restrict__ pos) {
  int e = blockIdx.x * blockDim.x + threadIdx.x;
  if (e >= ETOT) return;
  int src, dst;
  if (e < E0) { src = ei[e]; dst = ei[E0 + e]; } else { src = dst = e - E0; }
  int p = atomicAdd(&cursor[dst], 1);
  srcl[p] = src;
  pos[e] = p;
}

// ---------------- bf16 MFMA GEMM ----------------
// 128x128 tile, BK=32, 4 waves; 1D grid (nwg%8==0) with XCD-chunked swizzle.
// LDS: row-major [128][32], linear gload_lds dest. XOR k-slot swizzle (conflict-free,
// coalescing-preserving): stage lane l -> row l>>2, phys chunk (l&3)^((l>>3)&3);
// read slot kq^((r16>>1)&3).
// ACT: 0 none, 1 relu, 2 tanh, 3 abs(tanh). OBF: 1 bf16 out, 0 f32 out.
template <int ACT, int OBF>
__global__ __launch_bounds__(256) void gemm_mfma(
    const unsigned short* __restrict__ A, const unsigned short* __restrict__ BT,
    const float* __restrict__ bias, void* __restrict__ Cp,
    int Nreal, int K, int lda, int ldb, int ldc, int gx, int zpad) {
  __shared__ unsigned short As[128 * 32];
  __shared__ unsigned short Bs[128 * 32];
  const int nwg = gridDim.x;
  const int chunk = nwg >> 3;
  const int bid = blockIdx.x;
  const int swz = (bid & 7) * chunk + (bid >> 3);
  const int bm = (swz / gx) * 128, bn = (swz % gx) * 128;
  const int tid = threadIdx.x;
  const int wv = tid >> 6, lane = tid & 63;
  const int sr = lane >> 2;
  const int sk = ((lane & 3) ^ ((lane >> 3) & 3)) * 8;
  const int r16 = lane & 15, kq = lane >> 4;
  const int slot8 = (kq ^ ((r16 >> 1) & 3)) * 8;
  const int wr = wv >> 1, wc = wv & 1;
  f32x4 acc[4][4];
#pragma unroll
  for (int i = 0; i < 4; ++i)
#pragma unroll
    for (int j = 0; j < 4; ++j) acc[i][j] = (f32x4){0.f, 0.f, 0.f, 0.f};

  const unsigned short* Abase = A + (size_t)bm * lda;
  const unsigned short* Bbase = BT + (size_t)bn * ldb;
  for (int k0 = 0; k0 < K; k0 += 32) {
    gload_lds16(Abase + (size_t)(wv * 16 + sr) * lda + k0 + sk, &As[wv * 512]);
    gload_lds16(Abase + (size_t)(64 + wv * 16 + sr) * lda + k0 + sk, &As[2048 + wv * 512]);
    gload_lds16(Bbase + (size_t)(wv * 16 + sr) * ldb + k0 + sk, &Bs[wv * 512]);
    gload_lds16(Bbase + (size_t)(64 + wv * 16 + sr) * ldb + k0 + sk, &Bs[2048 + wv * 512]);
    __syncthreads();
    bf16x8 af[4], bfr[4];
#pragma unroll
    for (int i = 0; i < 4; ++i)
      af[i] = *(const bf16x8*)&As[(wr * 64 + i * 16 + r16) * 32 + slot8];
#pragma unroll
    for (int j = 0; j < 4; ++j)
      bfr[j] = *(const bf16x8*)&Bs[(wc * 64 + j * 16 + r16) * 32 + slot8];
#pragma unroll
    for (int i = 0; i < 4; ++i)
#pragma unroll
      for (int j = 0; j < 4; ++j)
        acc[i][j] = __builtin_amdgcn_mfma_f32_16x16x32_bf16(af[i], bfr[j], acc[i][j], 0, 0, 0);
    __syncthreads();
  }
#pragma unroll
  for (int i = 0; i < 4; ++i) {
    int row = bm + wr * 64 + i * 16 + kq * 4;
#pragma unroll
    for (int j = 0; j < 4; ++j) {
      int col = bn + wc * 64 + j * 16 + r16;
      bool real = col < Nreal;
      if (!real && !zpad) continue;
      float bv = (bias && real) ? bias[col] : 0.f;
#pragma unroll
      for (int r = 0; r < 4; ++r) {
        float v = acc[i][j][r] + bv;
        if (ACT == 1) v = v > 0.f ? v : 0.f;
        else if (ACT == 2) v = tanhf(v);
        else if (ACT == 3) v = fabsf(tanhf(v));
        if (!real) v = 0.f;
        if (OBF) ((unsigned short*)Cp)[(size_t)(row + r) * ldc + col] = f2b(v);
        else ((float*)Cp)[(size_t)(row + r) * ldc + col] = v;
      }
    }
  }
}

// ---------------- split-K MFMA GEMM for z1 ----------------
// M=1024, Npad=1664 (Nreal 1600), K=19136 (598 k-steps). 16 K-slices (38/37 steps).
// grid = 1664 (6.5 WGs/CU); XCD-chunk: each XCD owns 2 whole K-slices (L2 locality).
// f32 partials to PART[s][1024][1664] (109MB, aliased on dead HLIN+XB region).
__global__ __launch_bounds__(256) void gemm_mfma_sk(
    const unsigned short* __restrict__ A, const unsigned short* __restrict__ BT,
    float* __restrict__ PART, int lda, int ldb, int ldc) {
  __shared__ unsigned short As[128 * 32];
  __shared__ unsigned short Bs[128 * 32];
  const int bid = blockIdx.x;
  const int swz = (bid & 7) * 208 + (bid >> 3);  // nwg=1664, chunk=208
  const int s = swz / 104;                        // K-slice 0..15
  const int pos = swz - s * 104;                  // tile 0..103
  const int bm = (pos / 13) * 128, bn = (pos % 13) * 128;
  const int base = s * 37 + (s < 6 ? s : 6);
  const int nsteps = 37 + (s < 6 ? 1 : 0);
  const int tid = threadIdx.x;
  const int wv = tid >> 6, lane = tid & 63;
  const int sr = lane >> 2;
  const int sk = ((lane & 3) ^ ((lane >> 3) & 3)) * 8;
  const int r16 = lane & 15, kq = lane >> 4;
  const int slot8 = (kq ^ ((r16 >> 1) & 3)) * 8;
  const int wr = wv >> 1, wc = wv & 1;
  f32x4 acc[4][4];
#pragma unroll
  for (int i = 0; i < 4; ++i)
#pragma unroll
    for (int j = 0; j < 4; ++j) acc[i][j] = (f32x4){0.f, 0.f, 0.f, 0.f};

  const unsigned short* Abase = A + (size_t)bm * lda;
  const unsigned short* Bbase = BT + (size_t)bn * ldb;
  for (int ks = 0; ks < nsteps; ++ks) {
    int k0 = (base + ks) * 32;
    gload_lds16(Abase + (size_t)(wv * 16 + sr) * lda + k0 + sk, &As[wv * 512]);
    gload_lds16(Abase + (size_t)(64 + wv * 16 + sr) * lda + k0 + sk, &As[2048 + wv * 512]);
    gload_lds16(Bbase + (size_t)(wv * 16 + sr) * ldb + k0 + sk, &Bs[wv * 512]);
    gload_lds16(Bbase + (size_t)(64 + wv * 16 + sr) * ldb + k0 + sk, &Bs[2048 + wv * 512]);
    __syncthreads();
    bf16x8 af[4], bfr[4];
#pragma unroll
    for (int i = 0; i < 4; ++i)
      af[i] = *(const bf16x8*)&As[(wr * 64 + i * 16 + r16) * 32 + slot8];
#pragma unroll
    for (int j = 0; j < 4; ++j)
      bfr[j] = *(const bf16x8*)&Bs[(wc * 64 + j * 16 + r16) * 32 + slot8];
#pragma unroll
    for (int i = 0; i < 4; ++i)
#pragma unroll
      for (int j = 0; j < 4; ++j)
        acc[i][j] = __builtin_amdgcn_mfma_f32_16x16x32_bf16(af[i], bfr[j], acc[i][j], 0, 0, 0);
    __syncthreads();
  }
  float* out = PART + (size_t)s * 1024 * ldc;
#pragma unroll
  for (int i = 0; i < 4; ++i) {
    int row = bm + wr * 64 + i * 16 + kq * 4;
#pragma unroll
    for (int j = 0; j < 4; ++j) {
      int col = bn + wc * 64 + j * 16 + r16;
      if (col >= 1600) continue;
#pragma unroll
      for (int r = 0; r < 4; ++r)
        out[(size_t)(row + r) * ldc + col] = acc[i][j][r];
    }
  }
}

// reduce 16 f32 K-slice partials + bias + relu -> ZB bf16 [1024][1664], pad cols zeroed
__global__ void zred(const float* __restrict__ PART, const float* __restrict__ bias,
                     unsigned short* __restrict__ ZB) {
  int idx = blockIdx.x * blockDim.x + threadIdx.x;
  if (idx >= 1024 * 1664) return;
  int c = idx % 1664;
  if (c >= 1600) { ZB[idx] = 0; return; }
  float s = 0.f;
#pragma unroll
  for (int k = 0; k < 16; ++k) s += PART[(size_t)k * 1024 * 1664 + idx];
  s += bias[c];
  ZB[idx] = f2b(s > 0.f ? s : 0.f);
}

// ---------------- GAT pieces ----------------
__global__ void gat_scores_bf(const unsigned short* __restrict__ hlin,
                              const float* __restrict__ a_s, const float* __restrict__ a_d,
                              float* __restrict__ als, float* __restrict__ ald,
                              int H, int C, int tot) {
  int idx = blockIdx.x * blockDim.x + threadIdx.x;
  if (idx >= tot) return;
  int n = idx / H, h = idx - n * H;
  const unsigned short* base = hlin + (size_t)n * H * C + (size_t)h * C;
  const float* as = a_s + h * C;
  const float* ad = a_d + h * C;
  float ss = 0.f, sd = 0.f;
  for (int c = 0; c < C; c += 8) {
    ushort8 v = *(const ushort8*)(base + c);
#pragma unroll
    for (int t = 0; t < 8; ++t) {
      float f = b2f(v[t]);
      ss = fmaf(f, as[c + t], ss);
      sd = fmaf(f, ad[c + t], sd);
    }
  }
  als[idx] = ss;
  ald[idx] = sd;
}

// attention (no atomics): p = exp(leaky_relu(als[src]+ald[dst])) written to CSR-ordered EBS
template <int H>
__global__ void edge_attn(const int* __restrict__ ei, const float* __restrict__ als,
                          const float* __restrict__ ald, const int* __restrict__ pos,
                          float* __restrict__ ebs) {
  int e = blockIdx.x * blockDim.x + threadIdx.x;
  if (e >= ETOT) return;
  int src, dst;
  if (e < E0) { src = ei[e]; dst = ei[E0 + e]; } else { src = dst = e - E0; }
  int p = pos[e];
  if (H == 8) {
    float4 s0 = *(const float4*)(als + src * 8);
    float4 s1 = *(const float4*)(als + src * 8 + 4);
    float4 d0 = *(const float4*)(ald + dst * 8);
    float4 d1 = *(const float4*)(ald + dst * 8 + 4);
    float ev[8] = {s0.x + d0.x, s0.y + d0.y, s0.z + d0.z, s0.w + d0.w,
                   s1.x + d1.x, s1.y + d1.y, s1.z + d1.z, s1.w + d1.w};
#pragma unroll
    for (int h = 0; h < 8; ++h) {
      float v = ev[h];
      v = (v >= 0.f) ? v : 0.2f * v;
      ebs[(size_t)p * 8 + h] = __expf(v);
    }
  } else {
    float v = als[src] + ald[dst];
    v = (v >= 0.f) ? v : 0.2f * v;
    ebs[p] = __expf(v);
  }
}

// aggregate: thread = (node, 8-ch chunk). Contiguous srcl/ebs reads, inline softmax denom.
template <int F, int C>
__global__ __launch_bounds__(256) void gat_agg_v3(
    const int* __restrict__ rowptr, const float* __restrict__ ebs,
    const int* __restrict__ srcl, const unsigned short* __restrict__ hlin,
    const float* __restrict__ bias, unsigned short* __restrict__ out) {
  constexpr int H = F / C;
  constexpr int CPN = F / 8;
  int gidx = blockIdx.x * 256 + threadIdx.x;
  if (gidx >= NN * CPN) return;
  int node = gidx / CPN;
  int c0 = (gidx - node * CPN) * 8;
  int h = c0 / C;
  float s = 0.f;
  float acc[8] = {0.f, 0.f, 0.f, 0.f, 0.f, 0.f, 0.f, 0.f};
  int start = rowptr[node], end = rowptr[node + 1];
  for (int k = start; k < end; ++k) {
    int src = srcl[k];
    float p = ebs[(size_t)k * H + h];
    s += p;
    ushort8 hv = *(const ushort8*)(hlin + (size_t)src * F + c0);
#pragma unroll
    for (int t = 0; t < 8; ++t) acc[t] = fmaf(p, b2f(hv[t]), acc[t]);
  }
  float inv_s = 1.f / s;
  ushort8 o;
#pragma unroll
  for (int t = 0; t < 8; ++t) {
    float val = acc[t] * inv_s + bias[c0 + t];
    o[t] = f2b(val > 0.f ? val : 0.f);
  }
  *(ushort8*)(out + (size_t)node * F + c0) = o;
}

// per-graph max pool (32 consecutive nodes/graph), no atomics, bf16 out (exact)
__global__ void pool_max(const unsigned short* __restrict__ xb,
                         unsigned short* __restrict__ xgb) {
  int g = blockIdx.x, c = threadIdx.x;  // 128 threads
  const unsigned short* base = xb + (size_t)g * 32 * 128 + c;
  float m = -FLT_MAX;
#pragma unroll 8
  for (int n = 0; n < 32; ++n) m = fmaxf(m, b2f(base[n * 128]));
  xgb[g * 128 + c] = f2b(m);
}

__global__ void rownorm(const float* __restrict__ in, float* __restrict__ outp) {
  int r = blockIdx.x, lane = threadIdx.x;
  float v = in[r * 64 + lane];
  float ss = v * v;
#pragma unroll
  for (int off = 1; off < 64; off <<= 1) ss += __shfl_xor(ss, off);
  float nrm = fmaxf(sqrtf(ss), 1e-12f);
  outp[r * 64 + lane] = v / nrm;
}

__global__ __launch_bounds__(256) void freq_k(const float* __restrict__ dn,
                                              const float* __restrict__ sn,
                                              float* __restrict__ C, int M, int N) {
  __shared__ float As[16][64];
  __shared__ float Bs[16][65];
  int tid = threadIdx.x;
  int tx = tid & 15, ty = tid >> 4;
  int bi = blockIdx.y * 16, bj = blockIdx.x * 16;
#pragma unroll
  for (int t = 0; t < 4; ++t) {
    int idx = tid * 4 + t;
    int r = idx >> 6, c = idx & 63;
    As[r][c] = (bi + r < M) ? dn[(bi + r) * 64 + c] : 0.f;
    Bs[r][c] = (bj + r < N) ? sn[(bj + r) * 64 + c] : 0.f;
  }
  __syncthreads();
  float acc = 0.f;
#pragma unroll
  for (int k = 0; k < 64; ++k) acc = fmaf(As[ty][k], Bs[tx][k], acc);
  if (bi + ty < M && bj + tx < N) C[(size_t)(bi + ty) * N + (bj + tx)] = 5.f * acc;
}

// ---------------- launch ----------------
extern "C" void kernel_launch(void* const* d_in, const int* in_sizes, int n_in,
                              void* d_out, int out_size, void* d_ws, size_t ws_size,
                              hipStream_t stream) {
  const float* x = (const float*)d_in[0];
  const int* ei = (const int*)d_in[1];
  const int* batch = (const int*)d_in[2];
  const float* w = (const float*)d_in[3];
  const float* z = (const float*)d_in[4];
  const float* v = (const float*)d_in[5];
  const float* side = (const float*)d_in[6];
  const float* gW[4] = {(const float*)d_in[7], (const float*)d_in[11],
                        (const float*)d_in[15], (const float*)d_in[19]};
  const float* gas[4] = {(const float*)d_in[8], (const float*)d_in[12],
                         (const float*)d_in[16], (const float*)d_in[20]};
  const float* gad[4] = {(const float*)d_in[9], (const float*)d_in[13],
                         (const float*)d_in[17], (const float*)d_in[21]};
  const float* gb[4] = {(const float*)d_in[10], (const float*)d_in[14],
                        (const float*)d_in[18], (const float*)d_in[22]};
  const float* x5_W = (const float*)d_in[23]; const float* x5_b = (const float*)d_in[24];
  const float* x6_W = (const float*)d_in[25]; const float* x6_b = (const float*)d_in[26];
  const float* w1_W = (const float*)d_in[27]; const float* w1_b = (const float*)d_in[28];
  const float* w2_W = (const float*)d_in[29]; const float* w2_b = (const float*)d_in[30];
  const float* z1_W = (const float*)d_in[31]; const float* z1_b = (const float*)d_in[32];
  const float* z2_W = (const float*)d_in[33]; const float* z2_b = (const float*)d_in[34];
  const float* v1_W = (const float*)d_in[35]; const float* v1_b = (const float*)d_in[36];
  const float* v2_W = (const float*)d_in[37]; const float* v2_b = (const float*)d_in[38];
  const float* agg_W = (const float*)d_in[39]; const float* agg_b = (const float*)d_in[40];
  const float* col_W = (const float*)d_in[41]; const float* col_b = (const float*)d_in[42];
  const float* s1_W = (const float*)d_in[43]; const float* s1_b = (const float*)d_in[44];
  const float* s2_W = (const float*)d_in[45]; const float* s2_b = (const float*)d_in[46];

  char* wsb = (char*)d_ws;
  size_t off = 0;
  auto alloc = [&](size_t bytes) {
    void* p = wsb + off;
    off = (off + bytes + 255) & ~(size_t)255;
    return p;
  };
  // HLIN and XB are allocated first and contiguously; after the GAT stage both are
  // dead and the 128MB region is reused as PART (16 x 1024 x 1664 f32 = 109MB).
  unsigned short* HLIN = (unsigned short*)alloc((size_t)NN * 1024 * 2);
  unsigned short* XB = (unsigned short*)alloc((size_t)NN * 1024 * 2);
  unsigned short* WTZ = (unsigned short*)alloc((size_t)1664 * 19136 * 2);
  unsigned short* ZA = (unsigned short*)alloc((size_t)1024 * 19136 * 2);
  unsigned short* WT1 = (unsigned short*)alloc((size_t)768 * 128 * 2);
  unsigned short* WT2 = (unsigned short*)alloc((size_t)1024 * 768 * 2);
  unsigned short* WT3 = (unsigned short*)alloc((size_t)1024 * 1024 * 2);
  unsigned short* WT4 = (unsigned short*)alloc((size_t)128 * 1024 * 2);
  unsigned short* WTW1 = (unsigned short*)alloc((size_t)768 * 768 * 2);
  unsigned short* WTW2 = (unsigned short*)alloc((size_t)128 * 768 * 2);
  unsigned short* WTZ2 = (unsigned short*)alloc((size_t)128 * 1664 * 2);
  unsigned short* WTV1 = (unsigned short*)alloc((size_t)256 * 1024 * 2);
  unsigned short* WTV2 = (unsigned short*)alloc((size_t)128 * 256 * 2);
  unsigned short* WTX5 = (unsigned short*)alloc((size_t)128 * 128 * 2);
  unsigned short* WTX6 = (unsigned short*)alloc((size_t)128 * 64 * 2);
  unsigned short* WTAGG = (unsigned short*)alloc((size_t)128 * 192 * 2);
  unsigned short* WTCOL = (unsigned short*)alloc((size_t)128 * 128 * 2);
  unsigned short* WTS1 = (unsigned short*)alloc((size_t)128 * 1056 * 2);
  unsigned short* WTS2 = (unsigned short*)alloc((size_t)128 * 64 * 2);
  unsigned short* WB = (unsigned short*)alloc((size_t)1024 * 768 * 2);
  unsigned short* VB = (unsigned short*)alloc((size_t)1024 * 1024 * 2);
  unsigned short* SIDEB = (unsigned short*)alloc((size_t)1024 * 1056 * 2);
  unsigned short* XGB = (unsigned short*)alloc((size_t)1024 * 128 * 2);
  unsigned short* ZB = (unsigned short*)alloc((size_t)1024 * 1664 * 2);
  unsigned short* X5O = (unsigned short*)alloc((size_t)1024 * 128 * 2);
  unsigned short* WMID = (unsigned short*)alloc((size_t)1024 * 768 * 2);
  unsigned short* VMID = (unsigned short*)alloc((size_t)1024 * 256 * 2);
  unsigned short* SEMID = (unsigned short*)alloc((size_t)1024 * 128 * 2);
  unsigned short* CAT192 = (unsigned short*)alloc((size_t)1024 * 192 * 2);
  unsigned short* CAT128 = (unsigned short*)alloc((size_t)1024 * 128 * 2);
  float* EBS = (float*)alloc((size_t)ETOT * 8 * 4);
  float* ALS = (float*)alloc((size_t)NN * 8 * 4);
  float* ALD = (float*)alloc((size_t)NN * 8 * 4);
  float* DRUG = (float*)alloc((size_t)NB * 64 * 4);
  float* SE = (float*)alloc((size_t)1024 * 64 * 4);
  int* DEG = (int*)alloc((size_t)NN * 4);
  int* ROWPTR = (int*)alloc((size_t)(NN + 1) * 4);
  int* CURSOR = (int*)alloc((size_t)NN * 4);
  int* SRCL = (int*)alloc((size_t)ETOT * 4);
  int* POS = (int*)alloc((size_t)ETOT * 4);
  float* PART = (float*)HLIN;  // 109MB over HLIN+XB (both dead by z1 time)

  // CSR build
  hipLaunchKernelGGL(fill_i32, dim3((NN + 255) / 256), dim3(256), 0, stream, DEG, 0, NN);
  hipLaunchKernelGGL(count_deg, dim3((ETOT + 255) / 256), dim3(256), 0, stream, ei, DEG);
  hipLaunchKernelGGL(scan_deg, dim3(1), dim3(1024), 0, stream, DEG, ROWPTR);
  hipLaunchKernelGGL(copy_i32, dim3((NN + 255) / 256), dim3(256), 0, stream, ROWPTR, CURSOR, NN);
  hipLaunchKernelGGL(fill_csr, dim3((ETOT + 255) / 256), dim3(256), 0, stream, ei, CURSOR, SRCL, POS);

  // weight transposes (WT[Npad][Kp], zero-padded)
  auto launch_tw = [&](const float* W, unsigned short* WT, int K, int N, int Kp, int Npad) {
    dim3 g((Npad + 31) / 32, (Kp + 31) / 32);
    hipLaunchKernelGGL(transpose_w, g, dim3(256), 0, stream, W, WT, K, N, Kp, Npad);
  };
  launch_tw(gW[0], WT1, 109, 768, 128, 768);
  launch_tw(gW[1], WT2, 768, 1024, 768, 1024);
  launch_tw(gW[2], WT3, 1024, 1024, 1024, 1024);
  launch_tw(gW[3], WT4, 1024, 128, 1024, 128);
  launch_tw(z1_W, WTZ, 19127, 1600, 19136, 1664);
  launch_tw(w1_W, WTW1, 750, 750, 768, 768);
  launch_tw(w2_W, WTW2, 750, 64, 768, 128);
  launch_tw(z2_W, WTZ2, 1600, 64, 1664, 128);
  launch_tw(v1_W, WTV1, 1024, 256, 1024, 256);
  launch_tw(v2_W, WTV2, 256, 64, 256, 128);
  launch_tw(x5_W, WTX5, 128, 64, 128, 128);
  launch_tw(x6_W, WTX6, 64, 64, 64, 128);
  launch_tw(agg_W, WTAGG, 192, 64, 192, 128);
  launch_tw(col_W, WTCOL, 128, 64, 128, 128);
  launch_tw(s1_W, WTS1, 1050, 64, 1056, 128);
  launch_tw(s2_W, WTS2, 64, 64, 64, 128);

  // input conversions
  auto launch_conv = [&](const float* in, unsigned short* out, int rowsOut, int Rreal, int C, int Cp) {
    size_t tot = (size_t)rowsOut * Cp;
    hipLaunchKernelGGL(conv_pad, dim3((unsigned)((tot + 255) / 256)), dim3(256), 0, stream,
                       in, out, rowsOut, Rreal, C, Cp);
  };
  launch_conv(x, XB, NN, NN, 109, 128);
  launch_conv(z, ZA, NB, NB, 19127, 19136);
  launch_conv(w, WB, 1024, 1024, 750, 768);
  launch_conv(v, VB, 1024, 1024, 1024, 1024);
  launch_conv(side, SIDEB, 1024, 994, 1050, 1056);

  auto mm = [&](int act, int obf, const unsigned short* A, const unsigned short* BT,
                const float* bias, void* C, int M, int Npad, int Nreal, int K,
                int lda, int ldb, int ldc, int zpad) {
    int gx = Npad / 128;
    int nwg = gx * (M / 128);
    switch (act * 2 + obf) {
      case 0: hipLaunchKernelGGL((gemm_mfma<0,0>), dim3(nwg), dim3(256), 0, stream, A, BT, bias, C, Nreal, K, lda, ldb, ldc, gx, zpad); break;
      case 1: hipLaunchKernelGGL((gemm_mfma<0,1>), dim3(nwg), dim3(256), 0, stream, A, BT, bias, C, Nreal, K, lda, ldb, ldc, gx, zpad); break;
      case 2: hipLaunchKernelGGL((gemm_mfma<1,0>), dim3(nwg), dim3(256), 0, stream, A, BT, bias, C, Nreal, K, lda, ldb, ldc, gx, zpad); break;
      case 3: hipLaunchKernelGGL((gemm_mfma<1,1>), dim3(nwg), dim3(256), 0, stream, A, BT, bias, C, Nreal, K, lda, ldb, ldc, gx, zpad); break;
      case 4: hipLaunchKernelGGL((gemm_mfma<2,0>), dim3(nwg), dim3(256), 0, stream, A, BT, bias, C, Nreal, K, lda, ldb, ldc, gx, zpad); break;
      case 6: hipLaunchKernelGGL((gemm_mfma<3,0>), dim3(nwg), dim3(256), 0, stream, A, BT, bias, C, Nreal, K, lda, ldb, ldc, gx, zpad); break;
      default: break;
    }
  };

  // GAT layers
  const int Hs[4] = {8, 8, 8, 1};
  const int Kp[4] = {128, 768, 1024, 1024};
  const unsigned short* WTs[4] = {WT1, WT2, WT3, WT4};
  const int Fs[4] = {768, 1024, 1024, 128};
  for (int l = 0; l < 4; ++l) {
    int H = Hs[l], F = Fs[l], C = F / H;
    mm(0, 1, XB, WTs[l], nullptr, HLIN, NN, F, F, Kp[l], Kp[l], Kp[l], F, 0);
    int totNH = NN * H;
    hipLaunchKernelGGL(gat_scores_bf, dim3((totNH + 255) / 256), dim3(256), 0, stream,
                       HLIN, gas[l], gad[l], ALS, ALD, H, C, totNH);
    if (H == 8)
      hipLaunchKernelGGL((edge_attn<8>), dim3((ETOT + 255) / 256), dim3(256), 0, stream, ei, ALS, ALD, POS, EBS);
    else
      hipLaunchKernelGGL((edge_attn<1>), dim3((ETOT + 255) / 256), dim3(256), 0, stream, ei, ALS, ALD, POS, EBS);
    if (l == 0)
      hipLaunchKernelGGL((gat_agg_v3<768, 96>), dim3(NN * 96 / 256), dim3(256), 0, stream,
                         ROWPTR, EBS, SRCL, HLIN, gb[l], XB);
    else if (l == 3)
      hipLaunchKernelGGL((gat_agg_v3<128, 128>), dim3(NN * 16 / 256), dim3(256), 0, stream,
                         ROWPTR, EBS, SRCL, HLIN, gb[l], XB);
    else
      hipLaunchKernelGGL((gat_agg_v3<1024, 128>), dim3(NN * 128 / 256), dim3(256), 0, stream,
                         ROWPTR, EBS, SRCL, HLIN, gb[l], XB);
  }

  // global max pool (32 nodes/graph, consecutive) -> XGB bf16
  hipLaunchKernelGGL(pool_max, dim3(NB), dim3(128), 0, stream, XB, XGB);

  // z1 split-K (16 slices, f32 partials over dead HLIN+XB) + reduce -> ZB bf16
  hipLaunchKernelGGL(gemm_mfma_sk, dim3(1664), dim3(256), 0, stream, ZA, WTZ, PART, 19136, 19136, 1664);
  hipLaunchKernelGGL(zred, dim3((1024 * 1664 + 255) / 256), dim3(256), 0, stream, PART, z1_b, ZB);

  // tail chains (all MFMA bf16)
  mm(1, 1, XGB, WTX5, x5_b, X5O, 1024, 128, 64, 128, 128, 128, 128, 1);       // x5
  mm(1, 1, X5O, WTX6, x6_b, CAT192 + 0, 1024, 128, 64, 64, 128, 64, 192, 0);  // x6
  mm(1, 1, WB, WTW1, w1_b, WMID, 1024, 768, 750, 768, 768, 768, 768, 1);      // w1
  mm(1, 1, WMID, WTW2, w2_b, CAT192 + 64, 1024, 128, 64, 768, 768, 768, 192, 0);  // w2
  mm(1, 1, ZB, WTZ2, z2_b, CAT192 + 128, 1024, 128, 64, 1664, 1664, 1664, 192, 0); // z2
  mm(1, 1, VB, WTV1, v1_b, VMID, 1024, 256, 256, 1024, 1024, 1024, 256, 0);   // v1
  mm(1, 1, VMID, WTV2, v2_b, CAT128 + 64, 1024, 128, 64, 256, 256, 256, 128, 0);   // v2
  mm(0, 1, CAT192, WTAGG, agg_b, CAT128 + 0, 1024, 128, 64, 192, 192, 192, 128, 0); // agg
  mm(3, 0, CAT128, WTCOL, col_b, DRUG, 1024, 128, 64, 128, 128, 128, 64, 0);  // col: |tanh|
  mm(1, 1, SIDEB, WTS1, s1_b, SEMID, 1024, 128, 64, 1056, 1056, 1056, 128, 1); // s1
  mm(2, 0, SEMID, WTS2, s2_b, SE, 1024, 128, 64, 64, 128, 64, 64, 0);         // s2: tanh

  // normalize + similarity
  float* outp = (float*)d_out;
  float* DN = outp + (size_t)NB * NSIDE;
  float* SN = DN + (size_t)NB * 64;
  hipLaunchKernelGGL(rownorm, dim3(NB), dim3(64), 0, stream, DRUG, DN);
  hipLaunchKernelGGL(rownorm, dim3(NSIDE), dim3(64), 0, stream, SE, SN);
  hipLaunchKernelGGL(freq_k, dim3((NSIDE + 15) / 16, (NB + 15) / 16), dim3(256), 0, stream,
                     DN, SN, outp, NB, NSIDE);
}

// Round 8
// 1035.347 us; speedup vs baseline: 1.5136x; 1.1256x over previous
//
#include <hip/hip_runtime.h>
#include <math.h>
#include <float.h>

#define E0 131072
#define NN 32768
#define NB 1024
#define NSIDE 994
#define ETOT (E0 + NN)

typedef short bf16x8 __attribute__((ext_vector_type(8)));
typedef unsigned short ushort8 __attribute__((ext_vector_type(8)));
typedef float f32x4 __attribute__((ext_vector_type(4)));

__device__ inline float b2f(unsigned short u) { return __uint_as_float(((unsigned)u) << 16); }
__device__ inline unsigned short f2b(float f) {
  unsigned u = __float_as_uint(f);
  return (unsigned short)((u + 0x7fffu + ((u >> 16) & 1u)) >> 16);
}

__device__ inline void gload_lds16(const void* g, void* l) {
  __builtin_amdgcn_global_load_lds(
      (const __attribute__((address_space(1))) unsigned int*)g,
      (__attribute__((address_space(3))) unsigned int*)l, 16, 0, 0);
}

__global__ void fill_i32(int* p, int v, int n) {
  int i = blockIdx.x * blockDim.x + threadIdx.x;
  if (i < n) p[i] = v;
}

// ---------------- batched fp32 -> bf16 conversion with padding ----------------
struct CDesc { const float* in; unsigned short* out; int rowsOut, Rreal, C, Cp, wg_end; };
struct CBatch { CDesc d[5]; };
__global__ void conv_batch(CBatch cb) {
  int bid = blockIdx.x;
  int di = 0;
  while (bid >= cb.d[di].wg_end) ++di;
  const CDesc& g = cb.d[di];
  int rel = bid - (di ? cb.d[di - 1].wg_end : 0);
  size_t idx = (size_t)rel * 256 + threadIdx.x;
  size_t tot = (size_t)g.rowsOut * g.Cp;
  if (idx >= tot) return;
  int r = (int)(idx / g.Cp), c = (int)(idx % g.Cp);
  g.out[idx] = (r < g.Rreal && c < g.C) ? f2b(g.in[(size_t)r * g.C + c]) : (unsigned short)0;
}

// ---------------- batched transpose: W [K][N] f32 -> WT [Npad][Kp] bf16 ----------------
struct TDesc { const float* W; unsigned short* WT; int K, N, Kp, Npad, gx, wg_end; };
struct TBatch { TDesc d[16]; };
__global__ __launch_bounds__(256) void transpose_batch(TBatch tb) {
  __shared__ float t[32][33];
  int bid = blockIdx.x;
  int di = 0;
  while (bid >= tb.d[di].wg_end) ++di;
  const TDesc& g = tb.d[di];
  int rel = bid - (di ? tb.d[di - 1].wg_end : 0);
  int n0 = (rel % g.gx) * 32, k0 = (rel / g.gx) * 32;
  int tx = threadIdx.x & 31, ty = threadIdx.x >> 5;
  for (int r = ty; r < 32; r += 8) {
    int k = k0 + r, n = n0 + tx;
    t[r][tx] = (k < g.K && n < g.N) ? g.W[(size_t)k * g.N + n] : 0.f;
  }
  __syncthreads();
  for (int r = ty; r < 32; r += 8) {
    int n = n0 + r, k = k0 + tx;
    if (n < g.Npad && k < g.Kp)
      g.WT[(size_t)n * g.Kp + k] = (n < g.N) ? f2b(t[tx][r]) : (unsigned short)0;
  }
}

// ---------------- CSR build over dst ----------------
__global__ void count_deg(const int* __restrict__ ei, int* deg) {
  int e = blockIdx.x * blockDim.x + threadIdx.x;
  if (e >= ETOT) return;
  int dst = (e < E0) ? ei[E0 + e] : (e - E0);
  atomicAdd(&deg[dst], 1);
}

__global__ void scan_deg(const int* __restrict__ deg, int* rowptr, int* cursor) {
  __shared__ int part[1024];
  int tid = threadIdx.x;
  const int chunk = NN / 1024;  // 32
  int base = tid * chunk;
  int local[chunk];
  int sum = 0;
#pragma unroll
  for (int i = 0; i < chunk; ++i) { local[i] = sum; sum += deg[base + i]; }
  part[tid] = sum;
  __syncthreads();
  for (int off = 1; off < 1024; off <<= 1) {
    int t = (tid >= off) ? part[tid - off] : 0;
    __syncthreads();
    part[tid] += t;
    __syncthreads();
  }
  int offset = part[tid] - sum;
#pragma unroll
  for (int i = 0; i < chunk; ++i) {
    int v = offset + local[i];
    rowptr[base + i] = v;
    cursor[base + i] = v;
  }
  if (tid == 1023) rowptr[NN] = offset + sum;
}

__global__ void fill_csr(const int* __restrict__ ei, int* cursor,
                         int* __restrict__ srcl, int* __restrict__ pos) {
  int e = blockIdx.x * blockDim.x + threadIdx.x;
  if (e >= ETOT) return;
  int src, dst;
  if (e < E0) { src = ei[e]; dst = ei[E0 + e]; } else { src = dst = e - E0; }
  int p = atomicAdd(&cursor[dst], 1);
  srcl[p] = src;
  pos[e] = p;
}

// ---------------- bf16 MFMA GEMM (templated, XCD swizzle) for big GAT GEMMs ----------------
// 128x128 tile, BK=32, 4 waves. XOR k-slot swizzle (conflict-free, coalescing-preserving).
template <int ACT, int OBF>
__global__ __launch_bounds__(256) void gemm_mfma(
    const unsigned short* __restrict__ A, const unsigned short* __restrict__ BT,
    const float* __restrict__ bias, void* __restrict__ Cp,
    int Nreal, int K, int lda, int ldb, int ldc, int gx, int zpad) {
  __shared__ unsigned short As[128 * 32];
  __shared__ unsigned short Bs[128 * 32];
  const int nwg = gridDim.x;
  const int chunk = nwg >> 3;
  const int bid = blockIdx.x;
  const int swz = (bid & 7) * chunk + (bid >> 3);
  const int bm = (swz / gx) * 128, bn = (swz % gx) * 128;
  const int tid = threadIdx.x;
  const int wv = tid >> 6, lane = tid & 63;
  const int sr = lane >> 2;
  const int sk = ((lane & 3) ^ ((lane >> 3) & 3)) * 8;
  const int r16 = lane & 15, kq = lane >> 4;
  const int slot8 = (kq ^ ((r16 >> 1) & 3)) * 8;
  const int wr = wv >> 1, wc = wv & 1;
  f32x4 acc[4][4];
#pragma unroll
  for (int i = 0; i < 4; ++i)
#pragma unroll
    for (int j = 0; j < 4; ++j) acc[i][j] = (f32x4){0.f, 0.f, 0.f, 0.f};

  const unsigned short* Abase = A + (size_t)bm * lda;
  const unsigned short* Bbase = BT + (size_t)bn * ldb;
  for (int k0 = 0; k0 < K; k0 += 32) {
    gload_lds16(Abase + (size_t)(wv * 16 + sr) * lda + k0 + sk, &As[wv * 512]);
    gload_lds16(Abase + (size_t)(64 + wv * 16 + sr) * lda + k0 + sk, &As[2048 + wv * 512]);
    gload_lds16(Bbase + (size_t)(wv * 16 + sr) * ldb + k0 + sk, &Bs[wv * 512]);
    gload_lds16(Bbase + (size_t)(64 + wv * 16 + sr) * ldb + k0 + sk, &Bs[2048 + wv * 512]);
    __syncthreads();
    bf16x8 af[4], bfr[4];
#pragma unroll
    for (int i = 0; i < 4; ++i)
      af[i] = *(const bf16x8*)&As[(wr * 64 + i * 16 + r16) * 32 + slot8];
#pragma unroll
    for (int j = 0; j < 4; ++j)
      bfr[j] = *(const bf16x8*)&Bs[(wc * 64 + j * 16 + r16) * 32 + slot8];
#pragma unroll
    for (int i = 0; i < 4; ++i)
#pragma unroll
      for (int j = 0; j < 4; ++j)
        acc[i][j] = __builtin_amdgcn_mfma_f32_16x16x32_bf16(af[i], bfr[j], acc[i][j], 0, 0, 0);
    __syncthreads();
  }
#pragma unroll
  for (int i = 0; i < 4; ++i) {
    int row = bm + wr * 64 + i * 16 + kq * 4;
#pragma unroll
    for (int j = 0; j < 4; ++j) {
      int col = bn + wc * 64 + j * 16 + r16;
      bool real = col < Nreal;
      if (!real && !zpad) continue;
      float bv = (bias && real) ? bias[col] : 0.f;
#pragma unroll
      for (int r = 0; r < 4; ++r) {
        float v = acc[i][j][r] + bv;
        if (ACT == 1) v = v > 0.f ? v : 0.f;
        else if (ACT == 2) v = tanhf(v);
        else if (ACT == 3) v = fabsf(tanhf(v));
        if (!real) v = 0.f;
        if (OBF) ((unsigned short*)Cp)[(size_t)(row + r) * ldc + col] = f2b(v);
        else ((float*)Cp)[(size_t)(row + r) * ldc + col] = v;
      }
    }
  }
}

// ---------------- batched runtime-act MFMA GEMM for small tail GEMMs ----------------
// act: 0 none, 1 relu, 2 tanh, 3 abs(tanh); obf: 1 bf16 out, 0 f32 out.
struct GDesc {
  const unsigned short* A; const unsigned short* BT; const float* bias; void* C;
  int Nreal, K, lda, ldb, ldc, gx, zpad, act, obf, wg_end;
};
struct GBatch { GDesc d[5]; };
__global__ __launch_bounds__(256) void gemm_batch(GBatch gb) {
  __shared__ unsigned short As[128 * 32];
  __shared__ unsigned short Bs[128 * 32];
  int bid = blockIdx.x;
  int di = 0;
  while (bid >= gb.d[di].wg_end) ++di;
  const GDesc& g = gb.d[di];
  int rel = bid - (di ? gb.d[di - 1].wg_end : 0);
  const int bm = (rel / g.gx) * 128, bn = (rel % g.gx) * 128;
  const int tid = threadIdx.x;
  const int wv = tid >> 6, lane = tid & 63;
  const int sr = lane >> 2;
  const int sk = ((lane & 3) ^ ((lane >> 3) & 3)) * 8;
  const int r16 = lane & 15, kq = lane >> 4;
  const int slot8 = (kq ^ ((r16 >> 1) & 3)) * 8;
  const int wr = wv >> 1, wc = wv & 1;
  f32x4 acc[4][4];
#pragma unroll
  for (int i = 0; i < 4; ++i)
#pragma unroll
    for (int j = 0; j < 4; ++j) acc[i][j] = (f32x4){0.f, 0.f, 0.f, 0.f};

  const unsigned short* Abase = g.A + (size_t)bm * g.lda;
  const unsigned short* Bbase = g.BT + (size_t)bn * g.ldb;
  for (int k0 = 0; k0 < g.K; k0 += 32) {
    gload_lds16(Abase + (size_t)(wv * 16 + sr) * g.lda + k0 + sk, &As[wv * 512]);
    gload_lds16(Abase + (size_t)(64 + wv * 16 + sr) * g.lda + k0 + sk, &As[2048 + wv * 512]);
    gload_lds16(Bbase + (size_t)(wv * 16 + sr) * g.ldb + k0 + sk, &Bs[wv * 512]);
    gload_lds16(Bbase + (size_t)(64 + wv * 16 + sr) * g.ldb + k0 + sk, &Bs[2048 + wv * 512]);
    __syncthreads();
    bf16x8 af[4], bfr[4];
#pragma unroll
    for (int i = 0; i < 4; ++i)
      af[i] = *(const bf16x8*)&As[(wr * 64 + i * 16 + r16) * 32 + slot8];
#pragma unroll
    for (int j = 0; j < 4; ++j)
      bfr[j] = *(const bf16x8*)&Bs[(wc * 64 + j * 16 + r16) * 32 + slot8];
#pragma unroll
    for (int i = 0; i < 4; ++i)
#pragma unroll
      for (int j = 0; j < 4; ++j)
        acc[i][j] = __builtin_amdgcn_mfma_f32_16x16x32_bf16(af[i], bfr[j], acc[i][j], 0, 0, 0);
    __syncthreads();
  }
#pragma unroll
  for (int i = 0; i < 4; ++i) {
    int row = bm + wr * 64 + i * 16 + kq * 4;
#pragma unroll
    for (int j = 0; j < 4; ++j) {
      int col = bn + wc * 64 + j * 16 + r16;
      bool real = col < g.Nreal;
      if (!real && !g.zpad) continue;
      float bv = (g.bias && real) ? g.bias[col] : 0.f;
#pragma unroll
      for (int r = 0; r < 4; ++r) {
        float v = acc[i][j][r] + bv;
        if (g.act == 1) v = v > 0.f ? v : 0.f;
        else if (g.act == 2) v = tanhf(v);
        else if (g.act == 3) v = fabsf(tanhf(v));
        if (!real) v = 0.f;
        if (g.obf) ((unsigned short*)g.C)[(size_t)(row + r) * g.ldc + col] = f2b(v);
        else ((float*)g.C)[(size_t)(row + r) * g.ldc + col] = v;
      }
    }
  }
}

// ---------------- split-K MFMA GEMM for z1 ----------------
// 16 K-slices, grid=1664; XCD-chunk: each XCD owns 2 whole K-slices.
__global__ __launch_bounds__(256) void gemm_mfma_sk(
    const unsigned short* __restrict__ A, const unsigned short* __restrict__ BT,
    float* __restrict__ PART, int lda, int ldb, int ldc) {
  __shared__ unsigned short As[128 * 32];
  __shared__ unsigned short Bs[128 * 32];
  const int bid = blockIdx.x;
  const int swz = (bid & 7) * 208 + (bid >> 3);
  const int s = swz / 104;
  const int pos = swz - s * 104;
  const int bm = (pos / 13) * 128, bn = (pos % 13) * 128;
  const int base = s * 37 + (s < 6 ? s : 6);
  const int nsteps = 37 + (s < 6 ? 1 : 0);
  const int tid = threadIdx.x;
  const int wv = tid >> 6, lane = tid & 63;
  const int sr = lane >> 2;
  const int sk = ((lane & 3) ^ ((lane >> 3) & 3)) * 8;
  const int r16 = lane & 15, kq = lane >> 4;
  const int slot8 = (kq ^ ((r16 >> 1) & 3)) * 8;
  const int wr = wv >> 1, wc = wv & 1;
  f32x4 acc[4][4];
#pragma unroll
  for (int i = 0; i < 4; ++i)
#pragma unroll
    for (int j = 0; j < 4; ++j) acc[i][j] = (f32x4){0.f, 0.f, 0.f, 0.f};

  const unsigned short* Abase = A + (size_t)bm * lda;
  const unsigned short* Bbase = BT + (size_t)bn * ldb;
  for (int ks = 0; ks < nsteps; ++ks) {
    int k0 = (base + ks) * 32;
    gload_lds16(Abase + (size_t)(wv * 16 + sr) * lda + k0 + sk, &As[wv * 512]);
    gload_lds16(Abase + (size_t)(64 + wv * 16 + sr) * lda + k0 + sk, &As[2048 + wv * 512]);
    gload_lds16(Bbase + (size_t)(wv * 16 + sr) * ldb + k0 + sk, &Bs[wv * 512]);
    gload_lds16(Bbase + (size_t)(64 + wv * 16 + sr) * ldb + k0 + sk, &Bs[2048 + wv * 512]);
    __syncthreads();
    bf16x8 af[4], bfr[4];
#pragma unroll
    for (int i = 0; i < 4; ++i)
      af[i] = *(const bf16x8*)&As[(wr * 64 + i * 16 + r16) * 32 + slot8];
#pragma unroll
    for (int j = 0; j < 4; ++j)
      bfr[j] = *(const bf16x8*)&Bs[(wc * 64 + j * 16 + r16) * 32 + slot8];
#pragma unroll
    for (int i = 0; i < 4; ++i)
#pragma unroll
      for (int j = 0; j < 4; ++j)
        acc[i][j] = __builtin_amdgcn_mfma_f32_16x16x32_bf16(af[i], bfr[j], acc[i][j], 0, 0, 0);
    __syncthreads();
  }
  float* out = PART + (size_t)s * 1024 * ldc;
#pragma unroll
  for (int i = 0; i < 4; ++i) {
    int row = bm + wr * 64 + i * 16 + kq * 4;
#pragma unroll
    for (int j = 0; j < 4; ++j) {
      int col = bn + wc * 64 + j * 16 + r16;
      if (col >= 1600) continue;
#pragma unroll
      for (int r = 0; r < 4; ++r)
        out[(size_t)(row + r) * ldc + col] = acc[i][j][r];
    }
  }
}

// reduce 16 f32 K-slice partials + bias + relu -> ZB bf16 [1024][1664]
__global__ void zred(const float* __restrict__ PART, const float* __restrict__ bias,
                     unsigned short* __restrict__ ZB) {
  int idx = blockIdx.x * blockDim.x + threadIdx.x;
  if (idx >= 1024 * 1664) return;
  int c = idx % 1664;
  if (c >= 1600) { ZB[idx] = 0; return; }
  float s = 0.f;
#pragma unroll
  for (int k = 0; k < 16; ++k) s += PART[(size_t)k * 1024 * 1664 + idx];
  s += bias[c];
  ZB[idx] = f2b(s > 0.f ? s : 0.f);
}

// ---------------- GAT pieces ----------------
__global__ void gat_scores_bf(const unsigned short* __restrict__ hlin,
                              const float* __restrict__ a_s, const float* __restrict__ a_d,
                              float* __restrict__ als, float* __restrict__ ald,
                              int H, int C, int tot) {
  int idx = blockIdx.x * blockDim.x + threadIdx.x;
  if (idx >= tot) return;
  int n = idx / H, h = idx - n * H;
  const unsigned short* base = hlin + (size_t)n * H * C + (size_t)h * C;
  const float* as = a_s + h * C;
  const float* ad = a_d + h * C;
  float ss = 0.f, sd = 0.f;
  for (int c = 0; c < C; c += 8) {
    ushort8 v = *(const ushort8*)(base + c);
#pragma unroll
    for (int t = 0; t < 8; ++t) {
      float f = b2f(v[t]);
      ss = fmaf(f, as[c + t], ss);
      sd = fmaf(f, ad[c + t], sd);
    }
  }
  als[idx] = ss;
  ald[idx] = sd;
}

template <int H>
__global__ void edge_attn(const int* __restrict__ ei, const float* __restrict__ als,
                          const float* __restrict__ ald, const int* __restrict__ pos,
                          float* __restrict__ ebs) {
  int e = blockIdx.x * blockDim.x + threadIdx.x;
  if (e >= ETOT) return;
  int src, dst;
  if (e < E0) { src = ei[e]; dst = ei[E0 + e]; } else { src = dst = e - E0; }
  int p = pos[e];
  if (H == 8) {
    float4 s0 = *(const float4*)(als + src * 8);
    float4 s1 = *(const float4*)(als + src * 8 + 4);
    float4 d0 = *(const float4*)(ald + dst * 8);
    float4 d1 = *(const float4*)(ald + dst * 8 + 4);
    float ev[8] = {s0.x + d0.x, s0.y + d0.y, s0.z + d0.z, s0.w + d0.w,
                   s1.x + d1.x, s1.y + d1.y, s1.z + d1.z, s1.w + d1.w};
#pragma unroll
    for (int h = 0; h < 8; ++h) {
      float v = ev[h];
      v = (v >= 0.f) ? v : 0.2f * v;
      ebs[(size_t)p * 8 + h] = __expf(v);
    }
  } else {
    float v = als[src] + ald[dst];
    v = (v >= 0.f) ? v : 0.2f * v;
    ebs[p] = __expf(v);
  }
}

template <int F, int C>
__global__ __launch_bounds__(256) void gat_agg_v3(
    const int* __restrict__ rowptr, const float* __restrict__ ebs,
    const int* __restrict__ srcl, const unsigned short* __restrict__ hlin,
    const float* __restrict__ bias, unsigned short* __restrict__ out) {
  constexpr int H = F / C;
  constexpr int CPN = F / 8;
  int gidx = blockIdx.x * 256 + threadIdx.x;
  if (gidx >= NN * CPN) return;
  int node = gidx / CPN;
  int c0 = (gidx - node * CPN) * 8;
  int h = c0 / C;
  float s = 0.f;
  float acc[8] = {0.f, 0.f, 0.f, 0.f, 0.f, 0.f, 0.f, 0.f};
  int start = rowptr[node], end = rowptr[node + 1];
  for (int k = start; k < end; ++k) {
    int src = srcl[k];
    float p = ebs[(size_t)k * H + h];
    s += p;
    ushort8 hv = *(const ushort8*)(hlin + (size_t)src * F + c0);
#pragma unroll
    for (int t = 0; t < 8; ++t) acc[t] = fmaf(p, b2f(hv[t]), acc[t]);
  }
  float inv_s = 1.f / s;
  ushort8 o;
#pragma unroll
  for (int t = 0; t < 8; ++t) {
    float val = acc[t] * inv_s + bias[c0 + t];
    o[t] = f2b(val > 0.f ? val : 0.f);
  }
  *(ushort8*)(out + (size_t)node * F + c0) = o;
}

__global__ void pool_max(const unsigned short* __restrict__ xb,
                         unsigned short* __restrict__ xgb) {
  int g = blockIdx.x, c = threadIdx.x;  // 128 threads
  const unsigned short* base = xb + (size_t)g * 32 * 128 + c;
  float m = -FLT_MAX;
#pragma unroll 8
  for (int n = 0; n < 32; ++n) m = fmaxf(m, b2f(base[n * 128]));
  xgb[g * 128 + c] = f2b(m);
}

// blocks 0..NB-1: DRUG->DN ; blocks NB..NB+NSIDE-1: SE->SN
__global__ void rownorm2(const float* __restrict__ drug, const float* __restrict__ se,
                         float* __restrict__ dn, float* __restrict__ sn) {
  int b = blockIdx.x, lane = threadIdx.x;
  const float* in; float* outp; int r;
  if (b < NB) { in = drug; outp = dn; r = b; }
  else { in = se; outp = sn; r = b - NB; }
  float v = in[r * 64 + lane];
  float ss = v * v;
#pragma unroll
  for (int off = 1; off < 64; off <<= 1) ss += __shfl_xor(ss, off);
  float nrm = fmaxf(sqrtf(ss), 1e-12f);
  outp[r * 64 + lane] = v / nrm;
}

__global__ __launch_bounds__(256) void freq_k(const float* __restrict__ dn,
                                              const float* __restrict__ sn,
                                              float* __restrict__ C, int M, int N) {
  __shared__ float As[16][64];
  __shared__ float Bs[16][65];
  int tid = threadIdx.x;
  int tx = tid & 15, ty = tid >> 4;
  int bi = blockIdx.y * 16, bj = blockIdx.x * 16;
#pragma unroll
  for (int t = 0; t < 4; ++t) {
    int idx = tid * 4 + t;
    int r = idx >> 6, c = idx & 63;
    As[r][c] = (bi + r < M) ? dn[(bi + r) * 64 + c] : 0.f;
    Bs[r][c] = (bj + r < N) ? sn[(bj + r) * 64 + c] : 0.f;
  }
  __syncthreads();
  float acc = 0.f;
#pragma unroll
  for (int k = 0; k < 64; ++k) acc = fmaf(As[ty][k], Bs[tx][k], acc);
  if (bi + ty < M && bj + tx < N) C[(size_t)(bi + ty) * N + (bj + tx)] = 5.f * acc;
}

// ---------------- launch ----------------
extern "C" void kernel_launch(void* const* d_in, const int* in_sizes, int n_in,
                              void* d_out, int out_size, void* d_ws, size_t ws_size,
                              hipStream_t stream) {
  const float* x = (const float*)d_in[0];
  const int* ei = (const int*)d_in[1];
  const float* w = (const float*)d_in[3];
  const float* z = (const float*)d_in[4];
  const float* v = (const float*)d_in[5];
  const float* side = (const float*)d_in[6];
  const float* gW[4] = {(const float*)d_in[7], (const float*)d_in[11],
                        (const float*)d_in[15], (const float*)d_in[19]};
  const float* gas[4] = {(const float*)d_in[8], (const float*)d_in[12],
                         (const float*)d_in[16], (const float*)d_in[20]};
  const float* gad[4] = {(const float*)d_in[9], (const float*)d_in[13],
                         (const float*)d_in[17], (const float*)d_in[21]};
  const float* gb[4] = {(const float*)d_in[10], (const float*)d_in[14],
                        (const float*)d_in[18], (const float*)d_in[22]};
  const float* x5_W = (const float*)d_in[23]; const float* x5_b = (const float*)d_in[24];
  const float* x6_W = (const float*)d_in[25]; const float* x6_b = (const float*)d_in[26];
  const float* w1_W = (const float*)d_in[27]; const float* w1_b = (const float*)d_in[28];
  const float* w2_W = (const float*)d_in[29]; const float* w2_b = (const float*)d_in[30];
  const float* z1_W = (const float*)d_in[31]; const float* z1_b = (const float*)d_in[32];
  const float* z2_W = (const float*)d_in[33]; const float* z2_b = (const float*)d_in[34];
  const float* v1_W = (const float*)d_in[35]; const float* v1_b = (const float*)d_in[36];
  const float* v2_W = (const float*)d_in[37]; const float* v2_b = (const float*)d_in[38];
  const float* agg_W = (const float*)d_in[39]; const float* agg_b = (const float*)d_in[40];
  const float* col_W = (const float*)d_in[41]; const float* col_b = (const float*)d_in[42];
  const float* s1_W = (const float*)d_in[43]; const float* s1_b = (const float*)d_in[44];
  const float* s2_W = (const float*)d_in[45]; const float* s2_b = (const float*)d_in[46];

  char* wsb = (char*)d_ws;
  size_t off = 0;
  auto alloc = [&](size_t bytes) {
    void* p = wsb + off;
    off = (off + bytes + 255) & ~(size_t)255;
    return p;
  };
  unsigned short* HLIN = (unsigned short*)alloc((size_t)NN * 1024 * 2);
  unsigned short* XB = (unsigned short*)alloc((size_t)NN * 1024 * 2);
  unsigned short* WTZ = (unsigned short*)alloc((size_t)1664 * 19136 * 2);
  unsigned short* ZA = (unsigned short*)alloc((size_t)1024 * 19136 * 2);
  unsigned short* WT1 = (unsigned short*)alloc((size_t)768 * 128 * 2);
  unsigned short* WT2 = (unsigned short*)alloc((size_t)1024 * 768 * 2);
  unsigned short* WT3 = (unsigned short*)alloc((size_t)1024 * 1024 * 2);
  unsigned short* WT4 = (unsigned short*)alloc((size_t)128 * 1024 * 2);
  unsigned short* WTW1 = (unsigned short*)alloc((size_t)768 * 768 * 2);
  unsigned short* WTW2 = (unsigned short*)alloc((size_t)128 * 768 * 2);
  unsigned short* WTZ2 = (unsigned short*)alloc((size_t)128 * 1664 * 2);
  unsigned short* WTV1 = (unsigned short*)alloc((size_t)256 * 1024 * 2);
  unsigned short* WTV2 = (unsigned short*)alloc((size_t)128 * 256 * 2);
  unsigned short* WTX5 = (unsigned short*)alloc((size_t)128 * 128 * 2);
  unsigned short* WTX6 = (unsigned short*)alloc((size_t)128 * 64 * 2);
  unsigned short* WTAGG = (unsigned short*)alloc((size_t)128 * 192 * 2);
  unsigned short* WTCOL = (unsigned short*)alloc((size_t)128 * 128 * 2);
  unsigned short* WTS1 = (unsigned short*)alloc((size_t)128 * 1056 * 2);
  unsigned short* WTS2 = (unsigned short*)alloc((size_t)128 * 64 * 2);
  unsigned short* WB = (unsigned short*)alloc((size_t)1024 * 768 * 2);
  unsigned short* VB = (unsigned short*)alloc((size_t)1024 * 1024 * 2);
  unsigned short* SIDEB = (unsigned short*)alloc((size_t)1024 * 1056 * 2);
  unsigned short* XGB = (unsigned short*)alloc((size_t)1024 * 128 * 2);
  unsigned short* ZB = (unsigned short*)alloc((size_t)1024 * 1664 * 2);
  unsigned short* X5O = (unsigned short*)alloc((size_t)1024 * 128 * 2);
  unsigned short* WMID = (unsigned short*)alloc((size_t)1024 * 768 * 2);
  unsigned short* VMID = (unsigned short*)alloc((size_t)1024 * 256 * 2);
  unsigned short* SEMID = (unsigned short*)alloc((size_t)1024 * 128 * 2);
  unsigned short* CAT192 = (unsigned short*)alloc((size_t)1024 * 192 * 2);
  unsigned short* CAT128 = (unsigned short*)alloc((size_t)1024 * 128 * 2);
  float* EBS = (float*)alloc((size_t)ETOT * 8 * 4);
  float* ALS = (float*)alloc((size_t)NN * 8 * 4);
  float* ALD = (float*)alloc((size_t)NN * 8 * 4);
  float* DRUG = (float*)alloc((size_t)NB * 64 * 4);
  float* SE = (float*)alloc((size_t)1024 * 64 * 4);
  int* DEG = (int*)alloc((size_t)NN * 4);
  int* ROWPTR = (int*)alloc((size_t)(NN + 1) * 4);
  int* CURSOR = (int*)alloc((size_t)NN * 4);
  int* SRCL = (int*)alloc((size_t)ETOT * 4);
  int* POS = (int*)alloc((size_t)ETOT * 4);
  float* PART = (float*)HLIN;  // 109MB over dead HLIN+XB

  // CSR build (4 launches)
  hipLaunchKernelGGL(fill_i32, dim3((NN + 255) / 256), dim3(256), 0, stream, DEG, 0, NN);
  hipLaunchKernelGGL(count_deg, dim3((ETOT + 255) / 256), dim3(256), 0, stream, ei, DEG);
  hipLaunchKernelGGL(scan_deg, dim3(1), dim3(1024), 0, stream, DEG, ROWPTR, CURSOR);
  hipLaunchKernelGGL(fill_csr, dim3((ETOT + 255) / 256), dim3(256), 0, stream, ei, CURSOR, SRCL, POS);

  // batched weight transposes (1 launch)
  {
    TBatch tb;
    int acc_wg = 0, i = 0;
    auto add = [&](const float* W, unsigned short* WT, int K, int N, int Kp, int Npad) {
      int gx = Npad / 32, gy = Kp / 32;
      acc_wg += gx * gy;
      tb.d[i++] = {W, WT, K, N, Kp, Npad, gx, acc_wg};
    };
    add(z1_W, WTZ, 19127, 1600, 19136, 1664);
    add(gW[0], WT1, 109, 768, 128, 768);
    add(gW[1], WT2, 768, 1024, 768, 1024);
    add(gW[2], WT3, 1024, 1024, 1024, 1024);
    add(gW[3], WT4, 1024, 128, 1024, 128);
    add(w1_W, WTW1, 750, 750, 768, 768);
    add(w2_W, WTW2, 750, 64, 768, 128);
    add(z2_W, WTZ2, 1600, 64, 1664, 128);
    add(v1_W, WTV1, 1024, 256, 1024, 256);
    add(v2_W, WTV2, 256, 64, 256, 128);
    add(x5_W, WTX5, 128, 64, 128, 128);
    add(x6_W, WTX6, 64, 64, 64, 128);
    add(agg_W, WTAGG, 192, 64, 192, 128);
    add(col_W, WTCOL, 128, 64, 128, 128);
    add(s1_W, WTS1, 1050, 64, 1056, 128);
    add(s2_W, WTS2, 64, 64, 64, 128);
    hipLaunchKernelGGL(transpose_batch, dim3(acc_wg), dim3(256), 0, stream, tb);
  }

  // batched input conversions (1 launch)
  {
    CBatch cb;
    int acc_wg = 0, i = 0;
    auto add = [&](const float* in, unsigned short* out, int rowsOut, int Rreal, int C, int Cp) {
      acc_wg += (int)(((size_t)rowsOut * Cp + 255) / 256);
      cb.d[i++] = {in, out, rowsOut, Rreal, C, Cp, acc_wg};
    };
    add(z, ZA, NB, NB, 19127, 19136);
    add(x, XB, NN, NN, 109, 128);
    add(w, WB, 1024, 1024, 750, 768);
    add(v, VB, 1024, 1024, 1024, 1024);
    add(side, SIDEB, 1024, 994, 1050, 1056);
    hipLaunchKernelGGL(conv_batch, dim3(acc_wg), dim3(256), 0, stream, cb);
  }

  auto mm = [&](int act, int obf, const unsigned short* A, const unsigned short* BT,
                const float* bias, void* C, int M, int Npad, int Nreal, int K,
                int lda, int ldb, int ldc, int zpad) {
    int gx = Npad / 128;
    int nwg = gx * (M / 128);
    switch (act * 2 + obf) {
      case 1: hipLaunchKernelGGL((gemm_mfma<0,1>), dim3(nwg), dim3(256), 0, stream, A, BT, bias, C, Nreal, K, lda, ldb, ldc, gx, zpad); break;
      default: break;
    }
  };

  // GAT layers
  const int Hs[4] = {8, 8, 8, 1};
  const int Kp[4] = {128, 768, 1024, 1024};
  const unsigned short* WTs[4] = {WT1, WT2, WT3, WT4};
  const int Fs[4] = {768, 1024, 1024, 128};
  for (int l = 0; l < 4; ++l) {
    int H = Hs[l], F = Fs[l], C = F / H;
    mm(0, 1, XB, WTs[l], nullptr, HLIN, NN, F, F, Kp[l], Kp[l], Kp[l], F, 0);
    int totNH = NN * H;
    hipLaunchKernelGGL(gat_scores_bf, dim3((totNH + 255) / 256), dim3(256), 0, stream,
                       HLIN, gas[l], gad[l], ALS, ALD, H, C, totNH);
    if (H == 8)
      hipLaunchKernelGGL((edge_attn<8>), dim3((ETOT + 255) / 256), dim3(256), 0, stream, ei, ALS, ALD, POS, EBS);
    else
      hipLaunchKernelGGL((edge_attn<1>), dim3((ETOT + 255) / 256), dim3(256), 0, stream, ei, ALS, ALD, POS, EBS);
    if (l == 0)
      hipLaunchKernelGGL((gat_agg_v3<768, 96>), dim3(NN * 96 / 256), dim3(256), 0, stream,
                         ROWPTR, EBS, SRCL, HLIN, gb[l], XB);
    else if (l == 3)
      hipLaunchKernelGGL((gat_agg_v3<128, 128>), dim3(NN * 16 / 256), dim3(256), 0, stream,
                         ROWPTR, EBS, SRCL, HLIN, gb[l], XB);
    else
      hipLaunchKernelGGL((gat_agg_v3<1024, 128>), dim3(NN * 128 / 256), dim3(256), 0, stream,
                         ROWPTR, EBS, SRCL, HLIN, gb[l], XB);
  }

  // global max pool -> XGB bf16
  hipLaunchKernelGGL(pool_max, dim3(NB), dim3(128), 0, stream, XB, XGB);

  // B1: independent tail GEMMs {x5, w1, v1, s1} (1 launch, 80 WGs)
  {
    GBatch b;
    int acc_wg = 0, i = 0;
    auto add = [&](const unsigned short* A, const unsigned short* BT, const float* bias,
                   void* C, int Npad, int Nreal, int K, int lda, int ldb, int ldc,
                   int zpad, int act, int obf) {
      int gx = Npad / 128;
      acc_wg += gx * 8;
      b.d[i++] = {A, BT, bias, C, Nreal, K, lda, ldb, ldc, gx, zpad, act, obf, acc_wg};
    };
    add(WB, WTW1, w1_b, WMID, 768, 750, 768, 768, 768, 768, 1, 1, 1);
    add(VB, WTV1, v1_b, VMID, 256, 256, 1024, 1024, 1024, 256, 0, 1, 1);
    add(SIDEB, WTS1, s1_b, SEMID, 128, 64, 1056, 1056, 1056, 128, 1, 1, 1);
    add(XGB, WTX5, x5_b, X5O, 128, 64, 128, 128, 128, 128, 1, 1, 1);
    while (i < 5) { b.d[i] = b.d[i - 1]; b.d[i].wg_end = acc_wg; ++i; }
    hipLaunchKernelGGL(gemm_batch, dim3(acc_wg), dim3(256), 0, stream, b);
  }

  // z1 split-K + reduce -> ZB bf16
  hipLaunchKernelGGL(gemm_mfma_sk, dim3(1664), dim3(256), 0, stream, ZA, WTZ, PART, 19136, 19136, 1664);
  hipLaunchKernelGGL(zred, dim3((1024 * 1664 + 255) / 256), dim3(256), 0, stream, PART, z1_b, ZB);

  // B2: {x6, w2, z2, v2, s2} (1 launch, 40 WGs)
  {
    GBatch b;
    int acc_wg = 0, i = 0;
    auto add = [&](const unsigned short* A, const unsigned short* BT, const float* bias,
                   void* C, int Npad, int Nreal, int K, int lda, int ldb, int ldc,
                   int zpad, int act, int obf) {
      int gx = Npad / 128;
      acc_wg += gx * 8;
      b.d[i++] = {A, BT, bias, C, Nreal, K, lda, ldb, ldc, gx, zpad, act, obf, acc_wg};
    };
    add(X5O, WTX6, x6_b, CAT192 + 0, 128, 64, 64, 128, 64, 192, 0, 1, 1);
    add(WMID, WTW2, w2_b, CAT192 + 64, 128, 64, 768, 768, 768, 192, 0, 1, 1);
    add(ZB, WTZ2, z2_b, CAT192 + 128, 128, 64, 1664, 1664, 1664, 192, 0, 1, 1);
    add(VMID, WTV2, v2_b, CAT128 + 64, 128, 64, 256, 256, 256, 128, 0, 1, 1);
    add(SEMID, WTS2, s2_b, SE, 128, 64, 64, 128, 64, 64, 0, 2, 0);
    hipLaunchKernelGGL(gemm_batch, dim3(acc_wg), dim3(256), 0, stream, b);
  }

  // B3: agg (needs CAT192)
  {
    GBatch b;
    b.d[0] = {CAT192, WTAGG, agg_b, CAT128 + 0, 64, 192, 192, 192, 128, 1, 0, 0, 1, 8};
    for (int i = 1; i < 5; ++i) { b.d[i] = b.d[0]; }
    hipLaunchKernelGGL(gemm_batch, dim3(8), dim3(256), 0, stream, b);
  }
  // B4: col (needs CAT128)
  {
    GBatch b;
    b.d[0] = {CAT128, WTCOL, col_b, DRUG, 64, 128, 128, 128, 64, 1, 0, 3, 0, 8};
    for (int i = 1; i < 5; ++i) { b.d[i] = b.d[0]; }
    hipLaunchKernelGGL(gemm_batch, dim3(8), dim3(256), 0, stream, b);
  }

  // normalize + similarity
  float* outp = (float*)d_out;
  float* DN = outp + (size_t)NB * NSIDE;
  float* SN = DN + (size_t)NB * 64;
  hipLaunchKernelGGL(rownorm2, dim3(NB + NSIDE), dim3(64), 0, stream, DRUG, SE, DN, SN);
  hipLaunchKernelGGL(freq_k, dim3((NSIDE + 15) / 16, (NB + 15) / 16), dim3(256), 0, stream,
                     DN, SN, outp, NB, NSIDE);
}

// Round 9
// 1034.997 us; speedup vs baseline: 1.5141x; 1.0003x over previous
//
#include <hip/hip_runtime.h>
#include <math.h>
#include <float.h>

#define E0 131072
#define NN 32768
#define NB 1024
#define NSIDE 994
#define ETOT (E0 + NN)

typedef short bf16x8 __attribute__((ext_vector_type(8)));
typedef unsigned short ushort8 __attribute__((ext_vector_type(8)));
typedef float f32x4 __attribute__((ext_vector_type(4)));

__device__ inline float b2f(unsigned short u) { return __uint_as_float(((unsigned)u) << 16); }
__device__ inline unsigned short f2b(float f) {
  unsigned u = __float_as_uint(f);
  return (unsigned short)((u + 0x7fffu + ((u >> 16) & 1u)) >> 16);
}

__device__ inline void gload_lds16(const void* g, void* l) {
  __builtin_amdgcn_global_load_lds(
      (const __attribute__((address_space(1))) unsigned int*)g,
      (__attribute__((address_space(3))) unsigned int*)l, 16, 0, 0);
}

__global__ void fill_i32(int* p, int v, int n) {
  int i = blockIdx.x * blockDim.x + threadIdx.x;
  if (i < n) p[i] = v;
}

// ---------------- batched fp32 -> bf16 conversion with padding ----------------
struct CDesc { const float* in; unsigned short* out; int rowsOut, Rreal, C, Cp, wg_end; };
struct CBatch { CDesc d[5]; };
__global__ void conv_batch(CBatch cb) {
  int bid = blockIdx.x;
  int di = 0;
  while (bid >= cb.d[di].wg_end) ++di;
  const CDesc& g = cb.d[di];
  int rel = bid - (di ? cb.d[di - 1].wg_end : 0);
  size_t idx = (size_t)rel * 256 + threadIdx.x;
  size_t tot = (size_t)g.rowsOut * g.Cp;
  if (idx >= tot) return;
  int r = (int)(idx / g.Cp), c = (int)(idx % g.Cp);
  g.out[idx] = (r < g.Rreal && c < g.C) ? f2b(g.in[(size_t)r * g.C + c]) : (unsigned short)0;
}

// ---------------- batched transpose: W [K][N] f32 -> WT [Npad][Kp] bf16 ----------------
struct TDesc { const float* W; unsigned short* WT; int K, N, Kp, Npad, gx, wg_end; };
struct TBatch { TDesc d[16]; };
__global__ __launch_bounds__(256) void transpose_batch(TBatch tb) {
  __shared__ float t[32][33];
  int bid = blockIdx.x;
  int di = 0;
  while (bid >= tb.d[di].wg_end) ++di;
  const TDesc& g = tb.d[di];
  int rel = bid - (di ? tb.d[di - 1].wg_end : 0);
  int n0 = (rel % g.gx) * 32, k0 = (rel / g.gx) * 32;
  int tx = threadIdx.x & 31, ty = threadIdx.x >> 5;
  for (int r = ty; r < 32; r += 8) {
    int k = k0 + r, n = n0 + tx;
    t[r][tx] = (k < g.K && n < g.N) ? g.W[(size_t)k * g.N + n] : 0.f;
  }
  __syncthreads();
  for (int r = ty; r < 32; r += 8) {
    int n = n0 + r, k = k0 + tx;
    if (n < g.Npad && k < g.Kp)
      g.WT[(size_t)n * g.Kp + k] = (n < g.N) ? f2b(t[tx][r]) : (unsigned short)0;
  }
}

// ---------------- CSR build over dst ----------------
__global__ void count_deg(const int* __restrict__ ei, int* deg) {
  int e = blockIdx.x * blockDim.x + threadIdx.x;
  if (e >= ETOT) return;
  int dst = (e < E0) ? ei[E0 + e] : (e - E0);
  atomicAdd(&deg[dst], 1);
}

__global__ void scan_deg(const int* __restrict__ deg, int* rowptr, int* cursor) {
  __shared__ int part[1024];
  int tid = threadIdx.x;
  const int chunk = NN / 1024;  // 32
  int base = tid * chunk;
  int local[chunk];
  int sum = 0;
#pragma unroll
  for (int i = 0; i < chunk; ++i) { local[i] = sum; sum += deg[base + i]; }
  part[tid] = sum;
  __syncthreads();
  for (int off = 1; off < 1024; off <<= 1) {
    int t = (tid >= off) ? part[tid - off] : 0;
    __syncthreads();
    part[tid] += t;
    __syncthreads();
  }
  int offset = part[tid] - sum;
#pragma unroll
  for (int i = 0; i < chunk; ++i) {
    int v = offset + local[i];
    rowptr[base + i] = v;
    cursor[base + i] = v;
  }
  if (tid == 1023) rowptr[NN] = offset + sum;
}

__global__ void fill_csr(const int* __restrict__ ei, int* cursor,
                         int* __restrict__ srcl, int* __restrict__ pos) {
  int e = blockIdx.x * blockDim.x + threadIdx.x;
  if (e >= ETOT) return;
  int src, dst;
  if (e < E0) { src = ei[e]; dst = ei[E0 + e]; } else { src = dst = e - E0; }
  int p = atomicAdd(&cursor[dst], 1);
  srcl[p] = src;
  pos[e] = p;
}

// ---------------- bf16 MFMA GEMM, 2-phase double-buffered LDS ----------------
// 128x128 tile, BK=32, 4 waves; XCD-chunked swizzle; XOR k-slot LDS swizzle.
// K-loop: STAGE(buf^1, t+1) -> ds_read(buf)+MFMA -> barrier (auto vmcnt drain AFTER
// compute, so HBM latency hides under the 16 MFMAs) -> flip. One barrier per K-step.
template <int ACT, int OBF>
__global__ __launch_bounds__(256) void gemm_mfma(
    const unsigned short* __restrict__ A, const unsigned short* __restrict__ BT,
    const float* __restrict__ bias, void* __restrict__ Cp,
    int Nreal, int K, int lda, int ldb, int ldc, int gx, int zpad) {
  __shared__ unsigned short As[2][128 * 32];
  __shared__ unsigned short Bs[2][128 * 32];
  const int nwg = gridDim.x;
  const int chunk = nwg >> 3;
  const int bid = blockIdx.x;
  const int swz = (bid & 7) * chunk + (bid >> 3);
  const int bm = (swz / gx) * 128, bn = (swz % gx) * 128;
  const int tid = threadIdx.x;
  const int wv = tid >> 6, lane = tid & 63;
  const int sr = lane >> 2;
  const int sk = ((lane & 3) ^ ((lane >> 3) & 3)) * 8;
  const int r16 = lane & 15, kq = lane >> 4;
  const int slot8 = (kq ^ ((r16 >> 1) & 3)) * 8;
  const int wr = wv >> 1, wc = wv & 1;
  f32x4 acc[4][4];
#pragma unroll
  for (int i = 0; i < 4; ++i)
#pragma unroll
    for (int j = 0; j < 4; ++j) acc[i][j] = (f32x4){0.f, 0.f, 0.f, 0.f};

  const unsigned short* Abase = A + (size_t)bm * lda;
  const unsigned short* Bbase = BT + (size_t)bn * ldb;
  auto stage = [&](int buf, int k0) {
    gload_lds16(Abase + (size_t)(wv * 16 + sr) * lda + k0 + sk, &As[buf][wv * 512]);
    gload_lds16(Abase + (size_t)(64 + wv * 16 + sr) * lda + k0 + sk, &As[buf][2048 + wv * 512]);
    gload_lds16(Bbase + (size_t)(wv * 16 + sr) * ldb + k0 + sk, &Bs[buf][wv * 512]);
    gload_lds16(Bbase + (size_t)(64 + wv * 16 + sr) * ldb + k0 + sk, &Bs[buf][2048 + wv * 512]);
  };
  stage(0, 0);
  __syncthreads();
  int cur = 0;
  for (int k0 = 0; k0 < K; k0 += 32) {
    if (k0 + 32 < K) stage(cur ^ 1, k0 + 32);
    bf16x8 af[4], bfr[4];
#pragma unroll
    for (int i = 0; i < 4; ++i)
      af[i] = *(const bf16x8*)&As[cur][(wr * 64 + i * 16 + r16) * 32 + slot8];
#pragma unroll
    for (int j = 0; j < 4; ++j)
      bfr[j] = *(const bf16x8*)&Bs[cur][(wc * 64 + j * 16 + r16) * 32 + slot8];
#pragma unroll
    for (int i = 0; i < 4; ++i)
#pragma unroll
      for (int j = 0; j < 4; ++j)
        acc[i][j] = __builtin_amdgcn_mfma_f32_16x16x32_bf16(af[i], bfr[j], acc[i][j], 0, 0, 0);
    __syncthreads();
    cur ^= 1;
  }
#pragma unroll
  for (int i = 0; i < 4; ++i) {
    int row = bm + wr * 64 + i * 16 + kq * 4;
#pragma unroll
    for (int j = 0; j < 4; ++j) {
      int col = bn + wc * 64 + j * 16 + r16;
      bool real = col < Nreal;
      if (!real && !zpad) continue;
      float bv = (bias && real) ? bias[col] : 0.f;
#pragma unroll
      for (int r = 0; r < 4; ++r) {
        float v = acc[i][j][r] + bv;
        if (ACT == 1) v = v > 0.f ? v : 0.f;
        else if (ACT == 2) v = tanhf(v);
        else if (ACT == 3) v = fabsf(tanhf(v));
        if (!real) v = 0.f;
        if (OBF) ((unsigned short*)Cp)[(size_t)(row + r) * ldc + col] = f2b(v);
        else ((float*)Cp)[(size_t)(row + r) * ldc + col] = v;
      }
    }
  }
}

// ---------------- batched runtime-act MFMA GEMM (2-phase dbuf) ----------------
struct GDesc {
  const unsigned short* A; const unsigned short* BT; const float* bias; void* C;
  int Nreal, K, lda, ldb, ldc, gx, zpad, act, obf, wg_end;
};
struct GBatch { GDesc d[5]; };
__global__ __launch_bounds__(256) void gemm_batch(GBatch gb) {
  __shared__ unsigned short As[2][128 * 32];
  __shared__ unsigned short Bs[2][128 * 32];
  int bid = blockIdx.x;
  int di = 0;
  while (bid >= gb.d[di].wg_end) ++di;
  const GDesc& g = gb.d[di];
  int rel = bid - (di ? gb.d[di - 1].wg_end : 0);
  const int bm = (rel / g.gx) * 128, bn = (rel % g.gx) * 128;
  const int tid = threadIdx.x;
  const int wv = tid >> 6, lane = tid & 63;
  const int sr = lane >> 2;
  const int sk = ((lane & 3) ^ ((lane >> 3) & 3)) * 8;
  const int r16 = lane & 15, kq = lane >> 4;
  const int slot8 = (kq ^ ((r16 >> 1) & 3)) * 8;
  const int wr = wv >> 1, wc = wv & 1;
  f32x4 acc[4][4];
#pragma unroll
  for (int i = 0; i < 4; ++i)
#pragma unroll
    for (int j = 0; j < 4; ++j) acc[i][j] = (f32x4){0.f, 0.f, 0.f, 0.f};

  const unsigned short* Abase = g.A + (size_t)bm * g.lda;
  const unsigned short* Bbase = g.BT + (size_t)bn * g.ldb;
  auto stage = [&](int buf, int k0) {
    gload_lds16(Abase + (size_t)(wv * 16 + sr) * g.lda + k0 + sk, &As[buf][wv * 512]);
    gload_lds16(Abase + (size_t)(64 + wv * 16 + sr) * g.lda + k0 + sk, &As[buf][2048 + wv * 512]);
    gload_lds16(Bbase + (size_t)(wv * 16 + sr) * g.ldb + k0 + sk, &Bs[buf][wv * 512]);
    gload_lds16(Bbase + (size_t)(64 + wv * 16 + sr) * g.ldb + k0 + sk, &Bs[buf][2048 + wv * 512]);
  };
  stage(0, 0);
  __syncthreads();
  int cur = 0;
  for (int k0 = 0; k0 < g.K; k0 += 32) {
    if (k0 + 32 < g.K) stage(cur ^ 1, k0 + 32);
    bf16x8 af[4], bfr[4];
#pragma unroll
    for (int i = 0; i < 4; ++i)
      af[i] = *(const bf16x8*)&As[cur][(wr * 64 + i * 16 + r16) * 32 + slot8];
#pragma unroll
    for (int j = 0; j < 4; ++j)
      bfr[j] = *(const bf16x8*)&Bs[cur][(wc * 64 + j * 16 + r16) * 32 + slot8];
#pragma unroll
    for (int i = 0; i < 4; ++i)
#pragma unroll
      for (int j = 0; j < 4; ++j)
        acc[i][j] = __builtin_amdgcn_mfma_f32_16x16x32_bf16(af[i], bfr[j], acc[i][j], 0, 0, 0);
    __syncthreads();
    cur ^= 1;
  }
#pragma unroll
  for (int i = 0; i < 4; ++i) {
    int row = bm + wr * 64 + i * 16 + kq * 4;
#pragma unroll
    for (int j = 0; j < 4; ++j) {
      int col = bn + wc * 64 + j * 16 + r16;
      bool real = col < g.Nreal;
      if (!real && !g.zpad) continue;
      float bv = (g.bias && real) ? g.bias[col] : 0.f;
#pragma unroll
      for (int r = 0; r < 4; ++r) {
        float v = acc[i][j][r] + bv;
        if (g.act == 1) v = v > 0.f ? v : 0.f;
        else if (g.act == 2) v = tanhf(v);
        else if (g.act == 3) v = fabsf(tanhf(v));
        if (!real) v = 0.f;
        if (g.obf) ((unsigned short*)g.C)[(size_t)(row + r) * g.ldc + col] = f2b(v);
        else ((float*)g.C)[(size_t)(row + r) * g.ldc + col] = v;
      }
    }
  }
}

// ---------------- split-K MFMA GEMM for z1 (2-phase dbuf) ----------------
// 16 K-slices, grid=1664; XCD-chunk: each XCD owns 2 whole K-slices.
__global__ __launch_bounds__(256) void gemm_mfma_sk(
    const unsigned short* __restrict__ A, const unsigned short* __restrict__ BT,
    float* __restrict__ PART, int lda, int ldb, int ldc) {
  __shared__ unsigned short As[2][128 * 32];
  __shared__ unsigned short Bs[2][128 * 32];
  const int bid = blockIdx.x;
  const int swz = (bid & 7) * 208 + (bid >> 3);
  const int s = swz / 104;
  const int pos = swz - s * 104;
  const int bm = (pos / 13) * 128, bn = (pos % 13) * 128;
  const int base = s * 37 + (s < 6 ? s : 6);
  const int nsteps = 37 + (s < 6 ? 1 : 0);
  const int tid = threadIdx.x;
  const int wv = tid >> 6, lane = tid & 63;
  const int sr = lane >> 2;
  const int sk = ((lane & 3) ^ ((lane >> 3) & 3)) * 8;
  const int r16 = lane & 15, kq = lane >> 4;
  const int slot8 = (kq ^ ((r16 >> 1) & 3)) * 8;
  const int wr = wv >> 1, wc = wv & 1;
  f32x4 acc[4][4];
#pragma unroll
  for (int i = 0; i < 4; ++i)
#pragma unroll
    for (int j = 0; j < 4; ++j) acc[i][j] = (f32x4){0.f, 0.f, 0.f, 0.f};

  const unsigned short* Abase = A + (size_t)bm * lda;
  const unsigned short* Bbase = BT + (size_t)bn * ldb;
  auto stage = [&](int buf, int k0) {
    gload_lds16(Abase + (size_t)(wv * 16 + sr) * lda + k0 + sk, &As[buf][wv * 512]);
    gload_lds16(Abase + (size_t)(64 + wv * 16 + sr) * lda + k0 + sk, &As[buf][2048 + wv * 512]);
    gload_lds16(Bbase + (size_t)(wv * 16 + sr) * ldb + k0 + sk, &Bs[buf][wv * 512]);
    gload_lds16(Bbase + (size_t)(64 + wv * 16 + sr) * ldb + k0 + sk, &Bs[buf][2048 + wv * 512]);
  };
  stage(0, base * 32);
  __syncthreads();
  int cur = 0;
  for (int ks = 0; ks < nsteps; ++ks) {
    if (ks + 1 < nsteps) stage(cur ^ 1, (base + ks + 1) * 32);
    bf16x8 af[4], bfr[4];
#pragma unroll
    for (int i = 0; i < 4; ++i)
      af[i] = *(const bf16x8*)&As[cur][(wr * 64 + i * 16 + r16) * 32 + slot8];
#pragma unroll
    for (int j = 0; j < 4; ++j)
      bfr[j] = *(const bf16x8*)&Bs[cur][(wc * 64 + j * 16 + r16) * 32 + slot8];
#pragma unroll
    for (int i = 0; i < 4; ++i)
#pragma unroll
      for (int j = 0; j < 4; ++j)
        acc[i][j] = __builtin_amdgcn_mfma_f32_16x16x32_bf16(af[i], bfr[j], acc[i][j], 0, 0, 0);
    __syncthreads();
    cur ^= 1;
  }
  float* out = PART + (size_t)s * 1024 * ldc;
#pragma unroll
  for (int i = 0; i < 4; ++i) {
    int row = bm + wr * 64 + i * 16 + kq * 4;
#pragma unroll
    for (int j = 0; j < 4; ++j) {
      int col = bn + wc * 64 + j * 16 + r16;
      if (col >= 1600) continue;
#pragma unroll
      for (int r = 0; r < 4; ++r)
        out[(size_t)(row + r) * ldc + col] = acc[i][j][r];
    }
  }
}

// reduce 16 f32 K-slice partials + bias + relu -> ZB bf16 [1024][1664]
__global__ void zred(const float* __restrict__ PART, const float* __restrict__ bias,
                     unsigned short* __restrict__ ZB) {
  int idx = blockIdx.x * blockDim.x + threadIdx.x;
  if (idx >= 1024 * 1664) return;
  int c = idx % 1664;
  if (c >= 1600) { ZB[idx] = 0; return; }
  float s = 0.f;
#pragma unroll
  for (int k = 0; k < 16; ++k) s += PART[(size_t)k * 1024 * 1664 + idx];
  s += bias[c];
  ZB[idx] = f2b(s > 0.f ? s : 0.f);
}

// ---------------- GAT pieces ----------------
__global__ void gat_scores_bf(const unsigned short* __restrict__ hlin,
                              const float* __restrict__ a_s, const float* __restrict__ a_d,
                              float* __restrict__ als, float* __restrict__ ald,
                              int H, int C, int tot) {
  int idx = blockIdx.x * blockDim.x + threadIdx.x;
  if (idx >= tot) return;
  int n = idx / H, h = idx - n * H;
  const unsigned short* base = hlin + (size_t)n * H * C + (size_t)h * C;
  const float* as = a_s + h * C;
  const float* ad = a_d + h * C;
  float ss = 0.f, sd = 0.f;
  for (int c = 0; c < C; c += 8) {
    ushort8 v = *(const ushort8*)(base + c);
#pragma unroll
    for (int t = 0; t < 8; ++t) {
      float f = b2f(v[t]);
      ss = fmaf(f, as[c + t], ss);
      sd = fmaf(f, ad[c + t], sd);
    }
  }
  als[idx] = ss;
  ald[idx] = sd;
}

template <int H>
__global__ void edge_attn(const int* __restrict__ ei, const float* __restrict__ als,
                          const float* __restrict__ ald, const int* __restrict__ pos,
                          float* __restrict__ ebs) {
  int e = blockIdx.x * blockDim.x + threadIdx.x;
  if (e >= ETOT) return;
  int src, dst;
  if (e < E0) { src = ei[e]; dst = ei[E0 + e]; } else { src = dst = e - E0; }
  int p = pos[e];
  if (H == 8) {
    float4 s0 = *(const float4*)(als + src * 8);
    float4 s1 = *(const float4*)(als + src * 8 + 4);
    float4 d0 = *(const float4*)(ald + dst * 8);
    float4 d1 = *(const float4*)(ald + dst * 8 + 4);
    float ev[8] = {s0.x + d0.x, s0.y + d0.y, s0.z + d0.z, s0.w + d0.w,
                   s1.x + d1.x, s1.y + d1.y, s1.z + d1.z, s1.w + d1.w};
#pragma unroll
    for (int h = 0; h < 8; ++h) {
      float v = ev[h];
      v = (v >= 0.f) ? v : 0.2f * v;
      ebs[(size_t)p * 8 + h] = __expf(v);
    }
  } else {
    float v = als[src] + ald[dst];
    v = (v >= 0.f) ? v : 0.2f * v;
    ebs[p] = __expf(v);
  }
}

template <int F, int C>
__global__ __launch_bounds__(256) void gat_agg_v3(
    const int* __restrict__ rowptr, const float* __restrict__ ebs,
    const int* __restrict__ srcl, const unsigned short* __restrict__ hlin,
    const float* __restrict__ bias, unsigned short* __restrict__ out) {
  constexpr int H = F / C;
  constexpr int CPN = F / 8;
  int gidx = blockIdx.x * 256 + threadIdx.x;
  if (gidx >= NN * CPN) return;
  int node = gidx / CPN;
  int c0 = (gidx - node * CPN) * 8;
  int h = c0 / C;
  float s = 0.f;
  float acc[8] = {0.f, 0.f, 0.f, 0.f, 0.f, 0.f, 0.f, 0.f};
  int start = rowptr[node], end = rowptr[node + 1];
  for (int k = start; k < end; ++k) {
    int src = srcl[k];
    float p = ebs[(size_t)k * H + h];
    s += p;
    ushort8 hv = *(const ushort8*)(hlin + (size_t)src * F + c0);
#pragma unroll
    for (int t = 0; t < 8; ++t) acc[t] = fmaf(p, b2f(hv[t]), acc[t]);
  }
  float inv_s = 1.f / s;
  ushort8 o;
#pragma unroll
  for (int t = 0; t < 8; ++t) {
    float val = acc[t] * inv_s + bias[c0 + t];
    o[t] = f2b(val > 0.f ? val : 0.f);
  }
  *(ushort8*)(out + (size_t)node * F + c0) = o;
}

__global__ void pool_max(const unsigned short* __restrict__ xb,
                         unsigned short* __restrict__ xgb) {
  int g = blockIdx.x, c = threadIdx.x;  // 128 threads
  const unsigned short* base = xb + (size_t)g * 32 * 128 + c;
  float m = -FLT_MAX;
#pragma unroll 8
  for (int n = 0; n < 32; ++n) m = fmaxf(m, b2f(base[n * 128]));
  xgb[g * 128 + c] = f2b(m);
}

// blocks 0..NB-1: DRUG->DN ; blocks NB..NB+NSIDE-1: SE->SN
__global__ void rownorm2(const float* __restrict__ drug, const float* __restrict__ se,
                         float* __restrict__ dn, float* __restrict__ sn) {
  int b = blockIdx.x, lane = threadIdx.x;
  const float* in; float* outp; int r;
  if (b < NB) { in = drug; outp = dn; r = b; }
  else { in = se; outp = sn; r = b - NB; }
  float v = in[r * 64 + lane];
  float ss = v * v;
#pragma unroll
  for (int off = 1; off < 64; off <<= 1) ss += __shfl_xor(ss, off);
  float nrm = fmaxf(sqrtf(ss), 1e-12f);
  outp[r * 64 + lane] = v / nrm;
}

__global__ __launch_bounds__(256) void freq_k(const float* __restrict__ dn,
                                              const float* __restrict__ sn,
                                              float* __restrict__ C, int M, int N) {
  __shared__ float As[16][64];
  __shared__ float Bs[16][65];
  int tid = threadIdx.x;
  int tx = tid & 15, ty = tid >> 4;
  int bi = blockIdx.y * 16, bj = blockIdx.x * 16;
#pragma unroll
  for (int t = 0; t < 4; ++t) {
    int idx = tid * 4 + t;
    int r = idx >> 6, c = idx & 63;
    As[r][c] = (bi + r < M) ? dn[(bi + r) * 64 + c] : 0.f;
    Bs[r][c] = (bj + r < N) ? sn[(bj + r) * 64 + c] : 0.f;
  }
  __syncthreads();
  float acc = 0.f;
#pragma unroll
  for (int k = 0; k < 64; ++k) acc = fmaf(As[ty][k], Bs[tx][k], acc);
  if (bi + ty < M && bj + tx < N) C[(size_t)(bi + ty) * N + (bj + tx)] = 5.f * acc;
}

// ---------------- launch ----------------
extern "C" void kernel_launch(void* const* d_in, const int* in_sizes, int n_in,
                              void* d_out, int out_size, void* d_ws, size_t ws_size,
                              hipStream_t stream) {
  const float* x = (const float*)d_in[0];
  const int* ei = (const int*)d_in[1];
  const float* w = (const float*)d_in[3];
  const float* z = (const float*)d_in[4];
  const float* v = (const float*)d_in[5];
  const float* side = (const float*)d_in[6];
  const float* gW[4] = {(const float*)d_in[7], (const float*)d_in[11],
                        (const float*)d_in[15], (const float*)d_in[19]};
  const float* gas[4] = {(const float*)d_in[8], (const float*)d_in[12],
                         (const float*)d_in[16], (const float*)d_in[20]};
  const float* gad[4] = {(const float*)d_in[9], (const float*)d_in[13],
                         (const float*)d_in[17], (const float*)d_in[21]};
  const float* gb[4] = {(const float*)d_in[10], (const float*)d_in[14],
                        (const float*)d_in[18], (const float*)d_in[22]};
  const float* x5_W = (const float*)d_in[23]; const float* x5_b = (const float*)d_in[24];
  const float* x6_W = (const float*)d_in[25]; const float* x6_b = (const float*)d_in[26];
  const float* w1_W = (const float*)d_in[27]; const float* w1_b = (const float*)d_in[28];
  const float* w2_W = (const float*)d_in[29]; const float* w2_b = (const float*)d_in[30];
  const float* z1_W = (const float*)d_in[31]; const float* z1_b = (const float*)d_in[32];
  const float* z2_W = (const float*)d_in[33]; const float* z2_b = (const float*)d_in[34];
  const float* v1_W = (const float*)d_in[35]; const float* v1_b = (const float*)d_in[36];
  const float* v2_W = (const float*)d_in[37]; const float* v2_b = (const float*)d_in[38];
  const float* agg_W = (const float*)d_in[39]; const float* agg_b = (const float*)d_in[40];
  const float* col_W = (const float*)d_in[41]; const float* col_b = (const float*)d_in[42];
  const float* s1_W = (const float*)d_in[43]; const float* s1_b = (const float*)d_in[44];
  const float* s2_W = (const float*)d_in[45]; const float* s2_b = (const float*)d_in[46];

  char* wsb = (char*)d_ws;
  size_t off = 0;
  auto alloc = [&](size_t bytes) {
    void* p = wsb + off;
    off = (off + bytes + 255) & ~(size_t)255;
    return p;
  };
  unsigned short* HLIN = (unsigned short*)alloc((size_t)NN * 1024 * 2);
  unsigned short* XB = (unsigned short*)alloc((size_t)NN * 1024 * 2);
  unsigned short* WTZ = (unsigned short*)alloc((size_t)1664 * 19136 * 2);
  unsigned short* ZA = (unsigned short*)alloc((size_t)1024 * 19136 * 2);
  unsigned short* WT1 = (unsigned short*)alloc((size_t)768 * 128 * 2);
  unsigned short* WT2 = (unsigned short*)alloc((size_t)1024 * 768 * 2);
  unsigned short* WT3 = (unsigned short*)alloc((size_t)1024 * 1024 * 2);
  unsigned short* WT4 = (unsigned short*)alloc((size_t)128 * 1024 * 2);
  unsigned short* WTW1 = (unsigned short*)alloc((size_t)768 * 768 * 2);
  unsigned short* WTW2 = (unsigned short*)alloc((size_t)128 * 768 * 2);
  unsigned short* WTZ2 = (unsigned short*)alloc((size_t)128 * 1664 * 2);
  unsigned short* WTV1 = (unsigned short*)alloc((size_t)256 * 1024 * 2);
  unsigned short* WTV2 = (unsigned short*)alloc((size_t)128 * 256 * 2);
  unsigned short* WTX5 = (unsigned short*)alloc((size_t)128 * 128 * 2);
  unsigned short* WTX6 = (unsigned short*)alloc((size_t)128 * 64 * 2);
  unsigned short* WTAGG = (unsigned short*)alloc((size_t)128 * 192 * 2);
  unsigned short* WTCOL = (unsigned short*)alloc((size_t)128 * 128 * 2);
  unsigned short* WTS1 = (unsigned short*)alloc((size_t)128 * 1056 * 2);
  unsigned short* WTS2 = (unsigned short*)alloc((size_t)128 * 64 * 2);
  unsigned short* WB = (unsigned short*)alloc((size_t)1024 * 768 * 2);
  unsigned short* VB = (unsigned short*)alloc((size_t)1024 * 1024 * 2);
  unsigned short* SIDEB = (unsigned short*)alloc((size_t)1024 * 1056 * 2);
  unsigned short* XGB = (unsigned short*)alloc((size_t)1024 * 128 * 2);
  unsigned short* ZB = (unsigned short*)alloc((size_t)1024 * 1664 * 2);
  unsigned short* X5O = (unsigned short*)alloc((size_t)1024 * 128 * 2);
  unsigned short* WMID = (unsigned short*)alloc((size_t)1024 * 768 * 2);
  unsigned short* VMID = (unsigned short*)alloc((size_t)1024 * 256 * 2);
  unsigned short* SEMID = (unsigned short*)alloc((size_t)1024 * 128 * 2);
  unsigned short* CAT192 = (unsigned short*)alloc((size_t)1024 * 192 * 2);
  unsigned short* CAT128 = (unsigned short*)alloc((size_t)1024 * 128 * 2);
  float* EBS = (float*)alloc((size_t)ETOT * 8 * 4);
  float* ALS = (float*)alloc((size_t)NN * 8 * 4);
  float* ALD = (float*)alloc((size_t)NN * 8 * 4);
  float* DRUG = (float*)alloc((size_t)NB * 64 * 4);
  float* SE = (float*)alloc((size_t)1024 * 64 * 4);
  int* DEG = (int*)alloc((size_t)NN * 4);
  int* ROWPTR = (int*)alloc((size_t)(NN + 1) * 4);
  int* CURSOR = (int*)alloc((size_t)NN * 4);
  int* SRCL = (int*)alloc((size_t)ETOT * 4);
  int* POS = (int*)alloc((size_t)ETOT * 4);
  float* PART = (float*)HLIN;  // 109MB over dead HLIN+XB

  // CSR build (4 launches)
  hipLaunchKernelGGL(fill_i32, dim3((NN + 255) / 256), dim3(256), 0, stream, DEG, 0, NN);
  hipLaunchKernelGGL(count_deg, dim3((ETOT + 255) / 256), dim3(256), 0, stream, ei, DEG);
  hipLaunchKernelGGL(scan_deg, dim3(1), dim3(1024), 0, stream, DEG, ROWPTR, CURSOR);
  hipLaunchKernelGGL(fill_csr, dim3((ETOT + 255) / 256), dim3(256), 0, stream, ei, CURSOR, SRCL, POS);

  // batched weight transposes (1 launch)
  {
    TBatch tb;
    int acc_wg = 0, i = 0;
    auto add = [&](const float* W, unsigned short* WT, int K, int N, int Kp, int Npad) {
      int gx = Npad / 32, gy = Kp / 32;
      acc_wg += gx * gy;
      tb.d[i++] = {W, WT, K, N, Kp, Npad, gx, acc_wg};
    };
    add(z1_W, WTZ, 19127, 1600, 19136, 1664);
    add(gW[0], WT1, 109, 768, 128, 768);
    add(gW[1], WT2, 768, 1024, 768, 1024);
    add(gW[2], WT3, 1024, 1024, 1024, 1024);
    add(gW[3], WT4, 1024, 128, 1024, 128);
    add(w1_W, WTW1, 750, 750, 768, 768);
    add(w2_W, WTW2, 750, 64, 768, 128);
    add(z2_W, WTZ2, 1600, 64, 1664, 128);
    add(v1_W, WTV1, 1024, 256, 1024, 256);
    add(v2_W, WTV2, 256, 64, 256, 128);
    add(x5_W, WTX5, 128, 64, 128, 128);
    add(x6_W, WTX6, 64, 64, 64, 128);
    add(agg_W, WTAGG, 192, 64, 192, 128);
    add(col_W, WTCOL, 128, 64, 128, 128);
    add(s1_W, WTS1, 1050, 64, 1056, 128);
    add(s2_W, WTS2, 64, 64, 64, 128);
    hipLaunchKernelGGL(transpose_batch, dim3(acc_wg), dim3(256), 0, stream, tb);
  }

  // batched input conversions (1 launch)
  {
    CBatch cb;
    int acc_wg = 0, i = 0;
    auto add = [&](const float* in, unsigned short* out, int rowsOut, int Rreal, int C, int Cp) {
      acc_wg += (int)(((size_t)rowsOut * Cp + 255) / 256);
      cb.d[i++] = {in, out, rowsOut, Rreal, C, Cp, acc_wg};
    };
    add(z, ZA, NB, NB, 19127, 19136);
    add(x, XB, NN, NN, 109, 128);
    add(w, WB, 1024, 1024, 750, 768);
    add(v, VB, 1024, 1024, 1024, 1024);
    add(side, SIDEB, 1024, 994, 1050, 1056);
    hipLaunchKernelGGL(conv_batch, dim3(acc_wg), dim3(256), 0, stream, cb);
  }

  auto mm = [&](const unsigned short* A, const unsigned short* BT,
                const float* bias, void* C, int M, int Npad, int Nreal, int K,
                int lda, int ldb, int ldc, int zpad) {
    int gx = Npad / 128;
    int nwg = gx * (M / 128);
    hipLaunchKernelGGL((gemm_mfma<0, 1>), dim3(nwg), dim3(256), 0, stream,
                       A, BT, bias, C, Nreal, K, lda, ldb, ldc, gx, zpad);
  };

  // GAT layers
  const int Hs[4] = {8, 8, 8, 1};
  const int Kp[4] = {128, 768, 1024, 1024};
  const unsigned short* WTs[4] = {WT1, WT2, WT3, WT4};
  const int Fs[4] = {768, 1024, 1024, 128};
  for (int l = 0; l < 4; ++l) {
    int H = Hs[l], F = Fs[l], C = F / H;
    mm(XB, WTs[l], nullptr, HLIN, NN, F, F, Kp[l], Kp[l], Kp[l], F, 0);
    int totNH = NN * H;
    hipLaunchKernelGGL(gat_scores_bf, dim3((totNH + 255) / 256), dim3(256), 0, stream,
                       HLIN, gas[l], gad[l], ALS, ALD, H, C, totNH);
    if (H == 8)
      hipLaunchKernelGGL((edge_attn<8>), dim3((ETOT + 255) / 256), dim3(256), 0, stream, ei, ALS, ALD, POS, EBS);
    else
      hipLaunchKernelGGL((edge_attn<1>), dim3((ETOT + 255) / 256), dim3(256), 0, stream, ei, ALS, ALD, POS, EBS);
    if (l == 0)
      hipLaunchKernelGGL((gat_agg_v3<768, 96>), dim3(NN * 96 / 256), dim3(256), 0, stream,
                         ROWPTR, EBS, SRCL, HLIN, gb[l], XB);
    else if (l == 3)
      hipLaunchKernelGGL((gat_agg_v3<128, 128>), dim3(NN * 16 / 256), dim3(256), 0, stream,
                         ROWPTR, EBS, SRCL, HLIN, gb[l], XB);
    else
      hipLaunchKernelGGL((gat_agg_v3<1024, 128>), dim3(NN * 128 / 256), dim3(256), 0, stream,
                         ROWPTR, EBS, SRCL, HLIN, gb[l], XB);
  }

  // global max pool -> XGB bf16
  hipLaunchKernelGGL(pool_max, dim3(NB), dim3(128), 0, stream, XB, XGB);

  // B1: independent tail GEMMs {w1, v1, s1, x5} (1 launch, 80 WGs)
  {
    GBatch b;
    int acc_wg = 0, i = 0;
    auto add = [&](const unsigned short* A, const unsigned short* BT, const float* bias,
                   void* C, int Npad, int Nreal, int K, int lda, int ldb, int ldc,
                   int zpad, int act, int obf) {
      int gx = Npad / 128;
      acc_wg += gx * 8;
      b.d[i++] = {A, BT, bias, C, Nreal, K, lda, ldb, ldc, gx, zpad, act, obf, acc_wg};
    };
    add(WB, WTW1, w1_b, WMID, 768, 750, 768, 768, 768, 768, 1, 1, 1);
    add(VB, WTV1, v1_b, VMID, 256, 256, 1024, 1024, 1024, 256, 0, 1, 1);
    add(SIDEB, WTS1, s1_b, SEMID, 128, 64, 1056, 1056, 1056, 128, 1, 1, 1);
    add(XGB, WTX5, x5_b, X5O, 128, 64, 128, 128, 128, 128, 1, 1, 1);
    while (i < 5) { b.d[i] = b.d[i - 1]; b.d[i].wg_end = acc_wg; ++i; }
    hipLaunchKernelGGL(gemm_batch, dim3(acc_wg), dim3(256), 0, stream, b);
  }

  // z1 split-K + reduce -> ZB bf16
  hipLaunchKernelGGL(gemm_mfma_sk, dim3(1664), dim3(256), 0, stream, ZA, WTZ, PART, 19136, 19136, 1664);
  hipLaunchKernelGGL(zred, dim3((1024 * 1664 + 255) / 256), dim3(256), 0, stream, PART, z1_b, ZB);

  // B2: {x6, w2, z2, v2, s2} (1 launch, 40 WGs)
  {
    GBatch b;
    int acc_wg = 0, i = 0;
    auto add = [&](const unsigned short* A, const unsigned short* BT, const float* bias,
                   void* C, int Npad, int Nreal, int K, int lda, int ldb, int ldc,
                   int zpad, int act, int obf) {
      int gx = Npad / 128;
      acc_wg += gx * 8;
      b.d[i++] = {A, BT, bias, C, Nreal, K, lda, ldb, ldc, gx, zpad, act, obf, acc_wg};
    };
    add(X5O, WTX6, x6_b, CAT192 + 0, 128, 64, 64, 128, 64, 192, 0, 1, 1);
    add(WMID, WTW2, w2_b, CAT192 + 64, 128, 64, 768, 768, 768, 192, 0, 1, 1);
    add(ZB, WTZ2, z2_b, CAT192 + 128, 128, 64, 1664, 1664, 1664, 192, 0, 1, 1);
    add(VMID, WTV2, v2_b, CAT128 + 64, 128, 64, 256, 256, 256, 128, 0, 1, 1);
    add(SEMID, WTS2, s2_b, SE, 128, 64, 64, 128, 64, 64, 0, 2, 0);
    hipLaunchKernelGGL(gemm_batch, dim3(acc_wg), dim3(256), 0, stream, b);
  }

  // B3: agg (needs CAT192)
  {
    GBatch b;
    b.d[0] = {CAT192, WTAGG, agg_b, CAT128 + 0, 64, 192, 192, 192, 128, 1, 0, 0, 1, 8};
    for (int i = 1; i < 5; ++i) { b.d[i] = b.d[0]; }
    hipLaunchKernelGGL(gemm_batch, dim3(8), dim3(256), 0, stream, b);
  }
  // B4: col (needs CAT128)
  {
    GBatch b;
    b.d[0] = {CAT128, WTCOL, col_b, DRUG, 64, 128, 128, 128, 64, 1, 0, 3, 0, 8};
    for (int i = 1; i < 5; ++i) { b.d[i] = b.d[0]; }
    hipLaunchKernelGGL(gemm_batch, dim3(8), dim3(256), 0, stream, b);
  }

  // normalize + similarity
  float* outp = (float*)d_out;
  float* DN = outp + (size_t)NB * NSIDE;
  float* SN = DN + (size_t)NB * 64;
  hipLaunchKernelGGL(rownorm2, dim3(NB + NSIDE), dim3(64), 0, stream, DRUG, SE, DN, SN);
  hipLaunchKernelGGL(freq_k, dim3((NSIDE + 15) / 16, (NB + 15) / 16), dim3(256), 0, stream,
                     DN, SN, outp, NB, NSIDE);
}

// Round 10
// 1010.119 us; speedup vs baseline: 1.5514x; 1.0246x over previous
//
#include <hip/hip_runtime.h>
#include <math.h>
#include <float.h>

#define E0 131072
#define NN 32768
#define NB 1024
#define NSIDE 994
#define ETOT (E0 + NN)

typedef short bf16x8 __attribute__((ext_vector_type(8)));
typedef unsigned short ushort8 __attribute__((ext_vector_type(8)));
typedef float f32x4 __attribute__((ext_vector_type(4)));

__device__ inline float b2f(unsigned short u) { return __uint_as_float(((unsigned)u) << 16); }
__device__ inline unsigned short f2b(float f) {
  unsigned u = __float_as_uint(f);
  return (unsigned short)((u + 0x7fffu + ((u >> 16) & 1u)) >> 16);
}

__device__ inline void gload_lds16(const void* g, void* l) {
  __builtin_amdgcn_global_load_lds(
      (const __attribute__((address_space(1))) unsigned int*)g,
      (__attribute__((address_space(3))) unsigned int*)l, 16, 0, 0);
}

__global__ void fill_i32(int* p, int v, int n) {
  int i = blockIdx.x * blockDim.x + threadIdx.x;
  if (i < n) p[i] = v;
}

// ---------------- batched fp32 -> bf16 conversion with padding ----------------
struct CDesc { const float* in; unsigned short* out; int rowsOut, Rreal, C, Cp, wg_end; };
struct CBatch { CDesc d[5]; };
__global__ void conv_batch(CBatch cb) {
  int bid = blockIdx.x;
  int di = 0;
  while (bid >= cb.d[di].wg_end) ++di;
  const CDesc& g = cb.d[di];
  int rel = bid - (di ? cb.d[di - 1].wg_end : 0);
  size_t idx = (size_t)rel * 256 + threadIdx.x;
  size_t tot = (size_t)g.rowsOut * g.Cp;
  if (idx >= tot) return;
  int r = (int)(idx / g.Cp), c = (int)(idx % g.Cp);
  g.out[idx] = (r < g.Rreal && c < g.C) ? f2b(g.in[(size_t)r * g.C + c]) : (unsigned short)0;
}

// ---------------- batched transpose: W [K][N] f32 -> WT [Npad][Kp] bf16 ----------------
struct TDesc { const float* W; unsigned short* WT; int K, N, Kp, Npad, gx, wg_end; };
struct TBatch { TDesc d[16]; };
__global__ __launch_bounds__(256) void transpose_batch(TBatch tb) {
  __shared__ float t[32][33];
  int bid = blockIdx.x;
  int di = 0;
  while (bid >= tb.d[di].wg_end) ++di;
  const TDesc& g = tb.d[di];
  int rel = bid - (di ? tb.d[di - 1].wg_end : 0);
  int n0 = (rel % g.gx) * 32, k0 = (rel / g.gx) * 32;
  int tx = threadIdx.x & 31, ty = threadIdx.x >> 5;
  for (int r = ty; r < 32; r += 8) {
    int k = k0 + r, n = n0 + tx;
    t[r][tx] = (k < g.K && n < g.N) ? g.W[(size_t)k * g.N + n] : 0.f;
  }
  __syncthreads();
  for (int r = ty; r < 32; r += 8) {
    int n = n0 + r, k = k0 + tx;
    if (n < g.Npad && k < g.Kp)
      g.WT[(size_t)n * g.Kp + k] = (n < g.N) ? f2b(t[tx][r]) : (unsigned short)0;
  }
}

// ---------------- CSR build over dst ----------------
__global__ void count_deg(const int* __restrict__ ei, int* deg) {
  int e = blockIdx.x * blockDim.x + threadIdx.x;
  if (e >= ETOT) return;
  int dst = (e < E0) ? ei[E0 + e] : (e - E0);
  atomicAdd(&deg[dst], 1);
}

__global__ void scan_deg(const int* __restrict__ deg, int* rowptr, int* cursor) {
  __shared__ int part[1024];
  int tid = threadIdx.x;
  const int chunk = NN / 1024;  // 32
  int base = tid * chunk;
  int local[chunk];
  int sum = 0;
#pragma unroll
  for (int i = 0; i < chunk; ++i) { local[i] = sum; sum += deg[base + i]; }
  part[tid] = sum;
  __syncthreads();
  for (int off = 1; off < 1024; off <<= 1) {
    int t = (tid >= off) ? part[tid - off] : 0;
    __syncthreads();
    part[tid] += t;
    __syncthreads();
  }
  int offset = part[tid] - sum;
#pragma unroll
  for (int i = 0; i < chunk; ++i) {
    int v = offset + local[i];
    rowptr[base + i] = v;
    cursor[base + i] = v;
  }
  if (tid == 1023) rowptr[NN] = offset + sum;
}

__global__ void fill_csr(const int* __restrict__ ei, int* cursor,
                         int* __restrict__ srcl, int* __restrict__ pos) {
  int e = blockIdx.x * blockDim.x + threadIdx.x;
  if (e >= ETOT) return;
  int src, dst;
  if (e < E0) { src = ei[e]; dst = ei[E0 + e]; } else { src = dst = e - E0; }
  int p = atomicAdd(&cursor[dst], 1);
  srcl[p] = src;
  pos[e] = p;
}

// ---------------- bf16 MFMA GEMM, 2-phase double-buffered LDS (long-K path) ----------------
template <int ACT, int OBF>
__global__ __launch_bounds__(256) void gemm_mfma(
    const unsigned short* __restrict__ A, const unsigned short* __restrict__ BT,
    const float* __restrict__ bias, void* __restrict__ Cp,
    int Nreal, int K, int lda, int ldb, int ldc, int gx, int zpad) {
  __shared__ unsigned short As[2][128 * 32];
  __shared__ unsigned short Bs[2][128 * 32];
  const int nwg = gridDim.x;
  const int chunk = nwg >> 3;
  const int bid = blockIdx.x;
  const int swz = (bid & 7) * chunk + (bid >> 3);
  const int bm = (swz / gx) * 128, bn = (swz % gx) * 128;
  const int tid = threadIdx.x;
  const int wv = tid >> 6, lane = tid & 63;
  const int sr = lane >> 2;
  const int sk = ((lane & 3) ^ ((lane >> 3) & 3)) * 8;
  const int r16 = lane & 15, kq = lane >> 4;
  const int slot8 = (kq ^ ((r16 >> 1) & 3)) * 8;
  const int wr = wv >> 1, wc = wv & 1;
  f32x4 acc[4][4];
#pragma unroll
  for (int i = 0; i < 4; ++i)
#pragma unroll
    for (int j = 0; j < 4; ++j) acc[i][j] = (f32x4){0.f, 0.f, 0.f, 0.f};

  const unsigned short* Abase = A + (size_t)bm * lda;
  const unsigned short* Bbase = BT + (size_t)bn * ldb;
  auto stage = [&](int buf, int k0) {
    gload_lds16(Abase + (size_t)(wv * 16 + sr) * lda + k0 + sk, &As[buf][wv * 512]);
    gload_lds16(Abase + (size_t)(64 + wv * 16 + sr) * lda + k0 + sk, &As[buf][2048 + wv * 512]);
    gload_lds16(Bbase + (size_t)(wv * 16 + sr) * ldb + k0 + sk, &Bs[buf][wv * 512]);
    gload_lds16(Bbase + (size_t)(64 + wv * 16 + sr) * ldb + k0 + sk, &Bs[buf][2048 + wv * 512]);
  };
  stage(0, 0);
  __syncthreads();
  int cur = 0;
  for (int k0 = 0; k0 < K; k0 += 32) {
    if (k0 + 32 < K) stage(cur ^ 1, k0 + 32);
    bf16x8 af[4], bfr[4];
#pragma unroll
    for (int i = 0; i < 4; ++i)
      af[i] = *(const bf16x8*)&As[cur][(wr * 64 + i * 16 + r16) * 32 + slot8];
#pragma unroll
    for (int j = 0; j < 4; ++j)
      bfr[j] = *(const bf16x8*)&Bs[cur][(wc * 64 + j * 16 + r16) * 32 + slot8];
#pragma unroll
    for (int i = 0; i < 4; ++i)
#pragma unroll
      for (int j = 0; j < 4; ++j)
        acc[i][j] = __builtin_amdgcn_mfma_f32_16x16x32_bf16(af[i], bfr[j], acc[i][j], 0, 0, 0);
    __syncthreads();
    cur ^= 1;
  }
#pragma unroll
  for (int i = 0; i < 4; ++i) {
    int row = bm + wr * 64 + i * 16 + kq * 4;
#pragma unroll
    for (int j = 0; j < 4; ++j) {
      int col = bn + wc * 64 + j * 16 + r16;
      bool real = col < Nreal;
      if (!real && !zpad) continue;
      float bv = (bias && real) ? bias[col] : 0.f;
#pragma unroll
      for (int r = 0; r < 4; ++r) {
        float v = acc[i][j][r] + bv;
        if (ACT == 1) v = v > 0.f ? v : 0.f;
        else if (ACT == 2) v = tanhf(v);
        else if (ACT == 3) v = fabsf(tanhf(v));
        if (!real) v = 0.f;
        if (OBF) ((unsigned short*)Cp)[(size_t)(row + r) * ldc + col] = f2b(v);
        else ((float*)Cp)[(size_t)(row + r) * ldc + col] = v;
      }
    }
  }
}

// ---------------- batched runtime-act MFMA GEMM (2-phase dbuf) ----------------
// act: 0 none, 1 relu, 2 tanh, 3 abs(tanh), 4 tanh+rownorm (f32 out, row<Mreal guard)
struct GDesc {
  const unsigned short* A; const unsigned short* BT; const float* bias; void* C;
  int Nreal, K, lda, ldb, ldc, gx, zpad, act, obf, Mreal, wg_end;
};
struct GBatch { GDesc d[5]; };
__global__ __launch_bounds__(256) void gemm_batch(GBatch gb) {
  __shared__ unsigned short As[2][128 * 32];
  __shared__ unsigned short Bs[2][128 * 32];
  int bid = blockIdx.x;
  int di = 0;
  while (bid >= gb.d[di].wg_end) ++di;
  const GDesc& g = gb.d[di];
  int rel = bid - (di ? gb.d[di - 1].wg_end : 0);
  const int bm = (rel / g.gx) * 128, bn = (rel % g.gx) * 128;
  const int tid = threadIdx.x;
  const int wv = tid >> 6, lane = tid & 63;
  const int sr = lane >> 2;
  const int sk = ((lane & 3) ^ ((lane >> 3) & 3)) * 8;
  const int r16 = lane & 15, kq = lane >> 4;
  const int slot8 = (kq ^ ((r16 >> 1) & 3)) * 8;
  const int wr = wv >> 1, wc = wv & 1;
  f32x4 acc[4][4];
#pragma unroll
  for (int i = 0; i < 4; ++i)
#pragma unroll
    for (int j = 0; j < 4; ++j) acc[i][j] = (f32x4){0.f, 0.f, 0.f, 0.f};

  const unsigned short* Abase = g.A + (size_t)bm * g.lda;
  const unsigned short* Bbase = g.BT + (size_t)bn * g.ldb;
  auto stage = [&](int buf, int k0) {
    gload_lds16(Abase + (size_t)(wv * 16 + sr) * g.lda + k0 + sk, &As[buf][wv * 512]);
    gload_lds16(Abase + (size_t)(64 + wv * 16 + sr) * g.lda + k0 + sk, &As[buf][2048 + wv * 512]);
    gload_lds16(Bbase + (size_t)(wv * 16 + sr) * g.ldb + k0 + sk, &Bs[buf][wv * 512]);
    gload_lds16(Bbase + (size_t)(64 + wv * 16 + sr) * g.ldb + k0 + sk, &Bs[buf][2048 + wv * 512]);
  };
  stage(0, 0);
  __syncthreads();
  int cur = 0;
  for (int k0 = 0; k0 < g.K; k0 += 32) {
    if (k0 + 32 < g.K) stage(cur ^ 1, k0 + 32);
    bf16x8 af[4], bfr[4];
#pragma unroll
    for (int i = 0; i < 4; ++i)
      af[i] = *(const bf16x8*)&As[cur][(wr * 64 + i * 16 + r16) * 32 + slot8];
#pragma unroll
    for (int j = 0; j < 4; ++j)
      bfr[j] = *(const bf16x8*)&Bs[cur][(wc * 64 + j * 16 + r16) * 32 + slot8];
#pragma unroll
    for (int i = 0; i < 4; ++i)
#pragma unroll
      for (int j = 0; j < 4; ++j)
        acc[i][j] = __builtin_amdgcn_mfma_f32_16x16x32_bf16(af[i], bfr[j], acc[i][j], 0, 0, 0);
    __syncthreads();
    cur ^= 1;
  }
  if (g.act == 4) {
    // tanh + row-normalize (Nreal=64: full row lives in one 16-lane group x 4 j)
    if (wc == 0) {
#pragma unroll
      for (int i = 0; i < 4; ++i)
#pragma unroll
        for (int r = 0; r < 4; ++r) {
          int row = bm + wr * 64 + i * 16 + kq * 4 + r;
          float vv[4];
#pragma unroll
          for (int j = 0; j < 4; ++j) vv[j] = tanhf(acc[i][j][r] + g.bias[j * 16 + r16]);
          float ss = vv[0] * vv[0] + vv[1] * vv[1] + vv[2] * vv[2] + vv[3] * vv[3];
          ss += __shfl_xor(ss, 1);
          ss += __shfl_xor(ss, 2);
          ss += __shfl_xor(ss, 4);
          ss += __shfl_xor(ss, 8);
          float inv = 1.f / fmaxf(sqrtf(ss), 1e-12f);
          if (row < g.Mreal)
#pragma unroll
            for (int j = 0; j < 4; ++j)
              ((float*)g.C)[(size_t)row * g.ldc + j * 16 + r16] = vv[j] * inv;
        }
    }
    return;
  }
#pragma unroll
  for (int i = 0; i < 4; ++i) {
    int row = bm + wr * 64 + i * 16 + kq * 4;
#pragma unroll
    for (int j = 0; j < 4; ++j) {
      int col = bn + wc * 64 + j * 16 + r16;
      bool real = col < g.Nreal;
      if (!real && !g.zpad) continue;
      float bv = (g.bias && real) ? g.bias[col] : 0.f;
#pragma unroll
      for (int r = 0; r < 4; ++r) {
        float v = acc[i][j][r] + bv;
        if (g.act == 1) v = v > 0.f ? v : 0.f;
        else if (g.act == 2) v = tanhf(v);
        else if (g.act == 3) v = fabsf(tanhf(v));
        if (!real) v = 0.f;
        if (g.obf) ((unsigned short*)g.C)[(size_t)(row + r) * g.ldc + col] = f2b(v);
        else ((float*)g.C)[(size_t)(row + r) * g.ldc + col] = v;
      }
    }
  }
}

// ---------------- split-K MFMA GEMM for z1 (single-buffer, bf16 partials) ----------------
// 16 K-slices, grid=1664; XCD-chunk: each XCD owns 2 whole K-slices.
__global__ __launch_bounds__(256) void gemm_mfma_sk(
    const unsigned short* __restrict__ A, const unsigned short* __restrict__ BT,
    unsigned short* __restrict__ PART, int lda, int ldb, int ldc) {
  __shared__ unsigned short As[128 * 32];
  __shared__ unsigned short Bs[128 * 32];
  const int bid = blockIdx.x;
  const int swz = (bid & 7) * 208 + (bid >> 3);
  const int s = swz / 104;
  const int pos = swz - s * 104;
  const int bm = (pos / 13) * 128, bn = (pos % 13) * 128;
  const int base = s * 37 + (s < 6 ? s : 6);
  const int nsteps = 37 + (s < 6 ? 1 : 0);
  const int tid = threadIdx.x;
  const int wv = tid >> 6, lane = tid & 63;
  const int sr = lane >> 2;
  const int sk = ((lane & 3) ^ ((lane >> 3) & 3)) * 8;
  const int r16 = lane & 15, kq = lane >> 4;
  const int slot8 = (kq ^ ((r16 >> 1) & 3)) * 8;
  const int wr = wv >> 1, wc = wv & 1;
  f32x4 acc[4][4];
#pragma unroll
  for (int i = 0; i < 4; ++i)
#pragma unroll
    for (int j = 0; j < 4; ++j) acc[i][j] = (f32x4){0.f, 0.f, 0.f, 0.f};

  const unsigned short* Abase = A + (size_t)bm * lda;
  const unsigned short* Bbase = BT + (size_t)bn * ldb;
  for (int ks = 0; ks < nsteps; ++ks) {
    int k0 = (base + ks) * 32;
    gload_lds16(Abase + (size_t)(wv * 16 + sr) * lda + k0 + sk, &As[wv * 512]);
    gload_lds16(Abase + (size_t)(64 + wv * 16 + sr) * lda + k0 + sk, &As[2048 + wv * 512]);
    gload_lds16(Bbase + (size_t)(wv * 16 + sr) * ldb + k0 + sk, &Bs[wv * 512]);
    gload_lds16(Bbase + (size_t)(64 + wv * 16 + sr) * ldb + k0 + sk, &Bs[2048 + wv * 512]);
    __syncthreads();
    bf16x8 af[4], bfr[4];
#pragma unroll
    for (int i = 0; i < 4; ++i)
      af[i] = *(const bf16x8*)&As[(wr * 64 + i * 16 + r16) * 32 + slot8];
#pragma unroll
    for (int j = 0; j < 4; ++j)
      bfr[j] = *(const bf16x8*)&Bs[(wc * 64 + j * 16 + r16) * 32 + slot8];
#pragma unroll
    for (int i = 0; i < 4; ++i)
#pragma unroll
      for (int j = 0; j < 4; ++j)
        acc[i][j] = __builtin_amdgcn_mfma_f32_16x16x32_bf16(af[i], bfr[j], acc[i][j], 0, 0, 0);
    __syncthreads();
  }
  unsigned short* out = PART + (size_t)s * 1024 * ldc;
#pragma unroll
  for (int i = 0; i < 4; ++i) {
    int row = bm + wr * 64 + i * 16 + kq * 4;
#pragma unroll
    for (int j = 0; j < 4; ++j) {
      int col = bn + wc * 64 + j * 16 + r16;
      if (col >= 1600) continue;
#pragma unroll
      for (int r = 0; r < 4; ++r)
        out[(size_t)(row + r) * ldc + col] = f2b(acc[i][j][r]);
    }
  }
}

// reduce 16 bf16 K-slice partials + bias + relu -> ZB bf16 [1024][1664], ushort8 vectorized
__global__ void zred(const unsigned short* __restrict__ PART, const float* __restrict__ bias,
                     unsigned short* __restrict__ ZB) {
  int g = blockIdx.x * blockDim.x + threadIdx.x;
  if (g >= 1024 * 1664 / 8) return;
  size_t base = (size_t)g * 8;
  int c0 = (int)(base % 1664);
  ushort8 o;
  if (c0 >= 1600) {
#pragma unroll
    for (int t = 0; t < 8; ++t) o[t] = 0;
  } else {
    float s[8] = {0.f, 0.f, 0.f, 0.f, 0.f, 0.f, 0.f, 0.f};
#pragma unroll
    for (int k = 0; k < 16; ++k) {
      ushort8 p = *(const ushort8*)&PART[(size_t)k * 1024 * 1664 + base];
#pragma unroll
      for (int t = 0; t < 8; ++t) s[t] += b2f(p[t]);
    }
#pragma unroll
    for (int t = 0; t < 8; ++t) {
      float v = s[t] + bias[c0 + t];
      o[t] = f2b(v > 0.f ? v : 0.f);
    }
  }
  *(ushort8*)&ZB[base] = o;
}

// ---------------- fused tail: agg GEMM -> LDS -> col GEMM -> |tanh| -> rownorm -> DN ----
__global__ __launch_bounds__(256) void tail_fused(
    const unsigned short* __restrict__ CAT192, const unsigned short* __restrict__ WTAGG,
    const float* __restrict__ agg_b, const unsigned short* __restrict__ CAT128,
    const unsigned short* __restrict__ WTCOL, const float* __restrict__ col_b,
    float* __restrict__ DN) {
  __shared__ unsigned short S1[128 * 32];
  __shared__ unsigned short S2[128 * 32];
  __shared__ unsigned short ACAT[128 * 128];
  const int bm = blockIdx.x * 128;
  const int tid = threadIdx.x;
  const int wv = tid >> 6, lane = tid & 63;
  const int sr = lane >> 2;
  const int sk = ((lane & 3) ^ ((lane >> 3) & 3)) * 8;
  const int r16 = lane & 15, kq = lane >> 4;
  const int slot8 = (kq ^ ((r16 >> 1) & 3)) * 8;
  const int wr = wv >> 1, wc = wv & 1;
  f32x4 acc[4][4];
#pragma unroll
  for (int i = 0; i < 4; ++i)
#pragma unroll
    for (int j = 0; j < 4; ++j) acc[i][j] = (f32x4){0.f, 0.f, 0.f, 0.f};

  // phase 1: agg = CAT192[bm..bm+128) @ WTAGG^T, K=192
  const unsigned short* Abase = CAT192 + (size_t)bm * 192;
  for (int k0 = 0; k0 < 192; k0 += 32) {
    gload_lds16(Abase + (size_t)(wv * 16 + sr) * 192 + k0 + sk, &S1[wv * 512]);
    gload_lds16(Abase + (size_t)(64 + wv * 16 + sr) * 192 + k0 + sk, &S1[2048 + wv * 512]);
    gload_lds16(WTAGG + (size_t)(wv * 16 + sr) * 192 + k0 + sk, &S2[wv * 512]);
    gload_lds16(WTAGG + (size_t)(64 + wv * 16 + sr) * 192 + k0 + sk, &S2[2048 + wv * 512]);
    __syncthreads();
    bf16x8 af[4], bfr[4];
#pragma unroll
    for (int i = 0; i < 4; ++i)
      af[i] = *(const bf16x8*)&S1[(wr * 64 + i * 16 + r16) * 32 + slot8];
#pragma unroll
    for (int j = 0; j < 4; ++j)
      bfr[j] = *(const bf16x8*)&S2[(wc * 64 + j * 16 + r16) * 32 + slot8];
#pragma unroll
    for (int i = 0; i < 4; ++i)
#pragma unroll
      for (int j = 0; j < 4; ++j)
        acc[i][j] = __builtin_amdgcn_mfma_f32_16x16x32_bf16(af[i], bfr[j], acc[i][j], 0, 0, 0);
    __syncthreads();
  }
  // store agg (cols 0-63, no act) into ACAT; copy v2 output (cols 64-127) from CAT128
  if (wc == 0) {
#pragma unroll
    for (int i = 0; i < 4; ++i)
#pragma unroll
      for (int j = 0; j < 4; ++j) {
        int col = j * 16 + r16;  // < 64
#pragma unroll
        for (int r = 0; r < 4; ++r) {
          int rl = wr * 64 + i * 16 + kq * 4 + r;
          ACAT[rl * 128 + col] = f2b(acc[i][j][r] + agg_b[col]);
        }
      }
  }
  for (int idx = tid; idx < 128 * 8; idx += 256) {
    int row = idx >> 3, c8 = (idx & 7) * 8;
    *(ushort8*)&ACAT[row * 128 + 64 + c8] =
        *(const ushort8*)&CAT128[(size_t)(bm + row) * 128 + 64 + c8];
  }
#pragma unroll
  for (int i = 0; i < 4; ++i)
#pragma unroll
    for (int j = 0; j < 4; ++j) acc[i][j] = (f32x4){0.f, 0.f, 0.f, 0.f};
  __syncthreads();

  // phase 2: col GEMM, K=128; A = ACAT (LDS, linear), B = WTCOL staged
  for (int k0 = 0; k0 < 128; k0 += 32) {
    gload_lds16(WTCOL + (size_t)(wv * 16 + sr) * 128 + k0 + sk, &S1[wv * 512]);
    gload_lds16(WTCOL + (size_t)(64 + wv * 16 + sr) * 128 + k0 + sk, &S1[2048 + wv * 512]);
    __syncthreads();
    bf16x8 af[4], bfr[4];
#pragma unroll
    for (int i = 0; i < 4; ++i)
      af[i] = *(const bf16x8*)&ACAT[(wr * 64 + i * 16 + r16) * 128 + k0 + kq * 8];
#pragma unroll
    for (int j = 0; j < 4; ++j)
      bfr[j] = *(const bf16x8*)&S1[(wc * 64 + j * 16 + r16) * 32 + slot8];
#pragma unroll
    for (int i = 0; i < 4; ++i)
#pragma unroll
      for (int j = 0; j < 4; ++j)
        acc[i][j] = __builtin_amdgcn_mfma_f32_16x16x32_bf16(af[i], bfr[j], acc[i][j], 0, 0, 0);
    __syncthreads();
  }
  // epilogue: |tanh| + rownorm -> DN (all rows real, cols 0-63)
  if (wc == 0) {
#pragma unroll
    for (int i = 0; i < 4; ++i)
#pragma unroll
      for (int r = 0; r < 4; ++r) {
        int row = bm + wr * 64 + i * 16 + kq * 4 + r;
        float vv[4];
#pragma unroll
        for (int j = 0; j < 4; ++j) vv[j] = fabsf(tanhf(acc[i][j][r] + col_b[j * 16 + r16]));
        float ss = vv[0] * vv[0] + vv[1] * vv[1] + vv[2] * vv[2] + vv[3] * vv[3];
        ss += __shfl_xor(ss, 1);
        ss += __shfl_xor(ss, 2);
        ss += __shfl_xor(ss, 4);
        ss += __shfl_xor(ss, 8);
        float inv = 1.f / fmaxf(sqrtf(ss), 1e-12f);
#pragma unroll
        for (int j = 0; j < 4; ++j)
          DN[(size_t)row * 64 + j * 16 + r16] = vv[j] * inv;
      }
  }
}

// ---------------- GAT pieces ----------------
__global__ void gat_scores_bf(const unsigned short* __restrict__ hlin,
                              const float* __restrict__ a_s, const float* __restrict__ a_d,
                              float* __restrict__ als, float* __restrict__ ald,
                              int H, int C, int tot) {
  int idx = blockIdx.x * blockDim.x + threadIdx.x;
  if (idx >= tot) return;
  int n = idx / H, h = idx - n * H;
  const unsigned short* base = hlin + (size_t)n * H * C + (size_t)h * C;
  const float* as = a_s + h * C;
  const float* ad = a_d + h * C;
  float ss = 0.f, sd = 0.f;
  for (int c = 0; c < C; c += 8) {
    ushort8 v = *(const ushort8*)(base + c);
#pragma unroll
    for (int t = 0; t < 8; ++t) {
      float f = b2f(v[t]);
      ss = fmaf(f, as[c + t], ss);
      sd = fmaf(f, ad[c + t], sd);
    }
  }
  als[idx] = ss;
  ald[idx] = sd;
}

template <int H>
__global__ void edge_attn(const int* __restrict__ ei, const float* __restrict__ als,
                          const float* __restrict__ ald, const int* __restrict__ pos,
                          float* __restrict__ ebs) {
  int e = blockIdx.x * blockDim.x + threadIdx.x;
  if (e >= ETOT) return;
  int src, dst;
  if (e < E0) { src = ei[e]; dst = ei[E0 + e]; } else { src = dst = e - E0; }
  int p = pos[e];
  if (H == 8) {
    float4 s0 = *(const float4*)(als + src * 8);
    float4 s1 = *(const float4*)(als + src * 8 + 4);
    float4 d0 = *(const float4*)(ald + dst * 8);
    float4 d1 = *(const float4*)(ald + dst * 8 + 4);
    float ev[8] = {s0.x + d0.x, s0.y + d0.y, s0.z + d0.z, s0.w + d0.w,
                   s1.x + d1.x, s1.y + d1.y, s1.z + d1.z, s1.w + d1.w};
#pragma unroll
    for (int h = 0; h < 8; ++h) {
      float v = ev[h];
      v = (v >= 0.f) ? v : 0.2f * v;
      ebs[(size_t)p * 8 + h] = __expf(v);
    }
  } else {
    float v = als[src] + ald[dst];
    v = (v >= 0.f) ? v : 0.2f * v;
    ebs[p] = __expf(v);
  }
}

template <int F, int C>
__global__ __launch_bounds__(256) void gat_agg_v3(
    const int* __restrict__ rowptr, const float* __restrict__ ebs,
    const int* __restrict__ srcl, const unsigned short* __restrict__ hlin,
    const float* __restrict__ bias, unsigned short* __restrict__ out) {
  constexpr int H = F / C;
  constexpr int CPN = F / 8;
  int gidx = blockIdx.x * 256 + threadIdx.x;
  if (gidx >= NN * CPN) return;
  int node = gidx / CPN;
  int c0 = (gidx - node * CPN) * 8;
  int h = c0 / C;
  float s = 0.f;
  float acc[8] = {0.f, 0.f, 0.f, 0.f, 0.f, 0.f, 0.f, 0.f};
  int start = rowptr[node], end = rowptr[node + 1];
  for (int k = start; k < end; ++k) {
    int src = srcl[k];
    float p = ebs[(size_t)k * H + h];
    s += p;
    ushort8 hv = *(const ushort8*)(hlin + (size_t)src * F + c0);
#pragma unroll
    for (int t = 0; t < 8; ++t) acc[t] = fmaf(p, b2f(hv[t]), acc[t]);
  }
  float inv_s = 1.f / s;
  ushort8 o;
#pragma unroll
  for (int t = 0; t < 8; ++t) {
    float val = acc[t] * inv_s + bias[c0 + t];
    o[t] = f2b(val > 0.f ? val : 0.f);
  }
  *(ushort8*)(out + (size_t)node * F + c0) = o;
}

__global__ void pool_max(const unsigned short* __restrict__ xb,
                         unsigned short* __restrict__ xgb) {
  int g = blockIdx.x, c = threadIdx.x;  // 128 threads
  const unsigned short* base = xb + (size_t)g * 32 * 128 + c;
  float m = -FLT_MAX;
#pragma unroll 8
  for (int n = 0; n < 32; ++n) m = fmaxf(m, b2f(base[n * 128]));
  xgb[g * 128 + c] = f2b(m);
}

__global__ __launch_bounds__(256) void freq_k(const float* __restrict__ dn,
                                              const float* __restrict__ sn,
                                              float* __restrict__ C, int M, int N) {
  __shared__ float As[16][64];
  __shared__ float Bs[16][65];
  int tid = threadIdx.x;
  int tx = tid & 15, ty = tid >> 4;
  int bi = blockIdx.y * 16, bj = blockIdx.x * 16;
#pragma unroll
  for (int t = 0; t < 4; ++t) {
    int idx = tid * 4 + t;
    int r = idx >> 6, c = idx & 63;
    As[r][c] = (bi + r < M) ? dn[(bi + r) * 64 + c] : 0.f;
    Bs[r][c] = (bj + r < N) ? sn[(bj + r) * 64 + c] : 0.f;
  }
  __syncthreads();
  float acc = 0.f;
#pragma unroll
  for (int k = 0; k < 64; ++k) acc = fmaf(As[ty][k], Bs[tx][k], acc);
  if (bi + ty < M && bj + tx < N) C[(size_t)(bi + ty) * N + (bj + tx)] = 5.f * acc;
}

// ---------------- launch ----------------
extern "C" void kernel_launch(void* const* d_in, const int* in_sizes, int n_in,
                              void* d_out, int out_size, void* d_ws, size_t ws_size,
                              hipStream_t stream) {
  const float* x = (const float*)d_in[0];
  const int* ei = (const int*)d_in[1];
  const float* w = (const float*)d_in[3];
  const float* z = (const float*)d_in[4];
  const float* v = (const float*)d_in[5];
  const float* side = (const float*)d_in[6];
  const float* gW[4] = {(const float*)d_in[7], (const float*)d_in[11],
                        (const float*)d_in[15], (const float*)d_in[19]};
  const float* gas[4] = {(const float*)d_in[8], (const float*)d_in[12],
                         (const float*)d_in[16], (const float*)d_in[20]};
  const float* gad[4] = {(const float*)d_in[9], (const float*)d_in[13],
                         (const float*)d_in[17], (const float*)d_in[21]};
  const float* gb[4] = {(const float*)d_in[10], (const float*)d_in[14],
                        (const float*)d_in[18], (const float*)d_in[22]};
  const float* x5_W = (const float*)d_in[23]; const float* x5_b = (const float*)d_in[24];
  const float* x6_W = (const float*)d_in[25]; const float* x6_b = (const float*)d_in[26];
  const float* w1_W = (const float*)d_in[27]; const float* w1_b = (const float*)d_in[28];
  const float* w2_W = (const float*)d_in[29]; const float* w2_b = (const float*)d_in[30];
  const float* z1_W = (const float*)d_in[31]; const float* z1_b = (const float*)d_in[32];
  const float* z2_W = (const float*)d_in[33]; const float* z2_b = (const float*)d_in[34];
  const float* v1_W = (const float*)d_in[35]; const float* v1_b = (const float*)d_in[36];
  const float* v2_W = (const float*)d_in[37]; const float* v2_b = (const float*)d_in[38];
  const float* agg_W = (const float*)d_in[39]; const float* agg_b = (const float*)d_in[40];
  const float* col_W = (const float*)d_in[41]; const float* col_b = (const float*)d_in[42];
  const float* s1_W = (const float*)d_in[43]; const float* s1_b = (const float*)d_in[44];
  const float* s2_W = (const float*)d_in[45]; const float* s2_b = (const float*)d_in[46];

  char* wsb = (char*)d_ws;
  size_t off = 0;
  auto alloc = [&](size_t bytes) {
    void* p = wsb + off;
    off = (off + bytes + 255) & ~(size_t)255;
    return p;
  };
  unsigned short* HLIN = (unsigned short*)alloc((size_t)NN * 1024 * 2);
  unsigned short* XB = (unsigned short*)alloc((size_t)NN * 1024 * 2);
  unsigned short* WTZ = (unsigned short*)alloc((size_t)1664 * 19136 * 2);
  unsigned short* ZA = (unsigned short*)alloc((size_t)1024 * 19136 * 2);
  unsigned short* WT1 = (unsigned short*)alloc((size_t)768 * 128 * 2);
  unsigned short* WT2 = (unsigned short*)alloc((size_t)1024 * 768 * 2);
  unsigned short* WT3 = (unsigned short*)alloc((size_t)1024 * 1024 * 2);
  unsigned short* WT4 = (unsigned short*)alloc((size_t)128 * 1024 * 2);
  unsigned short* WTW1 = (unsigned short*)alloc((size_t)768 * 768 * 2);
  unsigned short* WTW2 = (unsigned short*)alloc((size_t)128 * 768 * 2);
  unsigned short* WTZ2 = (unsigned short*)alloc((size_t)128 * 1664 * 2);
  unsigned short* WTV1 = (unsigned short*)alloc((size_t)256 * 1024 * 2);
  unsigned short* WTV2 = (unsigned short*)alloc((size_t)128 * 256 * 2);
  unsigned short* WTX5 = (unsigned short*)alloc((size_t)128 * 128 * 2);
  unsigned short* WTX6 = (unsigned short*)alloc((size_t)128 * 64 * 2);
  unsigned short* WTAGG = (unsigned short*)alloc((size_t)128 * 192 * 2);
  unsigned short* WTCOL = (unsigned short*)alloc((size_t)128 * 128 * 2);
  unsigned short* WTS1 = (unsigned short*)alloc((size_t)128 * 1056 * 2);
  unsigned short* WTS2 = (unsigned short*)alloc((size_t)128 * 64 * 2);
  unsigned short* WB = (unsigned short*)alloc((size_t)1024 * 768 * 2);
  unsigned short* VB = (unsigned short*)alloc((size_t)1024 * 1024 * 2);
  unsigned short* SIDEB = (unsigned short*)alloc((size_t)1024 * 1056 * 2);
  unsigned short* XGB = (unsigned short*)alloc((size_t)1024 * 128 * 2);
  unsigned short* ZB = (unsigned short*)alloc((size_t)1024 * 1664 * 2);
  unsigned short* X5O = (unsigned short*)alloc((size_t)1024 * 128 * 2);
  unsigned short* WMID = (unsigned short*)alloc((size_t)1024 * 768 * 2);
  unsigned short* VMID = (unsigned short*)alloc((size_t)1024 * 256 * 2);
  unsigned short* SEMID = (unsigned short*)alloc((size_t)1024 * 128 * 2);
  unsigned short* CAT192 = (unsigned short*)alloc((size_t)1024 * 192 * 2);
  unsigned short* CAT128 = (unsigned short*)alloc((size_t)1024 * 128 * 2);
  float* EBS = (float*)alloc((size_t)ETOT * 8 * 4);
  float* ALS = (float*)alloc((size_t)NN * 8 * 4);
  float* ALD = (float*)alloc((size_t)NN * 8 * 4);
  int* DEG = (int*)alloc((size_t)NN * 4);
  int* ROWPTR = (int*)alloc((size_t)(NN + 1) * 4);
  int* CURSOR = (int*)alloc((size_t)NN * 4);
  int* SRCL = (int*)alloc((size_t)ETOT * 4);
  int* POS = (int*)alloc((size_t)ETOT * 4);
  unsigned short* PART = (unsigned short*)HLIN;  // 16x1024x1664 bf16 = 54.5MB over dead HLIN

  // CSR build
  hipLaunchKernelGGL(fill_i32, dim3((NN + 255) / 256), dim3(256), 0, stream, DEG, 0, NN);
  hipLaunchKernelGGL(count_deg, dim3((ETOT + 255) / 256), dim3(256), 0, stream, ei, DEG);
  hipLaunchKernelGGL(scan_deg, dim3(1), dim3(1024), 0, stream, DEG, ROWPTR, CURSOR);
  hipLaunchKernelGGL(fill_csr, dim3((ETOT + 255) / 256), dim3(256), 0, stream, ei, CURSOR, SRCL, POS);

  // batched weight transposes
  {
    TBatch tb;
    int acc_wg = 0, i = 0;
    auto add = [&](const float* W, unsigned short* WT, int K, int N, int Kp, int Npad) {
      int gx = Npad / 32, gy = Kp / 32;
      acc_wg += gx * gy;
      tb.d[i++] = {W, WT, K, N, Kp, Npad, gx, acc_wg};
    };
    add(z1_W, WTZ, 19127, 1600, 19136, 1664);
    add(gW[0], WT1, 109, 768, 128, 768);
    add(gW[1], WT2, 768, 1024, 768, 1024);
    add(gW[2], WT3, 1024, 1024, 1024, 1024);
    add(gW[3], WT4, 1024, 128, 1024, 128);
    add(w1_W, WTW1, 750, 750, 768, 768);
    add(w2_W, WTW2, 750, 64, 768, 128);
    add(z2_W, WTZ2, 1600, 64, 1664, 128);
    add(v1_W, WTV1, 1024, 256, 1024, 256);
    add(v2_W, WTV2, 256, 64, 256, 128);
    add(x5_W, WTX5, 128, 64, 128, 128);
    add(x6_W, WTX6, 64, 64, 64, 128);
    add(agg_W, WTAGG, 192, 64, 192, 128);
    add(col_W, WTCOL, 128, 64, 128, 128);
    add(s1_W, WTS1, 1050, 64, 1056, 128);
    add(s2_W, WTS2, 64, 64, 64, 128);
    hipLaunchKernelGGL(transpose_batch, dim3(acc_wg), dim3(256), 0, stream, tb);
  }

  // batched input conversions
  {
    CBatch cb;
    int acc_wg = 0, i = 0;
    auto add = [&](const float* in, unsigned short* out, int rowsOut, int Rreal, int C, int Cp) {
      acc_wg += (int)(((size_t)rowsOut * Cp + 255) / 256);
      cb.d[i++] = {in, out, rowsOut, Rreal, C, Cp, acc_wg};
    };
    add(z, ZA, NB, NB, 19127, 19136);
    add(x, XB, NN, NN, 109, 128);
    add(w, WB, 1024, 1024, 750, 768);
    add(v, VB, 1024, 1024, 1024, 1024);
    add(side, SIDEB, 1024, 994, 1050, 1056);
    hipLaunchKernelGGL(conv_batch, dim3(acc_wg), dim3(256), 0, stream, cb);
  }

  auto mm = [&](const unsigned short* A, const unsigned short* BT,
                const float* bias, void* C, int M, int Npad, int Nreal, int K,
                int lda, int ldb, int ldc, int zpad) {
    int gx = Npad / 128;
    int nwg = gx * (M / 128);
    hipLaunchKernelGGL((gemm_mfma<0, 1>), dim3(nwg), dim3(256), 0, stream,
                       A, BT, bias, C, Nreal, K, lda, ldb, ldc, gx, zpad);
  };

  // GAT layers
  const int Hs[4] = {8, 8, 8, 1};
  const int Kp[4] = {128, 768, 1024, 1024};
  const unsigned short* WTs[4] = {WT1, WT2, WT3, WT4};
  const int Fs[4] = {768, 1024, 1024, 128};
  for (int l = 0; l < 4; ++l) {
    int H = Hs[l], F = Fs[l], C = F / H;
    mm(XB, WTs[l], nullptr, HLIN, NN, F, F, Kp[l], Kp[l], Kp[l], F, 0);
    int totNH = NN * H;
    hipLaunchKernelGGL(gat_scores_bf, dim3((totNH + 255) / 256), dim3(256), 0, stream,
                       HLIN, gas[l], gad[l], ALS, ALD, H, C, totNH);
    if (H == 8)
      hipLaunchKernelGGL((edge_attn<8>), dim3((ETOT + 255) / 256), dim3(256), 0, stream, ei, ALS, ALD, POS, EBS);
    else
      hipLaunchKernelGGL((edge_attn<1>), dim3((ETOT + 255) / 256), dim3(256), 0, stream, ei, ALS, ALD, POS, EBS);
    if (l == 0)
      hipLaunchKernelGGL((gat_agg_v3<768, 96>), dim3(NN * 96 / 256), dim3(256), 0, stream,
                         ROWPTR, EBS, SRCL, HLIN, gb[l], XB);
    else if (l == 3)
      hipLaunchKernelGGL((gat_agg_v3<128, 128>), dim3(NN * 16 / 256), dim3(256), 0, stream,
                         ROWPTR, EBS, SRCL, HLIN, gb[l], XB);
    else
      hipLaunchKernelGGL((gat_agg_v3<1024, 128>), dim3(NN * 128 / 256), dim3(256), 0, stream,
                         ROWPTR, EBS, SRCL, HLIN, gb[l], XB);
  }

  // global max pool -> XGB bf16
  hipLaunchKernelGGL(pool_max, dim3(NB), dim3(128), 0, stream, XB, XGB);

  // B1: independent tail GEMMs {w1, v1, s1, x5}
  {
    GBatch b;
    int acc_wg = 0, i = 0;
    auto add = [&](const unsigned short* A, const unsigned short* BT, const float* bias,
                   void* C, int Npad, int Nreal, int K, int lda, int ldb, int ldc,
                   int zpad, int act, int obf, int Mreal) {
      int gx = Npad / 128;
      acc_wg += gx * 8;
      b.d[i++] = {A, BT, bias, C, Nreal, K, lda, ldb, ldc, gx, zpad, act, obf, Mreal, acc_wg};
    };
    add(WB, WTW1, w1_b, WMID, 768, 750, 768, 768, 768, 768, 1, 1, 1, 1024);
    add(VB, WTV1, v1_b, VMID, 256, 256, 1024, 1024, 1024, 256, 0, 1, 1, 1024);
    add(SIDEB, WTS1, s1_b, SEMID, 128, 64, 1056, 1056, 1056, 128, 1, 1, 1, 1024);
    add(XGB, WTX5, x5_b, X5O, 128, 64, 128, 128, 128, 128, 1, 1, 1, 1024);
    while (i < 5) { b.d[i] = b.d[i - 1]; b.d[i].wg_end = acc_wg; ++i; }
    hipLaunchKernelGGL(gemm_batch, dim3(acc_wg), dim3(256), 0, stream, b);
  }

  // z1 split-K (16 slices, bf16 partials) + reduce -> ZB bf16
  hipLaunchKernelGGL(gemm_mfma_sk, dim3(1664), dim3(256), 0, stream, ZA, WTZ, PART, 19136, 19136, 1664);
  hipLaunchKernelGGL(zred, dim3((1024 * 1664 / 8 + 255) / 256), dim3(256), 0, stream, PART, z1_b, ZB);

  // output pointers
  float* outp = (float*)d_out;
  float* DN = outp + (size_t)NB * NSIDE;
  float* SN = DN + (size_t)NB * 64;

  // B2: {x6, w2, z2, v2, s2(tanh+rownorm -> SN)}
  {
    GBatch b;
    int acc_wg = 0, i = 0;
    auto add = [&](const unsigned short* A, const unsigned short* BT, const float* bias,
                   void* C, int Npad, int Nreal, int K, int lda, int ldb, int ldc,
                   int zpad, int act, int obf, int Mreal) {
      int gx = Npad / 128;
      acc_wg += gx * 8;
      b.d[i++] = {A, BT, bias, C, Nreal, K, lda, ldb, ldc, gx, zpad, act, obf, Mreal, acc_wg};
    };
    add(X5O, WTX6, x6_b, CAT192 + 0, 128, 64, 64, 128, 64, 192, 0, 1, 1, 1024);
    add(WMID, WTW2, w2_b, CAT192 + 64, 128, 64, 768, 768, 768, 192, 0, 1, 1, 1024);
    add(ZB, WTZ2, z2_b, CAT192 + 128, 128, 64, 1664, 1664, 1664, 192, 0, 1, 1, 1024);
    add(VMID, WTV2, v2_b, CAT128 + 64, 128, 64, 256, 256, 256, 128, 0, 1, 1, 1024);
    add(SEMID, WTS2, s2_b, SN, 128, 64, 64, 128, 64, 64, 0, 4, 0, 994);
    hipLaunchKernelGGL(gemm_batch, dim3(acc_wg), dim3(256), 0, stream, b);
  }

  // fused tail: agg GEMM -> col GEMM -> |tanh| -> rownorm -> DN
  hipLaunchKernelGGL(tail_fused, dim3(8), dim3(256), 0, stream,
                     CAT192, WTAGG, agg_b, CAT128, WTCOL, col_b, DN);

  // similarity
  hipLaunchKernelGGL(freq_k, dim3((NSIDE + 15) / 16, (NB + 15) / 16), dim3(256), 0, stream,
                     DN, SN, outp, NB, NSIDE);
}

// Round 11
// 986.495 us; speedup vs baseline: 1.5886x; 1.0239x over previous
//
#include <hip/hip_runtime.h>
#include <math.h>
#include <float.h>

#define E0 131072
#define NN 32768
#define NB 1024
#define NSIDE 994
#define ETOT (E0 + NN)

typedef short bf16x8 __attribute__((ext_vector_type(8)));
typedef unsigned short ushort8 __attribute__((ext_vector_type(8)));
typedef float f32x4 __attribute__((ext_vector_type(4)));

__device__ inline float b2f(unsigned short u) { return __uint_as_float(((unsigned)u) << 16); }
__device__ inline unsigned short f2b(float f) {
  unsigned u = __float_as_uint(f);
  return (unsigned short)((u + 0x7fffu + ((u >> 16) & 1u)) >> 16);
}

__device__ inline void gload_lds16(const void* g, void* l) {
  __builtin_amdgcn_global_load_lds(
      (const __attribute__((address_space(1))) unsigned int*)g,
      (__attribute__((address_space(3))) unsigned int*)l, 16, 0, 0);
}

__global__ void fill_i32(int* p, int v, int n) {
  int i = blockIdx.x * blockDim.x + threadIdx.x;
  if (i < n) p[i] = v;
}

// ---------------- batched fp32 -> bf16 conversion with padding ----------------
struct CDesc { const float* in; unsigned short* out; int rowsOut, Rreal, C, Cp, wg_end; };
struct CBatch { CDesc d[5]; };
__global__ void conv_batch(CBatch cb) {
  int bid = blockIdx.x;
  int di = 0;
  while (bid >= cb.d[di].wg_end) ++di;
  const CDesc& g = cb.d[di];
  int rel = bid - (di ? cb.d[di - 1].wg_end : 0);
  size_t idx = (size_t)rel * 256 + threadIdx.x;
  size_t tot = (size_t)g.rowsOut * g.Cp;
  if (idx >= tot) return;
  int r = (int)(idx / g.Cp), c = (int)(idx % g.Cp);
  g.out[idx] = (r < g.Rreal && c < g.C) ? f2b(g.in[(size_t)r * g.C + c]) : (unsigned short)0;
}

// ---------------- batched transpose: W [K][N] f32 -> WT [Npad][Kp] bf16 ----------------
struct TDesc { const float* W; unsigned short* WT; int K, N, Kp, Npad, gx, wg_end; };
struct TBatch { TDesc d[16]; };
__global__ __launch_bounds__(256) void transpose_batch(TBatch tb) {
  __shared__ float t[32][33];
  int bid = blockIdx.x;
  int di = 0;
  while (bid >= tb.d[di].wg_end) ++di;
  const TDesc& g = tb.d[di];
  int rel = bid - (di ? tb.d[di - 1].wg_end : 0);
  int n0 = (rel % g.gx) * 32, k0 = (rel / g.gx) * 32;
  int tx = threadIdx.x & 31, ty = threadIdx.x >> 5;
  for (int r = ty; r < 32; r += 8) {
    int k = k0 + r, n = n0 + tx;
    t[r][tx] = (k < g.K && n < g.N) ? g.W[(size_t)k * g.N + n] : 0.f;
  }
  __syncthreads();
  for (int r = ty; r < 32; r += 8) {
    int n = n0 + r, k = k0 + tx;
    if (n < g.Npad && k < g.Kp)
      g.WT[(size_t)n * g.Kp + k] = (n < g.N) ? f2b(t[tx][r]) : (unsigned short)0;
  }
}

// ---------------- CSR build over dst ----------------
__global__ void count_deg(const int* __restrict__ ei, int* deg) {
  int e = blockIdx.x * blockDim.x + threadIdx.x;
  if (e >= ETOT) return;
  int dst = (e < E0) ? ei[E0 + e] : (e - E0);
  atomicAdd(&deg[dst], 1);
}

__global__ void scan_deg(const int* __restrict__ deg, int* rowptr, int* cursor) {
  __shared__ int part[1024];
  int tid = threadIdx.x;
  const int chunk = NN / 1024;  // 32
  int base = tid * chunk;
  int local[chunk];
  int sum = 0;
#pragma unroll
  for (int i = 0; i < chunk; ++i) { local[i] = sum; sum += deg[base + i]; }
  part[tid] = sum;
  __syncthreads();
  for (int off = 1; off < 1024; off <<= 1) {
    int t = (tid >= off) ? part[tid - off] : 0;
    __syncthreads();
    part[tid] += t;
    __syncthreads();
  }
  int offset = part[tid] - sum;
#pragma unroll
  for (int i = 0; i < chunk; ++i) {
    int v = offset + local[i];
    rowptr[base + i] = v;
    cursor[base + i] = v;
  }
  if (tid == 1023) rowptr[NN] = offset + sum;
}

__global__ void fill_csr(const int* __restrict__ ei, int* cursor, int* __restrict__ srcl) {
  int e = blockIdx.x * blockDim.x + threadIdx.x;
  if (e >= ETOT) return;
  int src, dst;
  if (e < E0) { src = ei[e]; dst = ei[E0 + e]; } else { src = dst = e - E0; }
  int p = atomicAdd(&cursor[dst], 1);
  srcl[p] = src;
}

// ---------------- bf16 MFMA GEMM, 2-phase double-buffered LDS (long-K path) ----------------
template <int ACT, int OBF>
__global__ __launch_bounds__(256) void gemm_mfma(
    const unsigned short* __restrict__ A, const unsigned short* __restrict__ BT,
    const float* __restrict__ bias, void* __restrict__ Cp,
    int Nreal, int K, int lda, int ldb, int ldc, int gx, int zpad) {
  __shared__ unsigned short As[2][128 * 32];
  __shared__ unsigned short Bs[2][128 * 32];
  const int nwg = gridDim.x;
  const int chunk = nwg >> 3;
  const int bid = blockIdx.x;
  const int swz = (bid & 7) * chunk + (bid >> 3);
  const int bm = (swz / gx) * 128, bn = (swz % gx) * 128;
  const int tid = threadIdx.x;
  const int wv = tid >> 6, lane = tid & 63;
  const int sr = lane >> 2;
  const int sk = ((lane & 3) ^ ((lane >> 3) & 3)) * 8;
  const int r16 = lane & 15, kq = lane >> 4;
  const int slot8 = (kq ^ ((r16 >> 1) & 3)) * 8;
  const int wr = wv >> 1, wc = wv & 1;
  f32x4 acc[4][4];
#pragma unroll
  for (int i = 0; i < 4; ++i)
#pragma unroll
    for (int j = 0; j < 4; ++j) acc[i][j] = (f32x4){0.f, 0.f, 0.f, 0.f};

  const unsigned short* Abase = A + (size_t)bm * lda;
  const unsigned short* Bbase = BT + (size_t)bn * ldb;
  auto stage = [&](int buf, int k0) {
    gload_lds16(Abase + (size_t)(wv * 16 + sr) * lda + k0 + sk, &As[buf][wv * 512]);
    gload_lds16(Abase + (size_t)(64 + wv * 16 + sr) * lda + k0 + sk, &As[buf][2048 + wv * 512]);
    gload_lds16(Bbase + (size_t)(wv * 16 + sr) * ldb + k0 + sk, &Bs[buf][wv * 512]);
    gload_lds16(Bbase + (size_t)(64 + wv * 16 + sr) * ldb + k0 + sk, &Bs[buf][2048 + wv * 512]);
  };
  stage(0, 0);
  __syncthreads();
  int cur = 0;
  for (int k0 = 0; k0 < K; k0 += 32) {
    if (k0 + 32 < K) stage(cur ^ 1, k0 + 32);
    bf16x8 af[4], bfr[4];
#pragma unroll
    for (int i = 0; i < 4; ++i)
      af[i] = *(const bf16x8*)&As[cur][(wr * 64 + i * 16 + r16) * 32 + slot8];
#pragma unroll
    for (int j = 0; j < 4; ++j)
      bfr[j] = *(const bf16x8*)&Bs[cur][(wc * 64 + j * 16 + r16) * 32 + slot8];
#pragma unroll
    for (int i = 0; i < 4; ++i)
#pragma unroll
      for (int j = 0; j < 4; ++j)
        acc[i][j] = __builtin_amdgcn_mfma_f32_16x16x32_bf16(af[i], bfr[j], acc[i][j], 0, 0, 0);
    __syncthreads();
    cur ^= 1;
  }
#pragma unroll
  for (int i = 0; i < 4; ++i) {
    int row = bm + wr * 64 + i * 16 + kq * 4;
#pragma unroll
    for (int j = 0; j < 4; ++j) {
      int col = bn + wc * 64 + j * 16 + r16;
      bool real = col < Nreal;
      if (!real && !zpad) continue;
      float bv = (bias && real) ? bias[col] : 0.f;
#pragma unroll
      for (int r = 0; r < 4; ++r) {
        float v = acc[i][j][r] + bv;
        if (ACT == 1) v = v > 0.f ? v : 0.f;
        else if (ACT == 2) v = tanhf(v);
        else if (ACT == 3) v = fabsf(tanhf(v));
        if (!real) v = 0.f;
        if (OBF) ((unsigned short*)Cp)[(size_t)(row + r) * ldc + col] = f2b(v);
        else ((float*)Cp)[(size_t)(row + r) * ldc + col] = v;
      }
    }
  }
}

// ---------------- batched runtime-act MFMA GEMM (2-phase dbuf) ----------------
// act: 0 none, 1 relu, 2 tanh, 3 abs(tanh), 4 tanh+rownorm (f32 out, row<Mreal guard)
struct GDesc {
  const unsigned short* A; const unsigned short* BT; const float* bias; void* C;
  int Nreal, K, lda, ldb, ldc, gx, zpad, act, obf, Mreal, wg_end;
};
struct GBatch { GDesc d[5]; };
__global__ __launch_bounds__(256) void gemm_batch(GBatch gb) {
  __shared__ unsigned short As[2][128 * 32];
  __shared__ unsigned short Bs[2][128 * 32];
  int bid = blockIdx.x;
  int di = 0;
  while (bid >= gb.d[di].wg_end) ++di;
  const GDesc& g = gb.d[di];
  int rel = bid - (di ? gb.d[di - 1].wg_end : 0);
  const int bm = (rel / g.gx) * 128, bn = (rel % g.gx) * 128;
  const int tid = threadIdx.x;
  const int wv = tid >> 6, lane = tid & 63;
  const int sr = lane >> 2;
  const int sk = ((lane & 3) ^ ((lane >> 3) & 3)) * 8;
  const int r16 = lane & 15, kq = lane >> 4;
  const int slot8 = (kq ^ ((r16 >> 1) & 3)) * 8;
  const int wr = wv >> 1, wc = wv & 1;
  f32x4 acc[4][4];
#pragma unroll
  for (int i = 0; i < 4; ++i)
#pragma unroll
    for (int j = 0; j < 4; ++j) acc[i][j] = (f32x4){0.f, 0.f, 0.f, 0.f};

  const unsigned short* Abase = g.A + (size_t)bm * g.lda;
  const unsigned short* Bbase = g.BT + (size_t)bn * g.ldb;
  auto stage = [&](int buf, int k0) {
    gload_lds16(Abase + (size_t)(wv * 16 + sr) * g.lda + k0 + sk, &As[buf][wv * 512]);
    gload_lds16(Abase + (size_t)(64 + wv * 16 + sr) * g.lda + k0 + sk, &As[buf][2048 + wv * 512]);
    gload_lds16(Bbase + (size_t)(wv * 16 + sr) * g.ldb + k0 + sk, &Bs[buf][wv * 512]);
    gload_lds16(Bbase + (size_t)(64 + wv * 16 + sr) * g.ldb + k0 + sk, &Bs[buf][2048 + wv * 512]);
  };
  stage(0, 0);
  __syncthreads();
  int cur = 0;
  for (int k0 = 0; k0 < g.K; k0 += 32) {
    if (k0 + 32 < g.K) stage(cur ^ 1, k0 + 32);
    bf16x8 af[4], bfr[4];
#pragma unroll
    for (int i = 0; i < 4; ++i)
      af[i] = *(const bf16x8*)&As[cur][(wr * 64 + i * 16 + r16) * 32 + slot8];
#pragma unroll
    for (int j = 0; j < 4; ++j)
      bfr[j] = *(const bf16x8*)&Bs[cur][(wc * 64 + j * 16 + r16) * 32 + slot8];
#pragma unroll
    for (int i = 0; i < 4; ++i)
#pragma unroll
      for (int j = 0; j < 4; ++j)
        acc[i][j] = __builtin_amdgcn_mfma_f32_16x16x32_bf16(af[i], bfr[j], acc[i][j], 0, 0, 0);
    __syncthreads();
    cur ^= 1;
  }
  if (g.act == 4) {
    if (wc == 0) {
#pragma unroll
      for (int i = 0; i < 4; ++i)
#pragma unroll
        for (int r = 0; r < 4; ++r) {
          int row = bm + wr * 64 + i * 16 + kq * 4 + r;
          float vv[4];
#pragma unroll
          for (int j = 0; j < 4; ++j) vv[j] = tanhf(acc[i][j][r] + g.bias[j * 16 + r16]);
          float ss = vv[0] * vv[0] + vv[1] * vv[1] + vv[2] * vv[2] + vv[3] * vv[3];
          ss += __shfl_xor(ss, 1);
          ss += __shfl_xor(ss, 2);
          ss += __shfl_xor(ss, 4);
          ss += __shfl_xor(ss, 8);
          float inv = 1.f / fmaxf(sqrtf(ss), 1e-12f);
          if (row < g.Mreal)
#pragma unroll
            for (int j = 0; j < 4; ++j)
              ((float*)g.C)[(size_t)row * g.ldc + j * 16 + r16] = vv[j] * inv;
        }
    }
    return;
  }
#pragma unroll
  for (int i = 0; i < 4; ++i) {
    int row = bm + wr * 64 + i * 16 + kq * 4;
#pragma unroll
    for (int j = 0; j < 4; ++j) {
      int col = bn + wc * 64 + j * 16 + r16;
      bool real = col < g.Nreal;
      if (!real && !g.zpad) continue;
      float bv = (g.bias && real) ? g.bias[col] : 0.f;
#pragma unroll
      for (int r = 0; r < 4; ++r) {
        float v = acc[i][j][r] + bv;
        if (g.act == 1) v = v > 0.f ? v : 0.f;
        else if (g.act == 2) v = tanhf(v);
        else if (g.act == 3) v = fabsf(tanhf(v));
        if (!real) v = 0.f;
        if (g.obf) ((unsigned short*)g.C)[(size_t)(row + r) * g.ldc + col] = f2b(v);
        else ((float*)g.C)[(size_t)(row + r) * g.ldc + col] = v;
      }
    }
  }
}

// ---------------- split-K MFMA GEMM for z1 (single-buffer, f32 partials) ----------------
// 16 K-slices, grid=1664; XCD-chunk: each XCD owns 2 whole K-slices.
__global__ __launch_bounds__(256) void gemm_mfma_sk(
    const unsigned short* __restrict__ A, const unsigned short* __restrict__ BT,
    float* __restrict__ PART, int lda, int ldb, int ldc) {
  __shared__ unsigned short As[128 * 32];
  __shared__ unsigned short Bs[128 * 32];
  const int bid = blockIdx.x;
  const int swz = (bid & 7) * 208 + (bid >> 3);
  const int s = swz / 104;
  const int pos = swz - s * 104;
  const int bm = (pos / 13) * 128, bn = (pos % 13) * 128;
  const int base = s * 37 + (s < 6 ? s : 6);
  const int nsteps = 37 + (s < 6 ? 1 : 0);
  const int tid = threadIdx.x;
  const int wv = tid >> 6, lane = tid & 63;
  const int sr = lane >> 2;
  const int sk = ((lane & 3) ^ ((lane >> 3) & 3)) * 8;
  const int r16 = lane & 15, kq = lane >> 4;
  const int slot8 = (kq ^ ((r16 >> 1) & 3)) * 8;
  const int wr = wv >> 1, wc = wv & 1;
  f32x4 acc[4][4];
#pragma unroll
  for (int i = 0; i < 4; ++i)
#pragma unroll
    for (int j = 0; j < 4; ++j) acc[i][j] = (f32x4){0.f, 0.f, 0.f, 0.f};

  const unsigned short* Abase = A + (size_t)bm * lda;
  const unsigned short* Bbase = BT + (size_t)bn * ldb;
  for (int ks = 0; ks < nsteps; ++ks) {
    int k0 = (base + ks) * 32;
    gload_lds16(Abase + (size_t)(wv * 16 + sr) * lda + k0 + sk, &As[wv * 512]);
    gload_lds16(Abase + (size_t)(64 + wv * 16 + sr) * lda + k0 + sk, &As[2048 + wv * 512]);
    gload_lds16(Bbase + (size_t)(wv * 16 + sr) * ldb + k0 + sk, &Bs[wv * 512]);
    gload_lds16(Bbase + (size_t)(64 + wv * 16 + sr) * ldb + k0 + sk, &Bs[2048 + wv * 512]);
    __syncthreads();
    bf16x8 af[4], bfr[4];
#pragma unroll
    for (int i = 0; i < 4; ++i)
      af[i] = *(const bf16x8*)&As[(wr * 64 + i * 16 + r16) * 32 + slot8];
#pragma unroll
    for (int j = 0; j < 4; ++j)
      bfr[j] = *(const bf16x8*)&Bs[(wc * 64 + j * 16 + r16) * 32 + slot8];
#pragma unroll
    for (int i = 0; i < 4; ++i)
#pragma unroll
      for (int j = 0; j < 4; ++j)
        acc[i][j] = __builtin_amdgcn_mfma_f32_16x16x32_bf16(af[i], bfr[j], acc[i][j], 0, 0, 0);
    __syncthreads();
  }
  float* out = PART + (size_t)s * 1024 * ldc;
#pragma unroll
  for (int i = 0; i < 4; ++i) {
    int row = bm + wr * 64 + i * 16 + kq * 4;
#pragma unroll
    for (int j = 0; j < 4; ++j) {
      int col = bn + wc * 64 + j * 16 + r16;
      if (col >= 1600) continue;
#pragma unroll
      for (int r = 0; r < 4; ++r)
        out[(size_t)(row + r) * ldc + col] = acc[i][j][r];
    }
  }
}

// reduce 16 f32 K-slice partials + bias + relu -> ZB bf16 [1024][1664], float4 vectorized
__global__ void zred(const float* __restrict__ PART, const float* __restrict__ bias,
                     unsigned short* __restrict__ ZB) {
  int g = blockIdx.x * blockDim.x + threadIdx.x;
  if (g >= 1024 * 1664 / 8) return;
  size_t base = (size_t)g * 8;
  int c0 = (int)(base % 1664);
  ushort8 o;
  if (c0 >= 1600) {
#pragma unroll
    for (int t = 0; t < 8; ++t) o[t] = 0;
  } else {
    float s[8] = {0.f, 0.f, 0.f, 0.f, 0.f, 0.f, 0.f, 0.f};
#pragma unroll
    for (int k = 0; k < 16; ++k) {
      const float* p = &PART[(size_t)k * 1024 * 1664 + base];
      float4 a = *(const float4*)p;
      float4 b = *(const float4*)(p + 4);
      s[0] += a.x; s[1] += a.y; s[2] += a.z; s[3] += a.w;
      s[4] += b.x; s[5] += b.y; s[6] += b.z; s[7] += b.w;
    }
#pragma unroll
    for (int t = 0; t < 8; ++t) {
      float v = s[t] + bias[c0 + t];
      o[t] = f2b(v > 0.f ? v : 0.f);
    }
  }
  *(ushort8*)&ZB[base] = o;
}

// ---------------- fused tail: agg GEMM -> LDS -> col GEMM -> |tanh| -> rownorm -> DN ----
__global__ __launch_bounds__(256) void tail_fused(
    const unsigned short* __restrict__ CAT192, const unsigned short* __restrict__ WTAGG,
    const float* __restrict__ agg_b, const unsigned short* __restrict__ CAT128,
    const unsigned short* __restrict__ WTCOL, const float* __restrict__ col_b,
    float* __restrict__ DN) {
  __shared__ unsigned short S1[128 * 32];
  __shared__ unsigned short S2[128 * 32];
  __shared__ unsigned short ACAT[128 * 128];
  const int bm = blockIdx.x * 128;
  const int tid = threadIdx.x;
  const int wv = tid >> 6, lane = tid & 63;
  const int sr = lane >> 2;
  const int sk = ((lane & 3) ^ ((lane >> 3) & 3)) * 8;
  const int r16 = lane & 15, kq = lane >> 4;
  const int slot8 = (kq ^ ((r16 >> 1) & 3)) * 8;
  const int wr = wv >> 1, wc = wv & 1;
  f32x4 acc[4][4];
#pragma unroll
  for (int i = 0; i < 4; ++i)
#pragma unroll
    for (int j = 0; j < 4; ++j) acc[i][j] = (f32x4){0.f, 0.f, 0.f, 0.f};

  const unsigned short* Abase = CAT192 + (size_t)bm * 192;
  for (int k0 = 0; k0 < 192; k0 += 32) {
    gload_lds16(Abase + (size_t)(wv * 16 + sr) * 192 + k0 + sk, &S1[wv * 512]);
    gload_lds16(Abase + (size_t)(64 + wv * 16 + sr) * 192 + k0 + sk, &S1[2048 + wv * 512]);
    gload_lds16(WTAGG + (size_t)(wv * 16 + sr) * 192 + k0 + sk, &S2[wv * 512]);
    gload_lds16(WTAGG + (size_t)(64 + wv * 16 + sr) * 192 + k0 + sk, &S2[2048 + wv * 512]);
    __syncthreads();
    bf16x8 af[4], bfr[4];
#pragma unroll
    for (int i = 0; i < 4; ++i)
      af[i] = *(const bf16x8*)&S1[(wr * 64 + i * 16 + r16) * 32 + slot8];
#pragma unroll
    for (int j = 0; j < 4; ++j)
      bfr[j] = *(const bf16x8*)&S2[(wc * 64 + j * 16 + r16) * 32 + slot8];
#pragma unroll
    for (int i = 0; i < 4; ++i)
#pragma unroll
      for (int j = 0; j < 4; ++j)
        acc[i][j] = __builtin_amdgcn_mfma_f32_16x16x32_bf16(af[i], bfr[j], acc[i][j], 0, 0, 0);
    __syncthreads();
  }
  if (wc == 0) {
#pragma unroll
    for (int i = 0; i < 4; ++i)
#pragma unroll
      for (int j = 0; j < 4; ++j) {
        int col = j * 16 + r16;
#pragma unroll
        for (int r = 0; r < 4; ++r) {
          int rl = wr * 64 + i * 16 + kq * 4 + r;
          ACAT[rl * 128 + col] = f2b(acc[i][j][r] + agg_b[col]);
        }
      }
  }
  for (int idx = tid; idx < 128 * 8; idx += 256) {
    int row = idx >> 3, c8 = (idx & 7) * 8;
    *(ushort8*)&ACAT[row * 128 + 64 + c8] =
        *(const ushort8*)&CAT128[(size_t)(bm + row) * 128 + 64 + c8];
  }
#pragma unroll
  for (int i = 0; i < 4; ++i)
#pragma unroll
    for (int j = 0; j < 4; ++j) acc[i][j] = (f32x4){0.f, 0.f, 0.f, 0.f};
  __syncthreads();

  for (int k0 = 0; k0 < 128; k0 += 32) {
    gload_lds16(WTCOL + (size_t)(wv * 16 + sr) * 128 + k0 + sk, &S1[wv * 512]);
    gload_lds16(WTCOL + (size_t)(64 + wv * 16 + sr) * 128 + k0 + sk, &S1[2048 + wv * 512]);
    __syncthreads();
    bf16x8 af[4], bfr[4];
#pragma unroll
    for (int i = 0; i < 4; ++i)
      af[i] = *(const bf16x8*)&ACAT[(wr * 64 + i * 16 + r16) * 128 + k0 + kq * 8];
#pragma unroll
    for (int j = 0; j < 4; ++j)
      bfr[j] = *(const bf16x8*)&S1[(wc * 64 + j * 16 + r16) * 32 + slot8];
#pragma unroll
    for (int i = 0; i < 4; ++i)
#pragma unroll
      for (int j = 0; j < 4; ++j)
        acc[i][j] = __builtin_amdgcn_mfma_f32_16x16x32_bf16(af[i], bfr[j], acc[i][j], 0, 0, 0);
    __syncthreads();
  }
  if (wc == 0) {
#pragma unroll
    for (int i = 0; i < 4; ++i)
#pragma unroll
      for (int r = 0; r < 4; ++r) {
        int row = bm + wr * 64 + i * 16 + kq * 4 + r;
        float vv[4];
#pragma unroll
        for (int j = 0; j < 4; ++j) vv[j] = fabsf(tanhf(acc[i][j][r] + col_b[j * 16 + r16]));
        float ss = vv[0] * vv[0] + vv[1] * vv[1] + vv[2] * vv[2] + vv[3] * vv[3];
        ss += __shfl_xor(ss, 1);
        ss += __shfl_xor(ss, 2);
        ss += __shfl_xor(ss, 4);
        ss += __shfl_xor(ss, 8);
        float inv = 1.f / fmaxf(sqrtf(ss), 1e-12f);
#pragma unroll
        for (int j = 0; j < 4; ++j)
          DN[(size_t)row * 64 + j * 16 + r16] = vv[j] * inv;
      }
  }
}

// ---------------- GAT pieces ----------------
__global__ void gat_scores_bf(const unsigned short* __restrict__ hlin,
                              const float* __restrict__ a_s, const float* __restrict__ a_d,
                              float* __restrict__ als, float* __restrict__ ald,
                              int H, int C, int tot) {
  int idx = blockIdx.x * blockDim.x + threadIdx.x;
  if (idx >= tot) return;
  int n = idx / H, h = idx - n * H;
  const unsigned short* base = hlin + (size_t)n * H * C + (size_t)h * C;
  const float* as = a_s + h * C;
  const float* ad = a_d + h * C;
  float ss = 0.f, sd = 0.f;
  for (int c = 0; c < C; c += 8) {
    ushort8 v = *(const ushort8*)(base + c);
#pragma unroll
    for (int t = 0; t < 8; ++t) {
      float f = b2f(v[t]);
      ss = fmaf(f, as[c + t], ss);
      sd = fmaf(f, ad[c + t], sd);
    }
  }
  als[idx] = ss;
  ald[idx] = sd;
}

// aggregate with INLINE attention: p = exp(lrelu(als[src]+ald[node])) computed in-loop.
// thread = (node, 8-ch chunk); contiguous srcl reads; softmax denom summed inline.
template <int F, int C>
__global__ __launch_bounds__(256) void gat_agg_v4(
    const int* __restrict__ rowptr, const int* __restrict__ srcl,
    const float* __restrict__ als, const float* __restrict__ ald,
    const unsigned short* __restrict__ hlin,
    const float* __restrict__ bias, unsigned short* __restrict__ out) {
  constexpr int H = F / C;
  constexpr int CPN = F / 8;
  int gidx = blockIdx.x * 256 + threadIdx.x;
  if (gidx >= NN * CPN) return;
  int node = gidx / CPN;
  int c0 = (gidx - node * CPN) * 8;
  int h = c0 / C;
  float aldv = ald[node * H + h];
  float s = 0.f;
  float acc[8] = {0.f, 0.f, 0.f, 0.f, 0.f, 0.f, 0.f, 0.f};
  int start = rowptr[node], end = rowptr[node + 1];
  for (int k = start; k < end; ++k) {
    int src = srcl[k];
    float e = als[src * H + h] + aldv;
    e = (e >= 0.f) ? e : 0.2f * e;
    float p = __expf(e);
    s += p;
    ushort8 hv = *(const ushort8*)(hlin + (size_t)src * F + c0);
#pragma unroll
    for (int t = 0; t < 8; ++t) acc[t] = fmaf(p, b2f(hv[t]), acc[t]);
  }
  float inv_s = 1.f / s;
  ushort8 o;
#pragma unroll
  for (int t = 0; t < 8; ++t) {
    float val = acc[t] * inv_s + bias[c0 + t];
    o[t] = f2b(val > 0.f ? val : 0.f);
  }
  *(ushort8*)(out + (size_t)node * F + c0) = o;
}

__global__ void pool_max(const unsigned short* __restrict__ xb,
                         unsigned short* __restrict__ xgb) {
  int g = blockIdx.x, c = threadIdx.x;  // 128 threads
  const unsigned short* base = xb + (size_t)g * 32 * 128 + c;
  float m = -FLT_MAX;
#pragma unroll 8
  for (int n = 0; n < 32; ++n) m = fmaxf(m, b2f(base[n * 128]));
  xgb[g * 128 + c] = f2b(m);
}

__global__ __launch_bounds__(256) void freq_k(const float* __restrict__ dn,
                                              const float* __restrict__ sn,
                                              float* __restrict__ C, int M, int N) {
  __shared__ float As[16][64];
  __shared__ float Bs[16][65];
  int tid = threadIdx.x;
  int tx = tid & 15, ty = tid >> 4;
  int bi = blockIdx.y * 16, bj = blockIdx.x * 16;
#pragma unroll
  for (int t = 0; t < 4; ++t) {
    int idx = tid * 4 + t;
    int r = idx >> 6, c = idx & 63;
    As[r][c] = (bi + r < M) ? dn[(bi + r) * 64 + c] : 0.f;
    Bs[r][c] = (bj + r < N) ? sn[(bj + r) * 64 + c] : 0.f;
  }
  __syncthreads();
  float acc = 0.f;
#pragma unroll
  for (int k = 0; k < 64; ++k) acc = fmaf(As[ty][k], Bs[tx][k], acc);
  if (bi + ty < M && bj + tx < N) C[(size_t)(bi + ty) * N + (bj + tx)] = 5.f * acc;
}

// ---------------- launch ----------------
extern "C" void kernel_launch(void* const* d_in, const int* in_sizes, int n_in,
                              void* d_out, int out_size, void* d_ws, size_t ws_size,
                              hipStream_t stream) {
  const float* x = (const float*)d_in[0];
  const int* ei = (const int*)d_in[1];
  const float* w = (const float*)d_in[3];
  const float* z = (const float*)d_in[4];
  const float* v = (const float*)d_in[5];
  const float* side = (const float*)d_in[6];
  const float* gW[4] = {(const float*)d_in[7], (const float*)d_in[11],
                        (const float*)d_in[15], (const float*)d_in[19]};
  const float* gas[4] = {(const float*)d_in[8], (const float*)d_in[12],
                         (const float*)d_in[16], (const float*)d_in[20]};
  const float* gad[4] = {(const float*)d_in[9], (const float*)d_in[13],
                         (const float*)d_in[17], (const float*)d_in[21]};
  const float* gb[4] = {(const float*)d_in[10], (const float*)d_in[14],
                        (const float*)d_in[18], (const float*)d_in[22]};
  const float* x5_W = (const float*)d_in[23]; const float* x5_b = (const float*)d_in[24];
  const float* x6_W = (const float*)d_in[25]; const float* x6_b = (const float*)d_in[26];
  const float* w1_W = (const float*)d_in[27]; const float* w1_b = (const float*)d_in[28];
  const float* w2_W = (const float*)d_in[29]; const float* w2_b = (const float*)d_in[30];
  const float* z1_W = (const float*)d_in[31]; const float* z1_b = (const float*)d_in[32];
  const float* z2_W = (const float*)d_in[33]; const float* z2_b = (const float*)d_in[34];
  const float* v1_W = (const float*)d_in[35]; const float* v1_b = (const float*)d_in[36];
  const float* v2_W = (const float*)d_in[37]; const float* v2_b = (const float*)d_in[38];
  const float* agg_W = (const float*)d_in[39]; const float* agg_b = (const float*)d_in[40];
  const float* col_W = (const float*)d_in[41]; const float* col_b = (const float*)d_in[42];
  const float* s1_W = (const float*)d_in[43]; const float* s1_b = (const float*)d_in[44];
  const float* s2_W = (const float*)d_in[45]; const float* s2_b = (const float*)d_in[46];

  char* wsb = (char*)d_ws;
  size_t off = 0;
  auto alloc = [&](size_t bytes) {
    void* p = wsb + off;
    off = (off + bytes + 255) & ~(size_t)255;
    return p;
  };
  unsigned short* HLIN = (unsigned short*)alloc((size_t)NN * 1024 * 2);
  unsigned short* XB = (unsigned short*)alloc((size_t)NN * 1024 * 2);
  unsigned short* WTZ = (unsigned short*)alloc((size_t)1664 * 19136 * 2);
  unsigned short* ZA = (unsigned short*)alloc((size_t)1024 * 19136 * 2);
  unsigned short* WT1 = (unsigned short*)alloc((size_t)768 * 128 * 2);
  unsigned short* WT2 = (unsigned short*)alloc((size_t)1024 * 768 * 2);
  unsigned short* WT3 = (unsigned short*)alloc((size_t)1024 * 1024 * 2);
  unsigned short* WT4 = (unsigned short*)alloc((size_t)128 * 1024 * 2);
  unsigned short* WTW1 = (unsigned short*)alloc((size_t)768 * 768 * 2);
  unsigned short* WTW2 = (unsigned short*)alloc((size_t)128 * 768 * 2);
  unsigned short* WTZ2 = (unsigned short*)alloc((size_t)128 * 1664 * 2);
  unsigned short* WTV1 = (unsigned short*)alloc((size_t)256 * 1024 * 2);
  unsigned short* WTV2 = (unsigned short*)alloc((size_t)128 * 256 * 2);
  unsigned short* WTX5 = (unsigned short*)alloc((size_t)128 * 128 * 2);
  unsigned short* WTX6 = (unsigned short*)alloc((size_t)128 * 64 * 2);
  unsigned short* WTAGG = (unsigned short*)alloc((size_t)128 * 192 * 2);
  unsigned short* WTCOL = (unsigned short*)alloc((size_t)128 * 128 * 2);
  unsigned short* WTS1 = (unsigned short*)alloc((size_t)128 * 1056 * 2);
  unsigned short* WTS2 = (unsigned short*)alloc((size_t)128 * 64 * 2);
  unsigned short* WB = (unsigned short*)alloc((size_t)1024 * 768 * 2);
  unsigned short* VB = (unsigned short*)alloc((size_t)1024 * 1024 * 2);
  unsigned short* SIDEB = (unsigned short*)alloc((size_t)1024 * 1056 * 2);
  unsigned short* XGB = (unsigned short*)alloc((size_t)1024 * 128 * 2);
  unsigned short* ZB = (unsigned short*)alloc((size_t)1024 * 1664 * 2);
  unsigned short* X5O = (unsigned short*)alloc((size_t)1024 * 128 * 2);
  unsigned short* WMID = (unsigned short*)alloc((size_t)1024 * 768 * 2);
  unsigned short* VMID = (unsigned short*)alloc((size_t)1024 * 256 * 2);
  unsigned short* SEMID = (unsigned short*)alloc((size_t)1024 * 128 * 2);
  unsigned short* CAT192 = (unsigned short*)alloc((size_t)1024 * 192 * 2);
  unsigned short* CAT128 = (unsigned short*)alloc((size_t)1024 * 128 * 2);
  float* ALS = (float*)alloc((size_t)NN * 8 * 4);
  float* ALD = (float*)alloc((size_t)NN * 8 * 4);
  int* DEG = (int*)alloc((size_t)NN * 4);
  int* ROWPTR = (int*)alloc((size_t)(NN + 1) * 4);
  int* CURSOR = (int*)alloc((size_t)NN * 4);
  int* SRCL = (int*)alloc((size_t)ETOT * 4);
  float* PART = (float*)HLIN;  // 16x1024x1664 f32 = 109MB over dead HLIN+XB (134MB)

  // CSR build
  hipLaunchKernelGGL(fill_i32, dim3((NN + 255) / 256), dim3(256), 0, stream, DEG, 0, NN);
  hipLaunchKernelGGL(count_deg, dim3((ETOT + 255) / 256), dim3(256), 0, stream, ei, DEG);
  hipLaunchKernelGGL(scan_deg, dim3(1), dim3(1024), 0, stream, DEG, ROWPTR, CURSOR);
  hipLaunchKernelGGL(fill_csr, dim3((ETOT + 255) / 256), dim3(256), 0, stream, ei, CURSOR, SRCL);

  // batched weight transposes
  {
    TBatch tb;
    int acc_wg = 0, i = 0;
    auto add = [&](const float* W, unsigned short* WT, int K, int N, int Kp, int Npad) {
      int gx = Npad / 32, gy = Kp / 32;
      acc_wg += gx * gy;
      tb.d[i++] = {W, WT, K, N, Kp, Npad, gx, acc_wg};
    };
    add(z1_W, WTZ, 19127, 1600, 19136, 1664);
    add(gW[0], WT1, 109, 768, 128, 768);
    add(gW[1], WT2, 768, 1024, 768, 1024);
    add(gW[2], WT3, 1024, 1024, 1024, 1024);
    add(gW[3], WT4, 1024, 128, 1024, 128);
    add(w1_W, WTW1, 750, 750, 768, 768);
    add(w2_W, WTW2, 750, 64, 768, 128);
    add(z2_W, WTZ2, 1600, 64, 1664, 128);
    add(v1_W, WTV1, 1024, 256, 1024, 256);
    add(v2_W, WTV2, 256, 64, 256, 128);
    add(x5_W, WTX5, 128, 64, 128, 128);
    add(x6_W, WTX6, 64, 64, 64, 128);
    add(agg_W, WTAGG, 192, 64, 192, 128);
    add(col_W, WTCOL, 128, 64, 128, 128);
    add(s1_W, WTS1, 1050, 64, 1056, 128);
    add(s2_W, WTS2, 64, 64, 64, 128);
    hipLaunchKernelGGL(transpose_batch, dim3(acc_wg), dim3(256), 0, stream, tb);
  }

  // batched input conversions
  {
    CBatch cb;
    int acc_wg = 0, i = 0;
    auto add = [&](const float* in, unsigned short* out, int rowsOut, int Rreal, int C, int Cp) {
      acc_wg += (int)(((size_t)rowsOut * Cp + 255) / 256);
      cb.d[i++] = {in, out, rowsOut, Rreal, C, Cp, acc_wg};
    };
    add(z, ZA, NB, NB, 19127, 19136);
    add(x, XB, NN, NN, 109, 128);
    add(w, WB, 1024, 1024, 750, 768);
    add(v, VB, 1024, 1024, 1024, 1024);
    add(side, SIDEB, 1024, 994, 1050, 1056);
    hipLaunchKernelGGL(conv_batch, dim3(acc_wg), dim3(256), 0, stream, cb);
  }

  auto mm = [&](const unsigned short* A, const unsigned short* BT,
                const float* bias, void* C, int M, int Npad, int Nreal, int K,
                int lda, int ldb, int ldc, int zpad) {
    int gx = Npad / 128;
    int nwg = gx * (M / 128);
    hipLaunchKernelGGL((gemm_mfma<0, 1>), dim3(nwg), dim3(256), 0, stream,
                       A, BT, bias, C, Nreal, K, lda, ldb, ldc, gx, zpad);
  };

  // GAT layers (scores -> fused-attn aggregate)
  const int Hs[4] = {8, 8, 8, 1};
  const int Kp[4] = {128, 768, 1024, 1024};
  const unsigned short* WTs[4] = {WT1, WT2, WT3, WT4};
  const int Fs[4] = {768, 1024, 1024, 128};
  for (int l = 0; l < 4; ++l) {
    int H = Hs[l], F = Fs[l], C = F / H;
    mm(XB, WTs[l], nullptr, HLIN, NN, F, F, Kp[l], Kp[l], Kp[l], F, 0);
    int totNH = NN * H;
    hipLaunchKernelGGL(gat_scores_bf, dim3((totNH + 255) / 256), dim3(256), 0, stream,
                       HLIN, gas[l], gad[l], ALS, ALD, H, C, totNH);
    if (l == 0)
      hipLaunchKernelGGL((gat_agg_v4<768, 96>), dim3(NN * 96 / 256), dim3(256), 0, stream,
                         ROWPTR, SRCL, ALS, ALD, HLIN, gb[l], XB);
    else if (l == 3)
      hipLaunchKernelGGL((gat_agg_v4<128, 128>), dim3(NN * 16 / 256), dim3(256), 0, stream,
                         ROWPTR, SRCL, ALS, ALD, HLIN, gb[l], XB);
    else
      hipLaunchKernelGGL((gat_agg_v4<1024, 128>), dim3(NN * 128 / 256), dim3(256), 0, stream,
                         ROWPTR, SRCL, ALS, ALD, HLIN, gb[l], XB);
  }

  // global max pool -> XGB bf16
  hipLaunchKernelGGL(pool_max, dim3(NB), dim3(128), 0, stream, XB, XGB);

  // B1: independent tail GEMMs {w1, v1, s1, x5}
  {
    GBatch b;
    int acc_wg = 0, i = 0;
    auto add = [&](const unsigned short* A, const unsigned short* BT, const float* bias,
                   void* C, int Npad, int Nreal, int K, int lda, int ldb, int ldc,
                   int zpad, int act, int obf, int Mreal) {
      int gx = Npad / 128;
      acc_wg += gx * 8;
      b.d[i++] = {A, BT, bias, C, Nreal, K, lda, ldb, ldc, gx, zpad, act, obf, Mreal, acc_wg};
    };
    add(WB, WTW1, w1_b, WMID, 768, 750, 768, 768, 768, 768, 1, 1, 1, 1024);
    add(VB, WTV1, v1_b, VMID, 256, 256, 1024, 1024, 1024, 256, 0, 1, 1, 1024);
    add(SIDEB, WTS1, s1_b, SEMID, 128, 64, 1056, 1056, 1056, 128, 1, 1, 1, 1024);
    add(XGB, WTX5, x5_b, X5O, 128, 64, 128, 128, 128, 128, 1, 1, 1, 1024);
    while (i < 5) { b.d[i] = b.d[i - 1]; b.d[i].wg_end = acc_wg; ++i; }
    hipLaunchKernelGGL(gemm_batch, dim3(acc_wg), dim3(256), 0, stream, b);
  }

  // z1 split-K (16 slices, f32 partials) + reduce -> ZB bf16
  hipLaunchKernelGGL(gemm_mfma_sk, dim3(1664), dim3(256), 0, stream, ZA, WTZ, PART, 19136, 19136, 1664);
  hipLaunchKernelGGL(zred, dim3((1024 * 1664 / 8 + 255) / 256), dim3(256), 0, stream, PART, z1_b, ZB);

  // output pointers
  float* outp = (float*)d_out;
  float* DN = outp + (size_t)NB * NSIDE;
  float* SN = DN + (size_t)NB * 64;

  // B2: {x6, w2, z2, v2, s2(tanh+rownorm -> SN)}
  {
    GBatch b;
    int acc_wg = 0, i = 0;
    auto add = [&](const unsigned short* A, const unsigned short* BT, const float* bias,
                   void* C, int Npad, int Nreal, int K, int lda, int ldb, int ldc,
                   int zpad, int act, int obf, int Mreal) {
      int gx = Npad / 128;
      acc_wg += gx * 8;
      b.d[i++] = {A, BT, bias, C, Nreal, K, lda, ldb, ldc, gx, zpad, act, obf, Mreal, acc_wg};
    };
    add(X5O, WTX6, x6_b, CAT192 + 0, 128, 64, 64, 128, 64, 192, 0, 1, 1, 1024);
    add(WMID, WTW2, w2_b, CAT192 + 64, 128, 64, 768, 768, 768, 192, 0, 1, 1, 1024);
    add(ZB, WTZ2, z2_b, CAT192 + 128, 128, 64, 1664, 1664, 1664, 192, 0, 1, 1, 1024);
    add(VMID, WTV2, v2_b, CAT128 + 64, 128, 64, 256, 256, 256, 128, 0, 1, 1, 1024);
    add(SEMID, WTS2, s2_b, SN, 128, 64, 64, 128, 64, 64, 0, 4, 0, 994);
    hipLaunchKernelGGL(gemm_batch, dim3(acc_wg), dim3(256), 0, stream, b);
  }

  // fused tail: agg GEMM -> col GEMM -> |tanh| -> rownorm -> DN
  hipLaunchKernelGGL(tail_fused, dim3(8), dim3(256), 0, stream,
                     CAT192, WTAGG, agg_b, CAT128, WTCOL, col_b, DN);

  // similarity
  hipLaunchKernelGGL(freq_k, dim3((NSIDE + 15) / 16, (NB + 15) / 16), dim3(256), 0, stream,
                     DN, SN, outp, NB, NSIDE);
}

// Round 12
// 958.265 us; speedup vs baseline: 1.6354x; 1.0295x over previous
//
#include <hip/hip_runtime.h>
#include <math.h>
#include <float.h>

#define E0 131072
#define NN 32768
#define NB 1024
#define NSIDE 994
#define ETOT (E0 + NN)

typedef short bf16x8 __attribute__((ext_vector_type(8)));
typedef unsigned short ushort8 __attribute__((ext_vector_type(8)));
typedef float f32x4 __attribute__((ext_vector_type(4)));

__device__ inline float b2f(unsigned short u) { return __uint_as_float(((unsigned)u) << 16); }
__device__ inline unsigned short f2b(float f) {
  unsigned u = __float_as_uint(f);
  return (unsigned short)((u + 0x7fffu + ((u >> 16) & 1u)) >> 16);
}

__device__ inline void gload_lds16(const void* g, void* l) {
  __builtin_amdgcn_global_load_lds(
      (const __attribute__((address_space(1))) unsigned int*)g,
      (__attribute__((address_space(3))) unsigned int*)l, 16, 0, 0);
}

__global__ void fill_i32(int* p, int v, int n) {
  int i = blockIdx.x * blockDim.x + threadIdx.x;
  if (i < n) p[i] = v;
}

// ---------------- batched fp32 -> bf16 conversion with padding ----------------
struct CDesc { const float* in; unsigned short* out; int rowsOut, Rreal, C, Cp, wg_end; };
struct CBatch { CDesc d[5]; };
__global__ void conv_batch(CBatch cb) {
  int bid = blockIdx.x;
  int di = 0;
  while (bid >= cb.d[di].wg_end) ++di;
  const CDesc& g = cb.d[di];
  int rel = bid - (di ? cb.d[di - 1].wg_end : 0);
  size_t idx = (size_t)rel * 256 + threadIdx.x;
  size_t tot = (size_t)g.rowsOut * g.Cp;
  if (idx >= tot) return;
  int r = (int)(idx / g.Cp), c = (int)(idx % g.Cp);
  g.out[idx] = (r < g.Rreal && c < g.C) ? f2b(g.in[(size_t)r * g.C + c]) : (unsigned short)0;
}

// ---------------- batched transpose: W [K][N] f32 -> WT [Npad][Kp] bf16 ----------------
struct TDesc { const float* W; unsigned short* WT; int K, N, Kp, Npad, gx, wg_end; };
struct TBatch { TDesc d[16]; };
__global__ __launch_bounds__(256) void transpose_batch(TBatch tb) {
  __shared__ float t[32][33];
  int bid = blockIdx.x;
  int di = 0;
  while (bid >= tb.d[di].wg_end) ++di;
  const TDesc& g = tb.d[di];
  int rel = bid - (di ? tb.d[di - 1].wg_end : 0);
  int n0 = (rel % g.gx) * 32, k0 = (rel / g.gx) * 32;
  int tx = threadIdx.x & 31, ty = threadIdx.x >> 5;
  for (int r = ty; r < 32; r += 8) {
    int k = k0 + r, n = n0 + tx;
    t[r][tx] = (k < g.K && n < g.N) ? g.W[(size_t)k * g.N + n] : 0.f;
  }
  __syncthreads();
  for (int r = ty; r < 32; r += 8) {
    int n = n0 + r, k = k0 + tx;
    if (n < g.Npad && k < g.Kp)
      g.WT[(size_t)n * g.Kp + k] = (n < g.N) ? f2b(t[tx][r]) : (unsigned short)0;
  }
}

// ---------------- CSR build over dst ----------------
__global__ void count_deg(const int* __restrict__ ei, int* deg) {
  int e = blockIdx.x * blockDim.x + threadIdx.x;
  if (e >= ETOT) return;
  int dst = (e < E0) ? ei[E0 + e] : (e - E0);
  atomicAdd(&deg[dst], 1);
}

__global__ void scan_deg(const int* __restrict__ deg, int* rowptr, int* cursor) {
  __shared__ int part[1024];
  int tid = threadIdx.x;
  const int chunk = NN / 1024;  // 32
  int base = tid * chunk;
  int local[chunk];
  int sum = 0;
#pragma unroll
  for (int i = 0; i < chunk; ++i) { local[i] = sum; sum += deg[base + i]; }
  part[tid] = sum;
  __syncthreads();
  for (int off = 1; off < 1024; off <<= 1) {
    int t = (tid >= off) ? part[tid - off] : 0;
    __syncthreads();
    part[tid] += t;
    __syncthreads();
  }
  int offset = part[tid] - sum;
#pragma unroll
  for (int i = 0; i < chunk; ++i) {
    int v = offset + local[i];
    rowptr[base + i] = v;
    cursor[base + i] = v;
  }
  if (tid == 1023) rowptr[NN] = offset + sum;
}

__global__ void fill_csr(const int* __restrict__ ei, int* cursor, int* __restrict__ srcl) {
  int e = blockIdx.x * blockDim.x + threadIdx.x;
  if (e >= ETOT) return;
  int src, dst;
  if (e < E0) { src = ei[e]; dst = ei[E0 + e]; } else { src = dst = e - E0; }
  int p = atomicAdd(&cursor[dst], 1);
  srcl[p] = src;
}

// ---------------- bf16 MFMA GEMM, 2-phase dbuf; optional fused GAT scores ----------------
// SC=1 (requires C=128 so each 128-col block == one head): epilogue computes
// als/ald[row][h] from the unrounded accumulators (shfl over r16, LDS over wc).
template <int ACT, int OBF, int SC>
__global__ __launch_bounds__(256) void gemm_mfma(
    const unsigned short* __restrict__ A, const unsigned short* __restrict__ BT,
    const float* __restrict__ bias, void* __restrict__ Cp,
    int Nreal, int K, int lda, int ldb, int ldc, int gx, int zpad,
    const float* __restrict__ asv, const float* __restrict__ adv,
    float* __restrict__ als, float* __restrict__ ald, int H) {
  __shared__ unsigned short As[2][128 * 32];
  __shared__ unsigned short Bs[2][128 * 32];
  const int nwg = gridDim.x;
  const int chunk = nwg >> 3;
  const int bid = blockIdx.x;
  const int swz = (bid & 7) * chunk + (bid >> 3);
  const int bm = (swz / gx) * 128, bn = (swz % gx) * 128;
  const int tid = threadIdx.x;
  const int wv = tid >> 6, lane = tid & 63;
  const int sr = lane >> 2;
  const int sk = ((lane & 3) ^ ((lane >> 3) & 3)) * 8;
  const int r16 = lane & 15, kq = lane >> 4;
  const int slot8 = (kq ^ ((r16 >> 1) & 3)) * 8;
  const int wr = wv >> 1, wc = wv & 1;
  f32x4 acc[4][4];
#pragma unroll
  for (int i = 0; i < 4; ++i)
#pragma unroll
    for (int j = 0; j < 4; ++j) acc[i][j] = (f32x4){0.f, 0.f, 0.f, 0.f};

  const unsigned short* Abase = A + (size_t)bm * lda;
  const unsigned short* Bbase = BT + (size_t)bn * ldb;
  auto stage = [&](int buf, int k0) {
    gload_lds16(Abase + (size_t)(wv * 16 + sr) * lda + k0 + sk, &As[buf][wv * 512]);
    gload_lds16(Abase + (size_t)(64 + wv * 16 + sr) * lda + k0 + sk, &As[buf][2048 + wv * 512]);
    gload_lds16(Bbase + (size_t)(wv * 16 + sr) * ldb + k0 + sk, &Bs[buf][wv * 512]);
    gload_lds16(Bbase + (size_t)(64 + wv * 16 + sr) * ldb + k0 + sk, &Bs[buf][2048 + wv * 512]);
  };
  stage(0, 0);
  __syncthreads();
  int cur = 0;
  for (int k0 = 0; k0 < K; k0 += 32) {
    if (k0 + 32 < K) stage(cur ^ 1, k0 + 32);
    bf16x8 af[4], bfr[4];
#pragma unroll
    for (int i = 0; i < 4; ++i)
      af[i] = *(const bf16x8*)&As[cur][(wr * 64 + i * 16 + r16) * 32 + slot8];
#pragma unroll
    for (int j = 0; j < 4; ++j)
      bfr[j] = *(const bf16x8*)&Bs[cur][(wc * 64 + j * 16 + r16) * 32 + slot8];
#pragma unroll
    for (int i = 0; i < 4; ++i)
#pragma unroll
      for (int j = 0; j < 4; ++j)
        acc[i][j] = __builtin_amdgcn_mfma_f32_16x16x32_bf16(af[i], bfr[j], acc[i][j], 0, 0, 0);
    __syncthreads();
    cur ^= 1;
  }
#pragma unroll
  for (int i = 0; i < 4; ++i) {
    int row = bm + wr * 64 + i * 16 + kq * 4;
#pragma unroll
    for (int j = 0; j < 4; ++j) {
      int col = bn + wc * 64 + j * 16 + r16;
      bool real = col < Nreal;
      if (!real && !zpad) continue;
      float bv = (bias && real) ? bias[col] : 0.f;
#pragma unroll
      for (int r = 0; r < 4; ++r) {
        float v = acc[i][j][r] + bv;
        if (ACT == 1) v = v > 0.f ? v : 0.f;
        else if (ACT == 2) v = tanhf(v);
        else if (ACT == 3) v = fabsf(tanhf(v));
        if (!real) v = 0.f;
        if (OBF) ((unsigned short*)Cp)[(size_t)(row + r) * ldc + col] = f2b(v);
        else ((float*)Cp)[(size_t)(row + r) * ldc + col] = v;
      }
    }
  }
  if (SC) {
    // fused GAT scores: head h spans exactly this block's 128 cols
    const int h = bn >> 7;
    float* scr = (float*)&As[0][0];  // 128 rows x {wc0_s, wc0_d, wc1_s, wc1_d}
    float a_s[4], a_d[4];
#pragma unroll
    for (int j = 0; j < 4; ++j) {
      int cwh = wc * 64 + j * 16 + r16;  // col within head
      a_s[j] = asv[h * 128 + cwh];
      a_d[j] = adv[h * 128 + cwh];
    }
#pragma unroll
    for (int i = 0; i < 4; ++i)
#pragma unroll
      for (int r = 0; r < 4; ++r) {
        float sp = 0.f, dp = 0.f;
#pragma unroll
        for (int j = 0; j < 4; ++j) {
          sp = fmaf(acc[i][j][r], a_s[j], sp);
          dp = fmaf(acc[i][j][r], a_d[j], dp);
        }
#pragma unroll
        for (int m = 1; m < 16; m <<= 1) {
          sp += __shfl_xor(sp, m);
          dp += __shfl_xor(dp, m);
        }
        if (r16 == 0) {
          int rl = wr * 64 + i * 16 + kq * 4 + r;
          scr[rl * 4 + wc * 2 + 0] = sp;
          scr[rl * 4 + wc * 2 + 1] = dp;
        }
      }
    __syncthreads();
    if (tid < 128) {
      float s = scr[tid * 4 + 0] + scr[tid * 4 + 2];
      float d = scr[tid * 4 + 1] + scr[tid * 4 + 3];
      als[(size_t)(bm + tid) * H + h] = s;
      ald[(size_t)(bm + tid) * H + h] = d;
    }
  }
}

// ---------------- batched runtime-act MFMA GEMM (2-phase dbuf) ----------------
// act: 0 none, 1 relu, 2 tanh, 3 abs(tanh), 4 tanh+rownorm (f32 out, row<Mreal guard)
struct GDesc {
  const unsigned short* A; const unsigned short* BT; const float* bias; void* C;
  int Nreal, K, lda, ldb, ldc, gx, zpad, act, obf, Mreal, wg_end;
};
struct GBatch { GDesc d[5]; };
__global__ __launch_bounds__(256) void gemm_batch(GBatch gb) {
  __shared__ unsigned short As[2][128 * 32];
  __shared__ unsigned short Bs[2][128 * 32];
  int bid = blockIdx.x;
  int di = 0;
  while (bid >= gb.d[di].wg_end) ++di;
  const GDesc& g = gb.d[di];
  int rel = bid - (di ? gb.d[di - 1].wg_end : 0);
  const int bm = (rel / g.gx) * 128, bn = (rel % g.gx) * 128;
  const int tid = threadIdx.x;
  const int wv = tid >> 6, lane = tid & 63;
  const int sr = lane >> 2;
  const int sk = ((lane & 3) ^ ((lane >> 3) & 3)) * 8;
  const int r16 = lane & 15, kq = lane >> 4;
  const int slot8 = (kq ^ ((r16 >> 1) & 3)) * 8;
  const int wr = wv >> 1, wc = wv & 1;
  f32x4 acc[4][4];
#pragma unroll
  for (int i = 0; i < 4; ++i)
#pragma unroll
    for (int j = 0; j < 4; ++j) acc[i][j] = (f32x4){0.f, 0.f, 0.f, 0.f};

  const unsigned short* Abase = g.A + (size_t)bm * g.lda;
  const unsigned short* Bbase = g.BT + (size_t)bn * g.ldb;
  auto stage = [&](int buf, int k0) {
    gload_lds16(Abase + (size_t)(wv * 16 + sr) * g.lda + k0 + sk, &As[buf][wv * 512]);
    gload_lds16(Abase + (size_t)(64 + wv * 16 + sr) * g.lda + k0 + sk, &As[buf][2048 + wv * 512]);
    gload_lds16(Bbase + (size_t)(wv * 16 + sr) * g.ldb + k0 + sk, &Bs[buf][wv * 512]);
    gload_lds16(Bbase + (size_t)(64 + wv * 16 + sr) * g.ldb + k0 + sk, &Bs[buf][2048 + wv * 512]);
  };
  stage(0, 0);
  __syncthreads();
  int cur = 0;
  for (int k0 = 0; k0 < g.K; k0 += 32) {
    if (k0 + 32 < g.K) stage(cur ^ 1, k0 + 32);
    bf16x8 af[4], bfr[4];
#pragma unroll
    for (int i = 0; i < 4; ++i)
      af[i] = *(const bf16x8*)&As[cur][(wr * 64 + i * 16 + r16) * 32 + slot8];
#pragma unroll
    for (int j = 0; j < 4; ++j)
      bfr[j] = *(const bf16x8*)&Bs[cur][(wc * 64 + j * 16 + r16) * 32 + slot8];
#pragma unroll
    for (int i = 0; i < 4; ++i)
#pragma unroll
      for (int j = 0; j < 4; ++j)
        acc[i][j] = __builtin_amdgcn_mfma_f32_16x16x32_bf16(af[i], bfr[j], acc[i][j], 0, 0, 0);
    __syncthreads();
    cur ^= 1;
  }
  if (g.act == 4) {
    if (wc == 0) {
#pragma unroll
      for (int i = 0; i < 4; ++i)
#pragma unroll
        for (int r = 0; r < 4; ++r) {
          int row = bm + wr * 64 + i * 16 + kq * 4 + r;
          float vv[4];
#pragma unroll
          for (int j = 0; j < 4; ++j) vv[j] = tanhf(acc[i][j][r] + g.bias[j * 16 + r16]);
          float ss = vv[0] * vv[0] + vv[1] * vv[1] + vv[2] * vv[2] + vv[3] * vv[3];
          ss += __shfl_xor(ss, 1);
          ss += __shfl_xor(ss, 2);
          ss += __shfl_xor(ss, 4);
          ss += __shfl_xor(ss, 8);
          float inv = 1.f / fmaxf(sqrtf(ss), 1e-12f);
          if (row < g.Mreal)
#pragma unroll
            for (int j = 0; j < 4; ++j)
              ((float*)g.C)[(size_t)row * g.ldc + j * 16 + r16] = vv[j] * inv;
        }
    }
    return;
  }
#pragma unroll
  for (int i = 0; i < 4; ++i) {
    int row = bm + wr * 64 + i * 16 + kq * 4;
#pragma unroll
    for (int j = 0; j < 4; ++j) {
      int col = bn + wc * 64 + j * 16 + r16;
      bool real = col < g.Nreal;
      if (!real && !g.zpad) continue;
      float bv = (g.bias && real) ? g.bias[col] : 0.f;
#pragma unroll
      for (int r = 0; r < 4; ++r) {
        float v = acc[i][j][r] + bv;
        if (g.act == 1) v = v > 0.f ? v : 0.f;
        else if (g.act == 2) v = tanhf(v);
        else if (g.act == 3) v = fabsf(tanhf(v));
        if (!real) v = 0.f;
        if (g.obf) ((unsigned short*)g.C)[(size_t)(row + r) * g.ldc + col] = f2b(v);
        else ((float*)g.C)[(size_t)(row + r) * g.ldc + col] = v;
      }
    }
  }
}

// ---------------- split-K MFMA GEMM for z1 (single-buffer, f32 partials) ----------------
__global__ __launch_bounds__(256) void gemm_mfma_sk(
    const unsigned short* __restrict__ A, const unsigned short* __restrict__ BT,
    float* __restrict__ PART, int lda, int ldb, int ldc) {
  __shared__ unsigned short As[128 * 32];
  __shared__ unsigned short Bs[128 * 32];
  const int bid = blockIdx.x;
  const int swz = (bid & 7) * 208 + (bid >> 3);
  const int s = swz / 104;
  const int pos = swz - s * 104;
  const int bm = (pos / 13) * 128, bn = (pos % 13) * 128;
  const int base = s * 37 + (s < 6 ? s : 6);
  const int nsteps = 37 + (s < 6 ? 1 : 0);
  const int tid = threadIdx.x;
  const int wv = tid >> 6, lane = tid & 63;
  const int sr = lane >> 2;
  const int sk = ((lane & 3) ^ ((lane >> 3) & 3)) * 8;
  const int r16 = lane & 15, kq = lane >> 4;
  const int slot8 = (kq ^ ((r16 >> 1) & 3)) * 8;
  const int wr = wv >> 1, wc = wv & 1;
  f32x4 acc[4][4];
#pragma unroll
  for (int i = 0; i < 4; ++i)
#pragma unroll
    for (int j = 0; j < 4; ++j) acc[i][j] = (f32x4){0.f, 0.f, 0.f, 0.f};

  const unsigned short* Abase = A + (size_t)bm * lda;
  const unsigned short* Bbase = BT + (size_t)bn * ldb;
  for (int ks = 0; ks < nsteps; ++ks) {
    int k0 = (base + ks) * 32;
    gload_lds16(Abase + (size_t)(wv * 16 + sr) * lda + k0 + sk, &As[wv * 512]);
    gload_lds16(Abase + (size_t)(64 + wv * 16 + sr) * lda + k0 + sk, &As[2048 + wv * 512]);
    gload_lds16(Bbase + (size_t)(wv * 16 + sr) * ldb + k0 + sk, &Bs[wv * 512]);
    gload_lds16(Bbase + (size_t)(64 + wv * 16 + sr) * ldb + k0 + sk, &Bs[2048 + wv * 512]);
    __syncthreads();
    bf16x8 af[4], bfr[4];
#pragma unroll
    for (int i = 0; i < 4; ++i)
      af[i] = *(const bf16x8*)&As[(wr * 64 + i * 16 + r16) * 32 + slot8];
#pragma unroll
    for (int j = 0; j < 4; ++j)
      bfr[j] = *(const bf16x8*)&Bs[(wc * 64 + j * 16 + r16) * 32 + slot8];
#pragma unroll
    for (int i = 0; i < 4; ++i)
#pragma unroll
      for (int j = 0; j < 4; ++j)
        acc[i][j] = __builtin_amdgcn_mfma_f32_16x16x32_bf16(af[i], bfr[j], acc[i][j], 0, 0, 0);
    __syncthreads();
  }
  float* out = PART + (size_t)s * 1024 * ldc;
#pragma unroll
  for (int i = 0; i < 4; ++i) {
    int row = bm + wr * 64 + i * 16 + kq * 4;
#pragma unroll
    for (int j = 0; j < 4; ++j) {
      int col = bn + wc * 64 + j * 16 + r16;
      if (col >= 1600) continue;
#pragma unroll
      for (int r = 0; r < 4; ++r)
        out[(size_t)(row + r) * ldc + col] = acc[i][j][r];
    }
  }
}

// reduce 16 f32 K-slice partials + bias + relu -> ZB bf16 [1024][1664], float4 vectorized
__global__ void zred(const float* __restrict__ PART, const float* __restrict__ bias,
                     unsigned short* __restrict__ ZB) {
  int g = blockIdx.x * blockDim.x + threadIdx.x;
  if (g >= 1024 * 1664 / 8) return;
  size_t base = (size_t)g * 8;
  int c0 = (int)(base % 1664);
  ushort8 o;
  if (c0 >= 1600) {
#pragma unroll
    for (int t = 0; t < 8; ++t) o[t] = 0;
  } else {
    float s[8] = {0.f, 0.f, 0.f, 0.f, 0.f, 0.f, 0.f, 0.f};
#pragma unroll
    for (int k = 0; k < 16; ++k) {
      const float* p = &PART[(size_t)k * 1024 * 1664 + base];
      float4 a = *(const float4*)p;
      float4 b = *(const float4*)(p + 4);
      s[0] += a.x; s[1] += a.y; s[2] += a.z; s[3] += a.w;
      s[4] += b.x; s[5] += b.y; s[6] += b.z; s[7] += b.w;
    }
#pragma unroll
    for (int t = 0; t < 8; ++t) {
      float v = s[t] + bias[c0 + t];
      o[t] = f2b(v > 0.f ? v : 0.f);
    }
  }
  *(ushort8*)&ZB[base] = o;
}

// ---------------- fused tail: agg GEMM -> LDS -> col GEMM -> |tanh| -> rownorm -> DN ----
__global__ __launch_bounds__(256) void tail_fused(
    const unsigned short* __restrict__ CAT192, const unsigned short* __restrict__ WTAGG,
    const float* __restrict__ agg_b, const unsigned short* __restrict__ CAT128,
    const unsigned short* __restrict__ WTCOL, const float* __restrict__ col_b,
    float* __restrict__ DN) {
  __shared__ unsigned short S1[128 * 32];
  __shared__ unsigned short S2[128 * 32];
  __shared__ unsigned short ACAT[128 * 128];
  const int bm = blockIdx.x * 128;
  const int tid = threadIdx.x;
  const int wv = tid >> 6, lane = tid & 63;
  const int sr = lane >> 2;
  const int sk = ((lane & 3) ^ ((lane >> 3) & 3)) * 8;
  const int r16 = lane & 15, kq = lane >> 4;
  const int slot8 = (kq ^ ((r16 >> 1) & 3)) * 8;
  const int wr = wv >> 1, wc = wv & 1;
  f32x4 acc[4][4];
#pragma unroll
  for (int i = 0; i < 4; ++i)
#pragma unroll
    for (int j = 0; j < 4; ++j) acc[i][j] = (f32x4){0.f, 0.f, 0.f, 0.f};

  const unsigned short* Abase = CAT192 + (size_t)bm * 192;
  for (int k0 = 0; k0 < 192; k0 += 32) {
    gload_lds16(Abase + (size_t)(wv * 16 + sr) * 192 + k0 + sk, &S1[wv * 512]);
    gload_lds16(Abase + (size_t)(64 + wv * 16 + sr) * 192 + k0 + sk, &S1[2048 + wv * 512]);
    gload_lds16(WTAGG + (size_t)(wv * 16 + sr) * 192 + k0 + sk, &S2[wv * 512]);
    gload_lds16(WTAGG + (size_t)(64 + wv * 16 + sr) * 192 + k0 + sk, &S2[2048 + wv * 512]);
    __syncthreads();
    bf16x8 af[4], bfr[4];
#pragma unroll
    for (int i = 0; i < 4; ++i)
      af[i] = *(const bf16x8*)&S1[(wr * 64 + i * 16 + r16) * 32 + slot8];
#pragma unroll
    for (int j = 0; j < 4; ++j)
      bfr[j] = *(const bf16x8*)&S2[(wc * 64 + j * 16 + r16) * 32 + slot8];
#pragma unroll
    for (int i = 0; i < 4; ++i)
#pragma unroll
      for (int j = 0; j < 4; ++j)
        acc[i][j] = __builtin_amdgcn_mfma_f32_16x16x32_bf16(af[i], bfr[j], acc[i][j], 0, 0, 0);
    __syncthreads();
  }
  if (wc == 0) {
#pragma unroll
    for (int i = 0; i < 4; ++i)
#pragma unroll
      for (int j = 0; j < 4; ++j) {
        int col = j * 16 + r16;
#pragma unroll
        for (int r = 0; r < 4; ++r) {
          int rl = wr * 64 + i * 16 + kq * 4 + r;
          ACAT[rl * 128 + col] = f2b(acc[i][j][r] + agg_b[col]);
        }
      }
  }
  for (int idx = tid; idx < 128 * 8; idx += 256) {
    int row = idx >> 3, c8 = (idx & 7) * 8;
    *(ushort8*)&ACAT[row * 128 + 64 + c8] =
        *(const ushort8*)&CAT128[(size_t)(bm + row) * 128 + 64 + c8];
  }
#pragma unroll
  for (int i = 0; i < 4; ++i)
#pragma unroll
    for (int j = 0; j < 4; ++j) acc[i][j] = (f32x4){0.f, 0.f, 0.f, 0.f};
  __syncthreads();

  for (int k0 = 0; k0 < 128; k0 += 32) {
    gload_lds16(WTCOL + (size_t)(wv * 16 + sr) * 128 + k0 + sk, &S1[wv * 512]);
    gload_lds16(WTCOL + (size_t)(64 + wv * 16 + sr) * 128 + k0 + sk, &S1[2048 + wv * 512]);
    __syncthreads();
    bf16x8 af[4], bfr[4];
#pragma unroll
    for (int i = 0; i < 4; ++i)
      af[i] = *(const bf16x8*)&ACAT[(wr * 64 + i * 16 + r16) * 128 + k0 + kq * 8];
#pragma unroll
    for (int j = 0; j < 4; ++j)
      bfr[j] = *(const bf16x8*)&S1[(wc * 64 + j * 16 + r16) * 32 + slot8];
#pragma unroll
    for (int i = 0; i < 4; ++i)
#pragma unroll
      for (int j = 0; j < 4; ++j)
        acc[i][j] = __builtin_amdgcn_mfma_f32_16x16x32_bf16(af[i], bfr[j], acc[i][j], 0, 0, 0);
    __syncthreads();
  }
  if (wc == 0) {
#pragma unroll
    for (int i = 0; i < 4; ++i)
#pragma unroll
      for (int r = 0; r < 4; ++r) {
        int row = bm + wr * 64 + i * 16 + kq * 4 + r;
        float vv[4];
#pragma unroll
        for (int j = 0; j < 4; ++j) vv[j] = fabsf(tanhf(acc[i][j][r] + col_b[j * 16 + r16]));
        float ss = vv[0] * vv[0] + vv[1] * vv[1] + vv[2] * vv[2] + vv[3] * vv[3];
        ss += __shfl_xor(ss, 1);
        ss += __shfl_xor(ss, 2);
        ss += __shfl_xor(ss, 4);
        ss += __shfl_xor(ss, 8);
        float inv = 1.f / fmaxf(sqrtf(ss), 1e-12f);
#pragma unroll
        for (int j = 0; j < 4; ++j)
          DN[(size_t)row * 64 + j * 16 + r16] = vv[j] * inv;
      }
  }
}

// ---------------- GAT pieces ----------------
__global__ void gat_scores_bf(const unsigned short* __restrict__ hlin,
                              const float* __restrict__ a_s, const float* __restrict__ a_d,
                              float* __restrict__ als, float* __restrict__ ald,
                              int H, int C, int tot) {
  int idx = blockIdx.x * blockDim.x + threadIdx.x;
  if (idx >= tot) return;
  int n = idx / H, h = idx - n * H;
  const unsigned short* base = hlin + (size_t)n * H * C + (size_t)h * C;
  const float* as = a_s + h * C;
  const float* ad = a_d + h * C;
  float ss = 0.f, sd = 0.f;
  for (int c = 0; c < C; c += 8) {
    ushort8 v = *(const ushort8*)(base + c);
#pragma unroll
    for (int t = 0; t < 8; ++t) {
      float f = b2f(v[t]);
      ss = fmaf(f, as[c + t], ss);
      sd = fmaf(f, ad[c + t], sd);
    }
  }
  als[idx] = ss;
  ald[idx] = sd;
}

// aggregate with INLINE attention: p = exp(lrelu(als[src]+ald[node])) computed in-loop.
template <int F, int C>
__global__ __launch_bounds__(256) void gat_agg_v4(
    const int* __restrict__ rowptr, const int* __restrict__ srcl,
    const float* __restrict__ als, const float* __restrict__ ald,
    const unsigned short* __restrict__ hlin,
    const float* __restrict__ bias, unsigned short* __restrict__ out) {
  constexpr int H = F / C;
  constexpr int CPN = F / 8;
  int gidx = blockIdx.x * 256 + threadIdx.x;
  if (gidx >= NN * CPN) return;
  int node = gidx / CPN;
  int c0 = (gidx - node * CPN) * 8;
  int h = c0 / C;
  float aldv = ald[node * H + h];
  float s = 0.f;
  float acc[8] = {0.f, 0.f, 0.f, 0.f, 0.f, 0.f, 0.f, 0.f};
  int start = rowptr[node], end = rowptr[node + 1];
  for (int k = start; k < end; ++k) {
    int src = srcl[k];
    float e = als[src * H + h] + aldv;
    e = (e >= 0.f) ? e : 0.2f * e;
    float p = __expf(e);
    s += p;
    ushort8 hv = *(const ushort8*)(hlin + (size_t)src * F + c0);
#pragma unroll
    for (int t = 0; t < 8; ++t) acc[t] = fmaf(p, b2f(hv[t]), acc[t]);
  }
  float inv_s = 1.f / s;
  ushort8 o;
#pragma unroll
  for (int t = 0; t < 8; ++t) {
    float val = acc[t] * inv_s + bias[c0 + t];
    o[t] = f2b(val > 0.f ? val : 0.f);
  }
  *(ushort8*)(out + (size_t)node * F + c0) = o;
}

__global__ void pool_max(const unsigned short* __restrict__ xb,
                         unsigned short* __restrict__ xgb) {
  int g = blockIdx.x, c = threadIdx.x;  // 128 threads
  const unsigned short* base = xb + (size_t)g * 32 * 128 + c;
  float m = -FLT_MAX;
#pragma unroll 8
  for (int n = 0; n < 32; ++n) m = fmaxf(m, b2f(base[n * 128]));
  xgb[g * 128 + c] = f2b(m);
}

__global__ __launch_bounds__(256) void freq_k(const float* __restrict__ dn,
                                              const float* __restrict__ sn,
                                              float* __restrict__ C, int M, int N) {
  __shared__ float As[16][64];
  __shared__ float Bs[16][65];
  int tid = threadIdx.x;
  int tx = tid & 15, ty = tid >> 4;
  int bi = blockIdx.y * 16, bj = blockIdx.x * 16;
#pragma unroll
  for (int t = 0; t < 4; ++t) {
    int idx = tid * 4 + t;
    int r = idx >> 6, c = idx & 63;
    As[r][c] = (bi + r < M) ? dn[(bi + r) * 64 + c] : 0.f;
    Bs[r][c] = (bj + r < N) ? sn[(bj + r) * 64 + c] : 0.f;
  }
  __syncthreads();
  float acc = 0.f;
#pragma unroll
  for (int k = 0; k < 64; ++k) acc = fmaf(As[ty][k], Bs[tx][k], acc);
  if (bi + ty < M && bj + tx < N) C[(size_t)(bi + ty) * N + (bj + tx)] = 5.f * acc;
}

// ---------------- launch ----------------
extern "C" void kernel_launch(void* const* d_in, const int* in_sizes, int n_in,
                              void* d_out, int out_size, void* d_ws, size_t ws_size,
                              hipStream_t stream) {
  const float* x = (const float*)d_in[0];
  const int* ei = (const int*)d_in[1];
  const float* w = (const float*)d_in[3];
  const float* z = (const float*)d_in[4];
  const float* v = (const float*)d_in[5];
  const float* side = (const float*)d_in[6];
  const float* gW[4] = {(const float*)d_in[7], (const float*)d_in[11],
                        (const float*)d_in[15], (const float*)d_in[19]};
  const float* gas[4] = {(const float*)d_in[8], (const float*)d_in[12],
                         (const float*)d_in[16], (const float*)d_in[20]};
  const float* gad[4] = {(const float*)d_in[9], (const float*)d_in[13],
                         (const float*)d_in[17], (const float*)d_in[21]};
  const float* gb[4] = {(const float*)d_in[10], (const float*)d_in[14],
                        (const float*)d_in[18], (const float*)d_in[22]};
  const float* x5_W = (const float*)d_in[23]; const float* x5_b = (const float*)d_in[24];
  const float* x6_W = (const float*)d_in[25]; const float* x6_b = (const float*)d_in[26];
  const float* w1_W = (const float*)d_in[27]; const float* w1_b = (const float*)d_in[28];
  const float* w2_W = (const float*)d_in[29]; const float* w2_b = (const float*)d_in[30];
  const float* z1_W = (const float*)d_in[31]; const float* z1_b = (const float*)d_in[32];
  const float* z2_W = (const float*)d_in[33]; const float* z2_b = (const float*)d_in[34];
  const float* v1_W = (const float*)d_in[35]; const float* v1_b = (const float*)d_in[36];
  const float* v2_W = (const float*)d_in[37]; const float* v2_b = (const float*)d_in[38];
  const float* agg_W = (const float*)d_in[39]; const float* agg_b = (const float*)d_in[40];
  const float* col_W = (const float*)d_in[41]; const float* col_b = (const float*)d_in[42];
  const float* s1_W = (const float*)d_in[43]; const float* s1_b = (const float*)d_in[44];
  const float* s2_W = (const float*)d_in[45]; const float* s2_b = (const float*)d_in[46];

  char* wsb = (char*)d_ws;
  size_t off = 0;
  auto alloc = [&](size_t bytes) {
    void* p = wsb + off;
    off = (off + bytes + 255) & ~(size_t)255;
    return p;
  };
  unsigned short* HLIN = (unsigned short*)alloc((size_t)NN * 1024 * 2);
  unsigned short* XB = (unsigned short*)alloc((size_t)NN * 1024 * 2);
  unsigned short* WTZ = (unsigned short*)alloc((size_t)1664 * 19136 * 2);
  unsigned short* ZA = (unsigned short*)alloc((size_t)1024 * 19136 * 2);
  unsigned short* WT1 = (unsigned short*)alloc((size_t)768 * 128 * 2);
  unsigned short* WT2 = (unsigned short*)alloc((size_t)1024 * 768 * 2);
  unsigned short* WT3 = (unsigned short*)alloc((size_t)1024 * 1024 * 2);
  unsigned short* WT4 = (unsigned short*)alloc((size_t)128 * 1024 * 2);
  unsigned short* WTW1 = (unsigned short*)alloc((size_t)768 * 768 * 2);
  unsigned short* WTW2 = (unsigned short*)alloc((size_t)128 * 768 * 2);
  unsigned short* WTZ2 = (unsigned short*)alloc((size_t)128 * 1664 * 2);
  unsigned short* WTV1 = (unsigned short*)alloc((size_t)256 * 1024 * 2);
  unsigned short* WTV2 = (unsigned short*)alloc((size_t)128 * 256 * 2);
  unsigned short* WTX5 = (unsigned short*)alloc((size_t)128 * 128 * 2);
  unsigned short* WTX6 = (unsigned short*)alloc((size_t)128 * 64 * 2);
  unsigned short* WTAGG = (unsigned short*)alloc((size_t)128 * 192 * 2);
  unsigned short* WTCOL = (unsigned short*)alloc((size_t)128 * 128 * 2);
  unsigned short* WTS1 = (unsigned short*)alloc((size_t)128 * 1056 * 2);
  unsigned short* WTS2 = (unsigned short*)alloc((size_t)128 * 64 * 2);
  unsigned short* WB = (unsigned short*)alloc((size_t)1024 * 768 * 2);
  unsigned short* VB = (unsigned short*)alloc((size_t)1024 * 1024 * 2);
  unsigned short* SIDEB = (unsigned short*)alloc((size_t)1024 * 1056 * 2);
  unsigned short* XGB = (unsigned short*)alloc((size_t)1024 * 128 * 2);
  unsigned short* ZB = (unsigned short*)alloc((size_t)1024 * 1664 * 2);
  unsigned short* X5O = (unsigned short*)alloc((size_t)1024 * 128 * 2);
  unsigned short* WMID = (unsigned short*)alloc((size_t)1024 * 768 * 2);
  unsigned short* VMID = (unsigned short*)alloc((size_t)1024 * 256 * 2);
  unsigned short* SEMID = (unsigned short*)alloc((size_t)1024 * 128 * 2);
  unsigned short* CAT192 = (unsigned short*)alloc((size_t)1024 * 192 * 2);
  unsigned short* CAT128 = (unsigned short*)alloc((size_t)1024 * 128 * 2);
  float* ALS = (float*)alloc((size_t)NN * 8 * 4);
  float* ALD = (float*)alloc((size_t)NN * 8 * 4);
  int* DEG = (int*)alloc((size_t)NN * 4);
  int* ROWPTR = (int*)alloc((size_t)(NN + 1) * 4);
  int* CURSOR = (int*)alloc((size_t)NN * 4);
  int* SRCL = (int*)alloc((size_t)ETOT * 4);
  float* PART = (float*)HLIN;  // 16x1024x1664 f32 = 109MB over dead HLIN+XB (134MB)

  // CSR build
  hipLaunchKernelGGL(fill_i32, dim3((NN + 255) / 256), dim3(256), 0, stream, DEG, 0, NN);
  hipLaunchKernelGGL(count_deg, dim3((ETOT + 255) / 256), dim3(256), 0, stream, ei, DEG);
  hipLaunchKernelGGL(scan_deg, dim3(1), dim3(1024), 0, stream, DEG, ROWPTR, CURSOR);
  hipLaunchKernelGGL(fill_csr, dim3((ETOT + 255) / 256), dim3(256), 0, stream, ei, CURSOR, SRCL);

  // batched weight transposes
  {
    TBatch tb;
    int acc_wg = 0, i = 0;
    auto add = [&](const float* W, unsigned short* WT, int K, int N, int Kp, int Npad) {
      int gx = Npad / 32, gy = Kp / 32;
      acc_wg += gx * gy;
      tb.d[i++] = {W, WT, K, N, Kp, Npad, gx, acc_wg};
    };
    add(z1_W, WTZ, 19127, 1600, 19136, 1664);
    add(gW[0], WT1, 109, 768, 128, 768);
    add(gW[1], WT2, 768, 1024, 768, 1024);
    add(gW[2], WT3, 1024, 1024, 1024, 1024);
    add(gW[3], WT4, 1024, 128, 1024, 128);
    add(w1_W, WTW1, 750, 750, 768, 768);
    add(w2_W, WTW2, 750, 64, 768, 128);
    add(z2_W, WTZ2, 1600, 64, 1664, 128);
    add(v1_W, WTV1, 1024, 256, 1024, 256);
    add(v2_W, WTV2, 256, 64, 256, 128);
    add(x5_W, WTX5, 128, 64, 128, 128);
    add(x6_W, WTX6, 64, 64, 64, 128);
    add(agg_W, WTAGG, 192, 64, 192, 128);
    add(col_W, WTCOL, 128, 64, 128, 128);
    add(s1_W, WTS1, 1050, 64, 1056, 128);
    add(s2_W, WTS2, 64, 64, 64, 128);
    hipLaunchKernelGGL(transpose_batch, dim3(acc_wg), dim3(256), 0, stream, tb);
  }

  // batched input conversions
  {
    CBatch cb;
    int acc_wg = 0, i = 0;
    auto add = [&](const float* in, unsigned short* out, int rowsOut, int Rreal, int C, int Cp) {
      acc_wg += (int)(((size_t)rowsOut * Cp + 255) / 256);
      cb.d[i++] = {in, out, rowsOut, Rreal, C, Cp, acc_wg};
    };
    add(z, ZA, NB, NB, 19127, 19136);
    add(x, XB, NN, NN, 109, 128);
    add(w, WB, 1024, 1024, 750, 768);
    add(v, VB, 1024, 1024, 1024, 1024);
    add(side, SIDEB, 1024, 994, 1050, 1056);
    hipLaunchKernelGGL(conv_batch, dim3(acc_wg), dim3(256), 0, stream, cb);
  }

  // GAT layers (scores fused into GEMM for C=128 layers)
  const int Hs[4] = {8, 8, 8, 1};
  const int Kp[4] = {128, 768, 1024, 1024};
  const unsigned short* WTs[4] = {WT1, WT2, WT3, WT4};
  const int Fs[4] = {768, 1024, 1024, 128};
  for (int l = 0; l < 4; ++l) {
    int H = Hs[l], F = Fs[l], C = F / H;
    int gx = F / 128;
    int nwg = gx * (NN / 128);
    if (C == 128) {
      hipLaunchKernelGGL((gemm_mfma<0, 1, 1>), dim3(nwg), dim3(256), 0, stream,
                         XB, WTs[l], (const float*)nullptr, (void*)HLIN, F, Kp[l],
                         Kp[l], Kp[l], F, gx, 0, gas[l], gad[l], ALS, ALD, H);
    } else {
      hipLaunchKernelGGL((gemm_mfma<0, 1, 0>), dim3(nwg), dim3(256), 0, stream,
                         XB, WTs[l], (const float*)nullptr, (void*)HLIN, F, Kp[l],
                         Kp[l], Kp[l], F, gx, 0, (const float*)nullptr,
                         (const float*)nullptr, (float*)nullptr, (float*)nullptr, H);
      int totNH = NN * H;
      hipLaunchKernelGGL(gat_scores_bf, dim3((totNH + 255) / 256), dim3(256), 0, stream,
                         HLIN, gas[l], gad[l], ALS, ALD, H, C, totNH);
    }
    if (l == 0)
      hipLaunchKernelGGL((gat_agg_v4<768, 96>), dim3(NN * 96 / 256), dim3(256), 0, stream,
                         ROWPTR, SRCL, ALS, ALD, HLIN, gb[l], XB);
    else if (l == 3)
      hipLaunchKernelGGL((gat_agg_v4<128, 128>), dim3(NN * 16 / 256), dim3(256), 0, stream,
                         ROWPTR, SRCL, ALS, ALD, HLIN, gb[l], XB);
    else
      hipLaunchKernelGGL((gat_agg_v4<1024, 128>), dim3(NN * 128 / 256), dim3(256), 0, stream,
                         ROWPTR, SRCL, ALS, ALD, HLIN, gb[l], XB);
  }

  // global max pool -> XGB bf16
  hipLaunchKernelGGL(pool_max, dim3(NB), dim3(128), 0, stream, XB, XGB);

  // B1: independent tail GEMMs {w1, v1, s1, x5}
  {
    GBatch b;
    int acc_wg = 0, i = 0;
    auto add = [&](const unsigned short* A, const unsigned short* BT, const float* bias,
                   void* C, int Npad, int Nreal, int K, int lda, int ldb, int ldc,
                   int zpad, int act, int obf, int Mreal) {
      int gx = Npad / 128;
      acc_wg += gx * 8;
      b.d[i++] = {A, BT, bias, C, Nreal, K, lda, ldb, ldc, gx, zpad, act, obf, Mreal, acc_wg};
    };
    add(WB, WTW1, w1_b, WMID, 768, 750, 768, 768, 768, 768, 1, 1, 1, 1024);
    add(VB, WTV1, v1_b, VMID, 256, 256, 1024, 1024, 1024, 256, 0, 1, 1, 1024);
    add(SIDEB, WTS1, s1_b, SEMID, 128, 64, 1056, 1056, 1056, 128, 1, 1, 1, 1024);
    add(XGB, WTX5, x5_b, X5O, 128, 64, 128, 128, 128, 128, 1, 1, 1, 1024);
    while (i < 5) { b.d[i] = b.d[i - 1]; b.d[i].wg_end = acc_wg; ++i; }
    hipLaunchKernelGGL(gemm_batch, dim3(acc_wg), dim3(256), 0, stream, b);
  }

  // z1 split-K (16 slices, f32 partials) + reduce -> ZB bf16
  hipLaunchKernelGGL(gemm_mfma_sk, dim3(1664), dim3(256), 0, stream, ZA, WTZ, PART, 19136, 19136, 1664);
  hipLaunchKernelGGL(zred, dim3((1024 * 1664 / 8 + 255) / 256), dim3(256), 0, stream, PART, z1_b, ZB);

  // output pointers
  float* outp = (float*)d_out;
  float* DN = outp + (size_t)NB * NSIDE;
  float* SN = DN + (size_t)NB * 64;

  // B2: {x6, w2, z2, v2, s2(tanh+rownorm -> SN)}
  {
    GBatch b;
    int acc_wg = 0, i = 0;
    auto add = [&](const unsigned short* A, const unsigned short* BT, const float* bias,
                   void* C, int Npad, int Nreal, int K, int lda, int ldb, int ldc,
                   int zpad, int act, int obf, int Mreal) {
      int gx = Npad / 128;
      acc_wg += gx * 8;
      b.d[i++] = {A, BT, bias, C, Nreal, K, lda, ldb, ldc, gx, zpad, act, obf, Mreal, acc_wg};
    };
    add(X5O, WTX6, x6_b, CAT192 + 0, 128, 64, 64, 128, 64, 192, 0, 1, 1, 1024);
    add(WMID, WTW2, w2_b, CAT192 + 64, 128, 64, 768, 768, 768, 192, 0, 1, 1, 1024);
    add(ZB, WTZ2, z2_b, CAT192 + 128, 128, 64, 1664, 1664, 1664, 192, 0, 1, 1, 1024);
    add(VMID, WTV2, v2_b, CAT128 + 64, 128, 64, 256, 256, 256, 128, 0, 1, 1, 1024);
    add(SEMID, WTS2, s2_b, SN, 128, 64, 64, 128, 64, 64, 0, 4, 0, 994);
    hipLaunchKernelGGL(gemm_batch, dim3(acc_wg), dim3(256), 0, stream, b);
  }

  // fused tail: agg GEMM -> col GEMM -> |tanh| -> rownorm -> DN
  hipLaunchKernelGGL(tail_fused, dim3(8), dim3(256), 0, stream,
                     CAT192, WTAGG, agg_b, CAT128, WTCOL, col_b, DN);

  // similarity
  hipLaunchKernelGGL(freq_k, dim3((NSIDE + 15) / 16, (NB + 15) / 16), dim3(256), 0, stream,
                     DN, SN, outp, NB, NSIDE);
}